// Round 1
// baseline (600.263 us; speedup 1.0000x reference)
//
#include <hip/hip_runtime.h>
#include <math.h>

#define B 8
#define C 256
#define L 4096
#define OC3 768

// ---------------- helpers ----------------
__device__ __forceinline__ float gelu_exact(float x){
  return 0.5f * x * (1.0f + erff(x * 0.70710678118654752440f));
}

__device__ __forceinline__ float wave_sum(float v){
  #pragma unroll
  for (int off = 32; off > 0; off >>= 1) v += __shfl_down(v, off, 64);
  return v;
}

// ---------------- GEMM: Y[b,o,l] = epi( sum_c W[o,c]*X[b,c,l] + bias[o] ) ----------------
// EPI: 0 = plain(+bias), 1 = gelu(acc+bias)*extra, 2 = acc+bias+extra
template<int K, int EPI>
__global__ __launch_bounds__(256) void gemm_kernel(
    const float* __restrict__ W, const float* __restrict__ X,
    float* __restrict__ Y, const float* __restrict__ bias,
    const float* __restrict__ extra, int O)
{
  __shared__ float Ws[16][128];
  __shared__ float Xs[16][128];
  const int t  = threadIdx.x;
  const int l0 = blockIdx.x * 128;
  const int o0 = blockIdx.y * 128;
  const int b  = blockIdx.z;
  const int tx = t & 15, ty = t >> 4;
  const float* Xb = X + (size_t)b * K * L + l0;
  float acc[8][8] = {};
  for (int k0 = 0; k0 < K; k0 += 16) {
    #pragma unroll
    for (int i = 0; i < 2; i++) {
      int fl = i * 256 + t;            // 0..511
      int o  = fl >> 2;                // 0..127
      int c4 = (fl & 3) << 2;          // 0,4,8,12
      const float4 w4 = *reinterpret_cast<const float4*>(&W[(size_t)(o0 + o) * K + k0 + c4]);
      Ws[c4+0][o] = w4.x; Ws[c4+1][o] = w4.y; Ws[c4+2][o] = w4.z; Ws[c4+3][o] = w4.w;
    }
    #pragma unroll
    for (int i = 0; i < 2; i++) {
      int fl = i * 256 + t;            // float4 index
      int c  = fl >> 5;                // 0..15
      int l  = (fl & 31) << 2;         // 0..124
      *reinterpret_cast<float4*>(&Xs[c][l]) =
          *reinterpret_cast<const float4*>(&Xb[(size_t)(k0 + c) * L + l]);
    }
    __syncthreads();
    #pragma unroll
    for (int kk = 0; kk < 16; kk++) {
      float a[8], xv[8];
      *reinterpret_cast<float4*>(&a[0])  = *reinterpret_cast<const float4*>(&Ws[kk][ty*8]);
      *reinterpret_cast<float4*>(&a[4])  = *reinterpret_cast<const float4*>(&Ws[kk][ty*8+4]);
      *reinterpret_cast<float4*>(&xv[0]) = *reinterpret_cast<const float4*>(&Xs[kk][tx*8]);
      *reinterpret_cast<float4*>(&xv[4]) = *reinterpret_cast<const float4*>(&Xs[kk][tx*8+4]);
      #pragma unroll
      for (int i = 0; i < 8; i++)
        #pragma unroll
        for (int j = 0; j < 8; j++)
          acc[i][j] = fmaf(a[i], xv[j], acc[i][j]);
    }
    __syncthreads();
  }
  #pragma unroll
  for (int i = 0; i < 8; i++) {
    const int o = o0 + ty * 8 + i;
    const float bv = bias ? bias[o] : 0.0f;
    const size_t base = ((size_t)b * O + o) * L + l0 + tx * 8;
    #pragma unroll
    for (int jj = 0; jj < 2; jj++) {
      float v0 = acc[i][jj*4+0] + bv, v1 = acc[i][jj*4+1] + bv;
      float v2 = acc[i][jj*4+2] + bv, v3 = acc[i][jj*4+3] + bv;
      float4 r;
      if (EPI == 1) {
        const float4 e = *reinterpret_cast<const float4*>(&extra[base + jj*4]);
        r.x = gelu_exact(v0) * e.x; r.y = gelu_exact(v1) * e.y;
        r.z = gelu_exact(v2) * e.z; r.w = gelu_exact(v3) * e.w;
      } else if (EPI == 2) {
        const float4 e = *reinterpret_cast<const float4*>(&extra[base + jj*4]);
        r.x = v0 + e.x; r.y = v1 + e.y; r.z = v2 + e.z; r.w = v3 + e.w;
      } else {
        r.x = v0; r.y = v1; r.z = v2; r.w = v3;
      }
      *reinterpret_cast<float4*>(&Y[base + jj*4]) = r;
    }
  }
}

// ---------------- depthwise 3x3 conv, padding 1 ----------------
__global__ __launch_bounds__(256) void dwconv_kernel(
    const float* __restrict__ in, const float* __restrict__ wdw, float* __restrict__ out)
{
  __shared__ float p[64][65];
  const int ch = blockIdx.x;
  const int b  = blockIdx.y;
  const int t  = threadIdx.x;
  const size_t base = ((size_t)b * OC3 + ch) * L;
  float wt[9];
  #pragma unroll
  for (int j = 0; j < 9; j++) wt[j] = wdw[ch * 9 + j];
  #pragma unroll
  for (int i = 0; i < 4; i++) {
    int pix = (i * 256 + t) * 4;
    const float4 v = *reinterpret_cast<const float4*>(&in[base + pix]);
    int h = pix >> 6, w = pix & 63;
    p[h][w] = v.x; p[h][w+1] = v.y; p[h][w+2] = v.z; p[h][w+3] = v.w;
  }
  __syncthreads();
  #pragma unroll
  for (int i = 0; i < 16; i++) {
    int pix = i * 256 + t;
    int h = pix >> 6, w = pix & 63;
    float acc = 0.0f;
    #pragma unroll
    for (int ky = 0; ky < 3; ky++) {
      int hh = h + ky - 1;
      if (hh < 0 || hh > 63) continue;
      #pragma unroll
      for (int kx = 0; kx < 3; kx++) {
        int ww = w + kx - 1;
        if (ww < 0 || ww > 63) continue;
        acc = fmaf(p[hh][ww], wt[ky * 3 + kx], acc);
      }
    }
    out[base + pix] = acc;
  }
}

// ---------------- per-(b,c) partial sums of q (for channel ordering) ----------------
__global__ __launch_bounds__(256) void qmean_kernel(const float* __restrict__ qkv,
                                                    float* __restrict__ partial)
{
  const int b = blockIdx.x >> 8, c = blockIdx.x & 255;
  const float4* src = reinterpret_cast<const float4*>(qkv + ((size_t)b * OC3 + c) * L);
  float s = 0.f;
  for (int i = threadIdx.x; i < 1024; i += 256) { float4 v = src[i]; s += (v.x + v.y) + (v.z + v.w); }
  s = wave_sum(s);
  __shared__ float red[4];
  if ((threadIdx.x & 63) == 0) red[threadIdx.x >> 6] = s;
  __syncthreads();
  if (threadIdx.x == 0) partial[blockIdx.x] = red[0] + red[1] + red[2] + red[3];
}

// ---------------- stable descending rank -> order[] ----------------
__global__ __launch_bounds__(256) void rank_kernel(const float* __restrict__ partial,
                                                   int* __restrict__ order)
{
  const int c = threadIdx.x;
  float key = 0.f;
  #pragma unroll
  for (int b = 0; b < 8; b++) key += partial[b * 256 + c];
  __shared__ float keys[256];
  keys[c] = key;
  __syncthreads();
  int rank = 0;
  for (int j = 0; j < 256; j++) {
    float kj = keys[j];
    rank += (kj > key) || (kj == key && j < c);
  }
  order[rank] = c;
}

// ---------------- per sorted channel: sums + inverse norms of q,k ----------------
__global__ __launch_bounds__(256) void norms_kernel(const float* __restrict__ qkv,
    const int* __restrict__ order, float* __restrict__ invnq, float* __restrict__ invnk,
    float* __restrict__ sumq, float* __restrict__ sumk)
{
  const int b = blockIdx.x >> 8, r = blockIdx.x & 255;
  const int ch = order[r];
  const float4* q = reinterpret_cast<const float4*>(qkv + ((size_t)b * OC3 + ch) * L);
  const float4* k = reinterpret_cast<const float4*>(qkv + ((size_t)b * OC3 + 256 + ch) * L);
  float sq = 0, sqq = 0, sk = 0, skk = 0;
  for (int i = threadIdx.x; i < 1024; i += 256) {
    float4 qv = q[i], kv = k[i];
    sq += (qv.x + qv.y) + (qv.z + qv.w);
    sqq = fmaf(qv.x, qv.x, fmaf(qv.y, qv.y, fmaf(qv.z, qv.z, fmaf(qv.w, qv.w, sqq))));
    sk += (kv.x + kv.y) + (kv.z + kv.w);
    skk = fmaf(kv.x, kv.x, fmaf(kv.y, kv.y, fmaf(kv.z, kv.z, fmaf(kv.w, kv.w, skk))));
  }
  sq = wave_sum(sq); sqq = wave_sum(sqq); sk = wave_sum(sk); skk = wave_sum(skk);
  __shared__ float red[4][4];
  const int lane = threadIdx.x & 63, wid = threadIdx.x >> 6;
  if (lane == 0) { red[wid][0] = sq; red[wid][1] = sqq; red[wid][2] = sk; red[wid][3] = skk; }
  __syncthreads();
  if (threadIdx.x == 0) {
    float a  = red[0][0] + red[1][0] + red[2][0] + red[3][0];
    float bq = red[0][1] + red[1][1] + red[2][1] + red[3][1];
    float cs = red[0][2] + red[1][2] + red[2][2] + red[3][2];
    float dk = red[0][3] + red[1][3] + red[2][3] + red[3][3];
    const int idx = b * 256 + r;
    sumq[idx] = a;
    invnq[idx] = 1.0f / fmaxf(sqrtf(bq), 1e-12f);
    sumk[idx] = cs;
    invnk[idx] = 1.0f / fmaxf(sqrtf(dk), 1e-12f);
  }
}

// ---------------- attention scores (raw q.k dot, L-split partials) ----------------
template<int G, int GI, int START>
__device__ void scores_body(const float* __restrict__ qkv, const int* __restrict__ order,
                            float* __restrict__ Spart, float* smem)
{
  constexpr int TC = G / 16;
  float* qs = smem;            // [G][65]
  float* ks = smem + G * 65;   // [G][65]
  __shared__ int ord_s[G];
  const int t  = threadIdx.x;
  const int b  = blockIdx.y;
  const int ls = blockIdx.x;
  for (int i = t; i < G; i += 256) ord_s[i] = order[START + i];
  __syncthreads();
  const int tx = t & 15, ty = t >> 4;
  float acc[TC][TC] = {};
  const int l0 = ls * 256;
  for (int lc = 0; lc < 256; lc += 64) {
    for (int idx = t; idx < G * 64; idx += 256) {
      const int row = idx >> 6, col = idx & 63;
      const int l = l0 + lc + col;
      qs[row * 65 + col] = qkv[((size_t)b * OC3 + ord_s[row]) * L + l];
      ks[row * 65 + col] = qkv[((size_t)b * OC3 + 256 + ord_s[row]) * L + l];
    }
    __syncthreads();
    #pragma unroll 16
    for (int l = 0; l < 64; l++) {
      float a[TC], bb[TC];
      #pragma unroll
      for (int i = 0; i < TC; i++) a[i] = qs[(ty * TC + i) * 65 + l];
      #pragma unroll
      for (int j = 0; j < TC; j++) bb[j] = ks[(tx * TC + j) * 65 + l];
      #pragma unroll
      for (int i = 0; i < TC; i++)
        #pragma unroll
        for (int j = 0; j < TC; j++) acc[i][j] = fmaf(a[i], bb[j], acc[i][j]);
    }
    __syncthreads();
  }
  float* dst = Spart + ((size_t)((b * 4 + GI) * 16 + ls)) * 9216;
  #pragma unroll
  for (int i = 0; i < TC; i++)
    #pragma unroll
    for (int j = 0; j < TC; j++)
      dst[(ty * TC + i) * G + tx * TC + j] = acc[i][j];
}

__global__ __launch_bounds__(256) void scores_kernel(const float* __restrict__ qkv,
    const int* __restrict__ order, float* __restrict__ Spart)
{
  extern __shared__ float smem[];
  switch (blockIdx.z) {
    case 0:  scores_body<32, 0, 0  >(qkv, order, Spart, smem); break;
    case 1:  scores_body<64, 1, 32 >(qkv, order, Spart, smem); break;
    case 2:  scores_body<64, 2, 96 >(qkv, order, Spart, smem); break;
    default: scores_body<96, 3, 160>(qkv, order, Spart, smem); break;
  }
}

// ---------------- reduce partials, scale by inv-norms & temperature, softmax ----------------
template<int G, int GI, int START>
__device__ void softmax_body(const float* __restrict__ Spart, const float* __restrict__ invnq,
    const float* __restrict__ invnk, const float* __restrict__ temperature,
    float* __restrict__ attn, float* Sm)
{
  const int t = threadIdx.x;
  const int b = blockIdx.x;
  const float temp = temperature[GI];
  for (int idx = t; idx < G * G; idx += 256) {
    float s = 0.f;
    #pragma unroll
    for (int ls = 0; ls < 16; ls++)
      s += Spart[((size_t)((b * 4 + GI) * 16 + ls)) * 9216 + idx];
    const int c = idx / G, d = idx - c * G;
    Sm[idx] = s * invnq[b * 256 + START + c] * invnk[b * 256 + START + d] * temp;
  }
  __syncthreads();
  for (int r = t; r < G; r += 256) {
    float m = -INFINITY;
    for (int d = 0; d < G; d++) m = fmaxf(m, Sm[r * G + d]);
    float sum = 0.f;
    for (int d = 0; d < G; d++) { float e = expf(Sm[r * G + d] - m); Sm[r * G + d] = e; sum += e; }
    const float inv = 1.0f / sum;
    float* dst = attn + (size_t)(b * 4 + GI) * 9216 + r * G;
    for (int d = 0; d < G; d++) dst[d] = Sm[r * G + d] * inv;
  }
}

__global__ __launch_bounds__(256) void softmax_kernel(const float* __restrict__ Spart,
    const float* __restrict__ invnq, const float* __restrict__ invnk,
    const float* __restrict__ temperature, float* __restrict__ attn)
{
  extern __shared__ float smem[];
  switch (blockIdx.y) {
    case 0:  softmax_body<32, 0, 0  >(Spart, invnq, invnk, temperature, attn, smem); break;
    case 1:  softmax_body<64, 1, 32 >(Spart, invnq, invnk, temperature, attn, smem); break;
    case 2:  softmax_body<64, 2, 96 >(Spart, invnq, invnk, temperature, attn, smem); break;
    default: softmax_body<96, 3, 160>(Spart, invnq, invnk, temperature, attn, smem); break;
  }
}

// ---------------- PV: out[b,c,l] = sum_d attn[c,d]*v[b,d,l] ----------------
template<int G, int GI, int START>
__device__ void pv_body(const float* __restrict__ qkv, const float* __restrict__ attn,
                        const int* __restrict__ order, float* __restrict__ outp, float* Sm)
{
  __shared__ int ord_s[G];
  const int t  = threadIdx.x;
  const int b  = blockIdx.y;
  const int lt = blockIdx.x;
  for (int i = t; i < G; i += 256) ord_s[i] = order[START + i];
  for (int idx = t; idx < G * G; idx += 256) Sm[idx] = attn[(size_t)(b * 4 + GI) * 9216 + idx];
  __syncthreads();
  const int l = lt * 256 + t;
  for (int c0 = 0; c0 < G; c0 += 32) {
    float acc[32];
    #pragma unroll
    for (int cc = 0; cc < 32; cc++) acc[cc] = 0.f;
    for (int d0 = 0; d0 < G; d0 += 4) {
      const float v0 = qkv[((size_t)b * OC3 + 512 + ord_s[d0+0]) * L + l];
      const float v1 = qkv[((size_t)b * OC3 + 512 + ord_s[d0+1]) * L + l];
      const float v2 = qkv[((size_t)b * OC3 + 512 + ord_s[d0+2]) * L + l];
      const float v3 = qkv[((size_t)b * OC3 + 512 + ord_s[d0+3]) * L + l];
      #pragma unroll
      for (int cc = 0; cc < 32; cc++) {
        const float4 a4 = *reinterpret_cast<const float4*>(&Sm[(c0 + cc) * G + d0]);
        acc[cc] = fmaf(a4.x, v0, fmaf(a4.y, v1, fmaf(a4.z, v2, fmaf(a4.w, v3, acc[cc]))));
      }
    }
    #pragma unroll
    for (int cc = 0; cc < 32; cc++)
      outp[((size_t)b * C + START + c0 + cc) * L + l] = acc[cc];
  }
}

__global__ __launch_bounds__(256) void pv_kernel(const float* __restrict__ qkv,
    const float* __restrict__ attn, const int* __restrict__ order, float* __restrict__ outp)
{
  extern __shared__ float smem[];
  switch (blockIdx.z) {
    case 0:  pv_body<32, 0, 0  >(qkv, attn, order, outp, smem); break;
    case 1:  pv_body<64, 1, 32 >(qkv, attn, order, outp, smem); break;
    case 2:  pv_body<64, 2, 96 >(qkv, attn, order, outp, smem); break;
    default: pv_body<96, 3, 160>(qkv, attn, order, outp, smem); break;
  }
}

// ---------------- z = qn + kn + out_attn ----------------
__global__ __launch_bounds__(256) void z_kernel(const float* __restrict__ qkv,
    const int* __restrict__ order, const float* __restrict__ invnq, const float* __restrict__ invnk,
    const float* __restrict__ out_attn, float* __restrict__ z)
{
  const int b = blockIdx.x >> 8, r = blockIdx.x & 255;
  const int ch = order[r];
  const float iq = invnq[b * 256 + r], ik = invnk[b * 256 + r];
  const float4* q  = reinterpret_cast<const float4*>(qkv + ((size_t)b * OC3 + ch) * L);
  const float4* k  = reinterpret_cast<const float4*>(qkv + ((size_t)b * OC3 + 256 + ch) * L);
  const float4* oa = reinterpret_cast<const float4*>(out_attn + ((size_t)b * C + r) * L);
  float4* zp = reinterpret_cast<float4*>(z + ((size_t)b * C + r) * L);
  for (int i = threadIdx.x; i < 1024; i += 256) {
    const float4 qv = q[i], kv = k[i], ov = oa[i];
    float4 o;
    o.x = fmaf(qv.x, iq, fmaf(kv.x, ik, ov.x));
    o.y = fmaf(qv.y, iq, fmaf(kv.y, ik, ov.y));
    o.z = fmaf(qv.z, iq, fmaf(kv.z, ik, ov.z));
    o.w = fmaf(qv.w, iq, fmaf(kv.w, ik, ov.w));
    zp[i] = o;
  }
}

// ---------------- qv_cache: tiled group means, broadcast ----------------
__global__ __launch_bounds__(256) void qv_kernel(const float* __restrict__ sumq,
    const float* __restrict__ sumk, const float* __restrict__ invnq,
    const float* __restrict__ invnk, float* __restrict__ out2)
{
  const int b = blockIdx.x >> 8, r = blockIdx.x & 255;
  float val = 0.f;
  {
    const int idx = b * 256 + 0 + (r & 31);
    val += fmaf(sumq[idx], invnq[idx], sumk[idx] * invnk[idx]);
  }
  {
    const int idx = b * 256 + 32 + (r & 63);
    val += fmaf(sumq[idx], invnq[idx], sumk[idx] * invnk[idx]);
  }
  {
    const int idx = b * 256 + 96 + (r & 63);
    val += fmaf(sumq[idx], invnq[idx], sumk[idx] * invnk[idx]);
  }
  if (r < 192) {
    const int rm = (r < 96) ? r : r - 96;
    const int idx = b * 256 + 160 + rm;
    val += fmaf(sumq[idx], invnq[idx], sumk[idx] * invnk[idx]);
  }
  val *= (1.0f / 4096.f) * 0.25f * 0.9f;
  const float4 o = {val, val, val, val};
  float4* dst = reinterpret_cast<float4*>(out2 + ((size_t)b * C + r) * L);
  for (int i = threadIdx.x; i < 1024; i += 256) dst[i] = o;
}

// ---------------- launch ----------------
extern "C" void kernel_launch(void* const* d_in, const int* in_sizes, int n_in,
                              void* d_out, int out_size, void* d_ws, size_t ws_size,
                              hipStream_t stream)
{
  const float* x           = (const float*)d_in[0];
  const float* temperature = (const float*)d_in[1];
  const float* w_qkv       = (const float*)d_in[2];
  const float* w_dw        = (const float*)d_in[3];
  const float* w_proj      = (const float*)d_in[4];
  const float* w_gate      = (const float*)d_in[5];
  const float* b_gate      = (const float*)d_in[6];
  const float* w_down      = (const float*)d_in[7];
  const float* b_down      = (const float*)d_in[8];
  const float* w_up        = (const float*)d_in[9];
  const float* b_up        = (const float*)d_in[10];

  if (ws_size < 202548224ULL) return;  // need ~193.2 MiB of scratch

  char* ws = (char*)d_ws;
  // Region 1 (96MB): qkv_pre -> later {score partials | out_attn, z, gated}
  float* qkv_pre  = (float*)(ws);
  float* Spart    = (float*)(ws);                      // 18.9MB, consumed before out_attn written
  float* out_attn = (float*)(ws);                      // 32MB
  float* zbuf     = (float*)(ws + 33554432);           // 32MB
  float* gated    = (float*)(ws + 67108864);           // 32MB
  // Region 2 (96MB): qkv_post -> later {mid, preproj}
  float* qkv_post = (float*)(ws + 100663296);
  float* mid      = (float*)(ws + 100663296);          // 16MB (q,k,v dead by then)
  float* preproj  = (float*)(ws + 117440512);          // 32MB
  // Stats
  float* statsF  = (float*)(ws + 201326592);
  float* partial = statsF;                // 2048
  float* invnq   = statsF + 2048;         // 2048
  float* invnk   = statsF + 4096;         // 2048
  float* sumq    = statsF + 6144;         // 2048
  float* sumk    = statsF + 8192;         // 2048
  float* attnb   = statsF + 10240;        // 294912
  int*   order   = (int*)(statsF + 10240 + 294912);    // 256

  float* out_all = (float*)d_out;
  float* qv_out  = out_all + (size_t)B * C * L;

  // 1. qkv = w_qkv @ x
  gemm_kernel<256, 0><<<dim3(32, 6, 8), 256, 0, stream>>>(w_qkv, x, qkv_pre, nullptr, nullptr, 768);
  // 2. depthwise conv
  dwconv_kernel<<<dim3(768, 8), 256, 0, stream>>>(qkv_pre, w_dw, qkv_post);
  // 3. channel ordering
  qmean_kernel<<<2048, 256, 0, stream>>>(qkv_post, partial);
  rank_kernel<<<1, 256, 0, stream>>>(partial, order);
  // 4. per-channel norms + sums (sorted order)
  norms_kernel<<<2048, 256, 0, stream>>>(qkv_post, order, invnq, invnk, sumq, sumk);
  // 5. attention
  scores_kernel<<<dim3(16, 8, 4), 256, 49920, stream>>>(qkv_post, order, Spart);
  softmax_kernel<<<dim3(8, 4), 256, 36864, stream>>>(Spart, invnq, invnk, temperature, attnb);
  pv_kernel<<<dim3(16, 8, 4), 256, 36864, stream>>>(qkv_post, attnb, order, out_attn);
  // 6. z = qn + kn + out_attn
  z_kernel<<<2048, 256, 0, stream>>>(qkv_post, order, invnq, invnk, out_attn, zbuf);
  // 7. gated MLP
  gemm_kernel<256, 1><<<dim3(32, 2, 8), 256, 0, stream>>>(w_gate, zbuf, gated, b_gate, zbuf, 256);
  gemm_kernel<256, 0><<<dim3(32, 1, 8), 256, 0, stream>>>(w_down, gated, mid, b_down, nullptr, 128);
  gemm_kernel<128, 2><<<dim3(32, 2, 8), 256, 0, stream>>>(w_up, mid, preproj, b_up, out_attn, 256);
  // 8. final projection -> output 0
  gemm_kernel<256, 0><<<dim3(32, 2, 8), 256, 0, stream>>>(w_proj, preproj, out_all, nullptr, nullptr, 256);
  // 9. qv_cache -> output 1
  qv_kernel<<<2048, 256, 0, stream>>>(sumq, sumk, invnq, invnk, qv_out);
}

// Round 2
// 448.861 us; speedup vs baseline: 1.3373x; 1.3373x over previous
//
#include <hip/hip_runtime.h>
#include <math.h>

#define B 8
#define C 256
#define L 4096
#define OC3 768

typedef __attribute__((ext_vector_type(8))) short short8v;
typedef __attribute__((ext_vector_type(8))) unsigned short u16x8;
typedef __attribute__((ext_vector_type(4))) float f32x4;

// ---------------- helpers ----------------
__device__ __forceinline__ float gelu_exact(float x){
  return 0.5f * x * (1.0f + erff(x * 0.70710678118654752440f));
}
__device__ __forceinline__ float wave_sum(float v){
  #pragma unroll
  for (int off = 32; off > 0; off >>= 1) v += __shfl_down(v, off, 64);
  return v;
}
__device__ __forceinline__ unsigned short bf16_rne(float f){
  unsigned int u = __float_as_uint(f);
  unsigned int r = u + 0x7FFFu + ((u >> 16) & 1u);
  return (unsigned short)(r >> 16);
}
__device__ __forceinline__ float bf16_tof(unsigned short h){
  return __uint_as_float(((unsigned int)h) << 16);
}
// pack value as (hi, lo) bf16 pair in one u32: mem order [hi][lo]
__device__ __forceinline__ unsigned int splitpack(float v){
  unsigned short hi = bf16_rne(v);
  float lof = v - bf16_tof(hi);
  unsigned short lo = bf16_rne(lof);
  return (unsigned int)hi | ((unsigned int)lo << 16);
}
__device__ __forceinline__ float unpack_sum(unsigned int p){
  return bf16_tof((unsigned short)(p & 0xFFFFu)) + bf16_tof((unsigned short)(p >> 16));
}

// ---------------- weight split: fp32 -> hi/lo bf16 ----------------
__global__ __launch_bounds__(256) void wsplit_kernel(
    const float* __restrict__ wqkv, const float* __restrict__ wgate,
    const float* __restrict__ wdown, const float* __restrict__ wup,
    const float* __restrict__ wproj,
    unsigned short* __restrict__ QH, unsigned short* __restrict__ QLo,
    unsigned short* __restrict__ MH, unsigned short* __restrict__ MLo)
{
  int idx = blockIdx.x * 256 + threadIdx.x;   // 0..393215
  float v;
  if (idx < 196608) {
    v = wqkv[idx];
    unsigned int p = splitpack(v);
    QH[idx] = (unsigned short)(p & 0xFFFFu); QLo[idx] = (unsigned short)(p >> 16);
  } else {
    int j = idx - 196608;
    float s;
    if (j < 65536)            s = wgate[j];
    else if (j < 98304)       s = wdown[j - 65536];
    else if (j < 131072)      s = wup[j - 98304];
    else                      s = wproj[j - 131072];
    unsigned int p = splitpack(s);
    MH[j] = (unsigned short)(p & 0xFFFFu); MLo[j] = (unsigned short)(p >> 16);
  }
}

// ---------------- x [b][c][l] fp32 -> xT hi/lo bf16 [b][l][c] ----------------
__global__ __launch_bounds__(256) void splitx_kernel(const float* __restrict__ x,
    unsigned short* __restrict__ XThi, unsigned short* __restrict__ XTlo)
{
  __shared__ float st[64][68];
  const int b = blockIdx.z, c0 = blockIdx.y * 64, lb = blockIdx.x * 64;
  const int t = threadIdx.x;
  #pragma unroll
  for (int i = 0; i < 4; i++) {
    int row = (t >> 4) + i * 16;
    int col = (t & 15) * 4;
    float4 v = *(const float4*)&x[((size_t)b * C + c0 + row) * L + lb + col];
    st[row][col] = v.x; st[row][col+1] = v.y; st[row][col+2] = v.z; st[row][col+3] = v.w;
  }
  __syncthreads();
  const int l = t >> 2, cq = t & 3;
  u16x8 hv0, hv1, lv0, lv1;
  #pragma unroll
  for (int i = 0; i < 16; i++) {
    unsigned int p = splitpack(st[cq * 16 + i][l]);
    if (i < 8) { hv0[i] = (unsigned short)(p & 0xFFFFu); lv0[i] = (unsigned short)(p >> 16); }
    else       { hv1[i-8] = (unsigned short)(p & 0xFFFFu); lv1[i-8] = (unsigned short)(p >> 16); }
  }
  size_t o = ((size_t)b * L + lb + l) * C + c0 + cq * 16;
  *(u16x8*)&XThi[o]     = hv0;
  *(u16x8*)&XThi[o + 8] = hv1;
  *(u16x8*)&XTlo[o]     = lv0;
  *(u16x8*)&XTlo[o + 8] = lv1;
}

// ---------------- split-bf16 MFMA GEMM ----------------
// Computes D[l][o] = sum_k A[l][k] * W[o][k]  (per batch b = blockIdx.z)
// A: ASRC=0 separate hi/lo bf16 [b][L][KTOT]; ASRC=1 interleaved u32 [b][L][KTOT]
// B: separate hi/lo bf16 [o][KTOT]
// EPI: 0 = store fp32 transposed to outF[b][o][L]
//      1 = +bias, store interleaved
//      2 = gelu(acc+bias)*unpack(extra), store interleaved
//      3 = acc+bias+unpack(extra), store interleaved
template<int KTOT, int ASRC, int EPI>
__global__ __launch_bounds__(256) void mgemm(
    const unsigned short* __restrict__ Ahi_g, const unsigned short* __restrict__ Alo_g,
    const unsigned int* __restrict__ Aint,
    const unsigned short* __restrict__ Bhi_g, const unsigned short* __restrict__ Blo_g,
    float* __restrict__ outF, unsigned int* __restrict__ outI,
    const float* __restrict__ bias, const unsigned int* __restrict__ extraI,
    int Ntot)
{
  __shared__ unsigned short Ah[128 * 40];
  __shared__ unsigned short Al[128 * 40];
  __shared__ unsigned short Bh[128 * 40];
  __shared__ unsigned short Bl[128 * 40];
  const int t  = threadIdx.x;
  const int lb = blockIdx.x * 128;         // l-block (M)
  const int o0 = blockIdx.y * 128;         // o-block (N)
  const int b  = blockIdx.z;
  const int w  = t >> 6, lane = t & 63;
  const int wm = w >> 1, wn = w & 1;
  const int ln = lane & 15, lg = lane >> 4;

  f32x4 z4 = {0.f, 0.f, 0.f, 0.f};
  f32x4 acc[4][4];
  #pragma unroll
  for (int i = 0; i < 4; i++)
    #pragma unroll
    for (int j = 0; j < 4; j++) acc[i][j] = z4;

  for (int kt = 0; kt < KTOT / 32; ++kt) {
    const int k0 = kt * 32;
    // ---- stage B (weights, separate hi/lo) ----
    #pragma unroll
    for (int i = 0; i < 2; i++) {
      int c = t + i * 256;
      int row = c >> 2, q = c & 3;
      const size_t g = (size_t)(o0 + row) * KTOT + k0 + q * 8;
      *(u16x8*)&Bh[row * 40 + q * 8] = *(const u16x8*)&Bhi_g[g];
      *(u16x8*)&Bl[row * 40 + q * 8] = *(const u16x8*)&Blo_g[g];
    }
    // ---- stage A (activations) ----
    if (ASRC == 0) {
      #pragma unroll
      for (int i = 0; i < 2; i++) {
        int c = t + i * 256;
        int row = c >> 2, q = c & 3;
        const size_t g = ((size_t)b * L + lb + row) * KTOT + k0 + q * 8;
        *(u16x8*)&Ah[row * 40 + q * 8] = *(const u16x8*)&Ahi_g[g];
        *(u16x8*)&Al[row * 40 + q * 8] = *(const u16x8*)&Alo_g[g];
      }
    } else {
      #pragma unroll
      for (int i = 0; i < 4; i++) {
        int c = t + i * 256;
        int row = c >> 3, q = c & 7;   // q indexes 4-elem groups
        const unsigned int* src = Aint + ((size_t)b * L + lb + row) * KTOT + k0 + q * 4;
        uint4 wv = *(const uint4*)src;
        unsigned int h0 = (wv.x & 0xFFFFu) | (wv.y << 16);
        unsigned int lo0 = (wv.x >> 16) | (wv.y & 0xFFFF0000u);
        unsigned int h1 = (wv.z & 0xFFFFu) | (wv.w << 16);
        unsigned int lo1 = (wv.z >> 16) | (wv.w & 0xFFFF0000u);
        *(uint2*)&Ah[row * 40 + q * 4] = make_uint2(h0, h1);
        *(uint2*)&Al[row * 40 + q * 4] = make_uint2(lo0, lo1);
      }
    }
    __syncthreads();
    // ---- fragments + MFMA ----
    short8v bh[4], bl[4];
    #pragma unroll
    for (int nf = 0; nf < 4; nf++) {
      int row = wn * 64 + nf * 16 + ln;
      bh[nf] = *(const short8v*)&Bh[row * 40 + lg * 8];
      bl[nf] = *(const short8v*)&Bl[row * 40 + lg * 8];
    }
    #pragma unroll
    for (int mf = 0; mf < 4; mf++) {
      int row = wm * 64 + mf * 16 + ln;
      short8v ah = *(const short8v*)&Ah[row * 40 + lg * 8];
      short8v al = *(const short8v*)&Al[row * 40 + lg * 8];
      #pragma unroll
      for (int nf = 0; nf < 4; nf++) {
        acc[mf][nf] = __builtin_amdgcn_mfma_f32_16x16x32_bf16(ah, bh[nf], acc[mf][nf], 0, 0, 0);
        acc[mf][nf] = __builtin_amdgcn_mfma_f32_16x16x32_bf16(ah, bl[nf], acc[mf][nf], 0, 0, 0);
        acc[mf][nf] = __builtin_amdgcn_mfma_f32_16x16x32_bf16(al, bh[nf], acc[mf][nf], 0, 0, 0);
      }
    }
    __syncthreads();
  }
  // ---- epilogue ----
  #pragma unroll
  for (int mf = 0; mf < 4; mf++) {
    const int mbase = lb + wm * 64 + mf * 16 + lg * 4;  // global l of reg 0
    #pragma unroll
    for (int nf = 0; nf < 4; nf++) {
      const int o = o0 + wn * 64 + nf * 16 + ln;        // global output channel
      if (EPI == 0) {
        float4 r;
        r.x = acc[mf][nf][0]; r.y = acc[mf][nf][1];
        r.z = acc[mf][nf][2]; r.w = acc[mf][nf][3];
        *(float4*)&outF[((size_t)b * Ntot + o) * L + mbase] = r;
      } else {
        const float bv = bias ? bias[o] : 0.0f;
        #pragma unroll
        for (int r = 0; r < 4; r++) {
          const size_t idx = ((size_t)b * L + mbase + r) * Ntot + o;
          float v = acc[mf][nf][r] + bv;
          if (EPI == 2) { v = gelu_exact(v) * unpack_sum(extraI[idx]); }
          if (EPI == 3) { v = v + unpack_sum(extraI[idx]); }
          outI[idx] = splitpack(v);
        }
      }
    }
  }
}

// ---------------- depthwise 3x3 conv, padding 1 ----------------
__global__ __launch_bounds__(256) void dwconv_kernel(
    const float* __restrict__ in, const float* __restrict__ wdw, float* __restrict__ out)
{
  __shared__ float p[64][65];
  const int ch = blockIdx.x;
  const int b  = blockIdx.y;
  const int t  = threadIdx.x;
  const size_t base = ((size_t)b * OC3 + ch) * L;
  float wt[9];
  #pragma unroll
  for (int j = 0; j < 9; j++) wt[j] = wdw[ch * 9 + j];
  #pragma unroll
  for (int i = 0; i < 4; i++) {
    int pix = (i * 256 + t) * 4;
    const float4 v = *reinterpret_cast<const float4*>(&in[base + pix]);
    int h = pix >> 6, ww = pix & 63;
    p[h][ww] = v.x; p[h][ww+1] = v.y; p[h][ww+2] = v.z; p[h][ww+3] = v.w;
  }
  __syncthreads();
  #pragma unroll
  for (int i = 0; i < 16; i++) {
    int pix = i * 256 + t;
    int h = pix >> 6, ww = pix & 63;
    float acc = 0.0f;
    #pragma unroll
    for (int ky = 0; ky < 3; ky++) {
      int hh = h + ky - 1;
      if (hh < 0 || hh > 63) continue;
      #pragma unroll
      for (int kx = 0; kx < 3; kx++) {
        int cc = ww + kx - 1;
        if (cc < 0 || cc > 63) continue;
        acc = fmaf(p[hh][cc], wt[ky * 3 + kx], acc);
      }
    }
    out[base + pix] = acc;
  }
}

// ---------------- per-(b,c) partial sums of q ----------------
__global__ __launch_bounds__(256) void qmean_kernel(const float* __restrict__ qkv,
                                                    float* __restrict__ partial)
{
  const int b = blockIdx.x >> 8, c = blockIdx.x & 255;
  const float4* src = reinterpret_cast<const float4*>(qkv + ((size_t)b * OC3 + c) * L);
  float s = 0.f;
  for (int i = threadIdx.x; i < 1024; i += 256) { float4 v = src[i]; s += (v.x + v.y) + (v.z + v.w); }
  s = wave_sum(s);
  __shared__ float red[4];
  if ((threadIdx.x & 63) == 0) red[threadIdx.x >> 6] = s;
  __syncthreads();
  if (threadIdx.x == 0) partial[blockIdx.x] = red[0] + red[1] + red[2] + red[3];
}

// ---------------- stable descending rank ----------------
__global__ __launch_bounds__(256) void rank_kernel(const float* __restrict__ partial,
                                                   int* __restrict__ order)
{
  const int c = threadIdx.x;
  float key = 0.f;
  #pragma unroll
  for (int b = 0; b < 8; b++) key += partial[b * 256 + c];
  __shared__ float keys[256];
  keys[c] = key;
  __syncthreads();
  int rank = 0;
  for (int j = 0; j < 256; j++) {
    float kj = keys[j];
    rank += (kj > key) || (kj == key && j < c);
  }
  order[rank] = c;
}

// ---------------- per sorted channel: sums + inverse norms of q,k ----------------
__global__ __launch_bounds__(256) void norms_kernel(const float* __restrict__ qkv,
    const int* __restrict__ order, float* __restrict__ invnq, float* __restrict__ invnk,
    float* __restrict__ sumq, float* __restrict__ sumk)
{
  const int b = blockIdx.x >> 8, r = blockIdx.x & 255;
  const int ch = order[r];
  const float4* q = reinterpret_cast<const float4*>(qkv + ((size_t)b * OC3 + ch) * L);
  const float4* k = reinterpret_cast<const float4*>(qkv + ((size_t)b * OC3 + 256 + ch) * L);
  float sq = 0, sqq = 0, sk = 0, skk = 0;
  for (int i = threadIdx.x; i < 1024; i += 256) {
    float4 qv = q[i], kv = k[i];
    sq += (qv.x + qv.y) + (qv.z + qv.w);
    sqq = fmaf(qv.x, qv.x, fmaf(qv.y, qv.y, fmaf(qv.z, qv.z, fmaf(qv.w, qv.w, sqq))));
    sk += (kv.x + kv.y) + (kv.z + kv.w);
    skk = fmaf(kv.x, kv.x, fmaf(kv.y, kv.y, fmaf(kv.z, kv.z, fmaf(kv.w, kv.w, skk))));
  }
  sq = wave_sum(sq); sqq = wave_sum(sqq); sk = wave_sum(sk); skk = wave_sum(skk);
  __shared__ float red[4][4];
  const int lane = threadIdx.x & 63, wid = threadIdx.x >> 6;
  if (lane == 0) { red[wid][0] = sq; red[wid][1] = sqq; red[wid][2] = sk; red[wid][3] = skk; }
  __syncthreads();
  if (threadIdx.x == 0) {
    float a  = red[0][0] + red[1][0] + red[2][0] + red[3][0];
    float bq = red[0][1] + red[1][1] + red[2][1] + red[3][1];
    float cs = red[0][2] + red[1][2] + red[2][2] + red[3][2];
    float dk = red[0][3] + red[1][3] + red[2][3] + red[3][3];
    const int idx = b * 256 + r;
    sumq[idx] = a;
    invnq[idx] = 1.0f / fmaxf(sqrtf(bq), 1e-12f);
    sumk[idx] = cs;
    invnk[idx] = 1.0f / fmaxf(sqrtf(dk), 1e-12f);
  }
}

// ---------------- attention scores (raw q.k dot, L-split partials) ----------------
template<int G, int GI, int START>
__device__ void scores_body(const float* __restrict__ qkv, const int* __restrict__ order,
                            float* __restrict__ Spart, float* smem)
{
  constexpr int TC = G / 16;
  float* qs = smem;
  float* ks = smem + G * 65;
  __shared__ int ord_s[G];
  const int t  = threadIdx.x;
  const int b  = blockIdx.y;
  const int ls = blockIdx.x;
  for (int i = t; i < G; i += 256) ord_s[i] = order[START + i];
  __syncthreads();
  const int tx = t & 15, ty = t >> 4;
  float acc[TC][TC] = {};
  const int lq = ls * 256;
  for (int lc = 0; lc < 256; lc += 64) {
    for (int idx = t; idx < G * 64; idx += 256) {
      const int row = idx >> 6, col = idx & 63;
      const int l = lq + lc + col;
      qs[row * 65 + col] = qkv[((size_t)b * OC3 + ord_s[row]) * L + l];
      ks[row * 65 + col] = qkv[((size_t)b * OC3 + 256 + ord_s[row]) * L + l];
    }
    __syncthreads();
    #pragma unroll 16
    for (int l = 0; l < 64; l++) {
      float a[TC], bb[TC];
      #pragma unroll
      for (int i = 0; i < TC; i++) a[i] = qs[(ty * TC + i) * 65 + l];
      #pragma unroll
      for (int j = 0; j < TC; j++) bb[j] = ks[(tx * TC + j) * 65 + l];
      #pragma unroll
      for (int i = 0; i < TC; i++)
        #pragma unroll
        for (int j = 0; j < TC; j++) acc[i][j] = fmaf(a[i], bb[j], acc[i][j]);
    }
    __syncthreads();
  }
  float* dst = Spart + ((size_t)((b * 4 + GI) * 16 + ls)) * 9216;
  #pragma unroll
  for (int i = 0; i < TC; i++)
    #pragma unroll
    for (int j = 0; j < TC; j++)
      dst[(ty * TC + i) * G + tx * TC + j] = acc[i][j];
}

__global__ __launch_bounds__(256) void scores_kernel(const float* __restrict__ qkv,
    const int* __restrict__ order, float* __restrict__ Spart)
{
  extern __shared__ float smem[];
  switch (blockIdx.z) {
    case 0:  scores_body<32, 0, 0  >(qkv, order, Spart, smem); break;
    case 1:  scores_body<64, 1, 32 >(qkv, order, Spart, smem); break;
    case 2:  scores_body<64, 2, 96 >(qkv, order, Spart, smem); break;
    default: scores_body<96, 3, 160>(qkv, order, Spart, smem); break;
  }
}

// ---------------- reduce partials, scale, softmax ----------------
template<int G, int GI, int START>
__device__ void softmax_body(const float* __restrict__ Spart, const float* __restrict__ invnq,
    const float* __restrict__ invnk, const float* __restrict__ temperature,
    float* __restrict__ attn, float* Sm)
{
  const int t = threadIdx.x;
  const int b = blockIdx.x;
  const float temp = temperature[GI];
  for (int idx = t; idx < G * G; idx += 256) {
    float s = 0.f;
    #pragma unroll
    for (int ls = 0; ls < 16; ls++)
      s += Spart[((size_t)((b * 4 + GI) * 16 + ls)) * 9216 + idx];
    const int c = idx / G, d = idx - c * G;
    Sm[idx] = s * invnq[b * 256 + START + c] * invnk[b * 256 + START + d] * temp;
  }
  __syncthreads();
  for (int r = t; r < G; r += 256) {
    float m = -INFINITY;
    for (int d = 0; d < G; d++) m = fmaxf(m, Sm[r * G + d]);
    float sum = 0.f;
    for (int d = 0; d < G; d++) { float e = expf(Sm[r * G + d] - m); Sm[r * G + d] = e; sum += e; }
    const float inv = 1.0f / sum;
    float* dst = attn + (size_t)(b * 4 + GI) * 9216 + r * G;
    for (int d = 0; d < G; d++) dst[d] = Sm[r * G + d] * inv;
  }
}

__global__ __launch_bounds__(256) void softmax_kernel(const float* __restrict__ Spart,
    const float* __restrict__ invnq, const float* __restrict__ invnk,
    const float* __restrict__ temperature, float* __restrict__ attn)
{
  extern __shared__ float smem[];
  switch (blockIdx.y) {
    case 0:  softmax_body<32, 0, 0  >(Spart, invnq, invnk, temperature, attn, smem); break;
    case 1:  softmax_body<64, 1, 32 >(Spart, invnq, invnk, temperature, attn, smem); break;
    case 2:  softmax_body<64, 2, 96 >(Spart, invnq, invnk, temperature, attn, smem); break;
    default: softmax_body<96, 3, 160>(Spart, invnq, invnk, temperature, attn, smem); break;
  }
}

// ---------------- PV + fused z: writes outT (attn out) and zT = qn+kn+out, both split-bf16 [b][l][c] ----------------
template<int G, int GI, int START>
__device__ void pv_body(const float* __restrict__ qkv, const float* __restrict__ attn,
                        const int* __restrict__ order,
                        const float* __restrict__ invnq, const float* __restrict__ invnk,
                        unsigned int* __restrict__ zT, unsigned int* __restrict__ outT,
                        float* Sm)
{
  __shared__ int ord_s[G];
  const int t  = threadIdx.x;
  const int b  = blockIdx.y;
  const int lt = blockIdx.x;
  for (int i = t; i < G; i += 256) ord_s[i] = order[START + i];
  for (int idx = t; idx < G * G; idx += 256) Sm[idx] = attn[(size_t)(b * 4 + GI) * 9216 + idx];
  __syncthreads();
  const int l = lt * 256 + t;
  for (int c0 = 0; c0 < G; c0 += 32) {
    float acc[32];
    #pragma unroll
    for (int cc = 0; cc < 32; cc++) acc[cc] = 0.f;
    for (int d0 = 0; d0 < G; d0 += 4) {
      const float v0 = qkv[((size_t)b * OC3 + 512 + ord_s[d0+0]) * L + l];
      const float v1 = qkv[((size_t)b * OC3 + 512 + ord_s[d0+1]) * L + l];
      const float v2 = qkv[((size_t)b * OC3 + 512 + ord_s[d0+2]) * L + l];
      const float v3 = qkv[((size_t)b * OC3 + 512 + ord_s[d0+3]) * L + l];
      #pragma unroll
      for (int cc = 0; cc < 32; cc++) {
        const float4 a4 = *reinterpret_cast<const float4*>(&Sm[(c0 + cc) * G + d0]);
        acc[cc] = fmaf(a4.x, v0, fmaf(a4.y, v1, fmaf(a4.z, v2, fmaf(a4.w, v3, acc[cc]))));
      }
    }
    #pragma unroll
    for (int cc = 0; cc < 32; cc++) {
      const int r = START + c0 + cc;
      const float qv = qkv[((size_t)b * OC3 + ord_s[c0 + cc]) * L + l];
      const float kv = qkv[((size_t)b * OC3 + 256 + ord_s[c0 + cc]) * L + l];
      const float iq = invnq[b * 256 + r], ik = invnk[b * 256 + r];
      const size_t uidx = ((size_t)b * L + l) * C + r;
      outT[uidx] = splitpack(acc[cc]);
      zT[uidx]   = splitpack(acc[cc] + qv * iq + kv * ik);
    }
  }
}

__global__ __launch_bounds__(256) void pv_kernel(const float* __restrict__ qkv,
    const float* __restrict__ attn, const int* __restrict__ order,
    const float* __restrict__ invnq, const float* __restrict__ invnk,
    unsigned int* __restrict__ zT, unsigned int* __restrict__ outT)
{
  extern __shared__ float smem[];
  switch (blockIdx.z) {
    case 0:  pv_body<32, 0, 0  >(qkv, attn, order, invnq, invnk, zT, outT, smem); break;
    case 1:  pv_body<64, 1, 32 >(qkv, attn, order, invnq, invnk, zT, outT, smem); break;
    case 2:  pv_body<64, 2, 96 >(qkv, attn, order, invnq, invnk, zT, outT, smem); break;
    default: pv_body<96, 3, 160>(qkv, attn, order, invnq, invnk, zT, outT, smem); break;
  }
}

// ---------------- qv_cache ----------------
__global__ __launch_bounds__(256) void qv_kernel(const float* __restrict__ sumq,
    const float* __restrict__ sumk, const float* __restrict__ invnq,
    const float* __restrict__ invnk, float* __restrict__ out2)
{
  const int b = blockIdx.x >> 8, r = blockIdx.x & 255;
  float val = 0.f;
  {
    const int idx = b * 256 + 0 + (r & 31);
    val += fmaf(sumq[idx], invnq[idx], sumk[idx] * invnk[idx]);
  }
  {
    const int idx = b * 256 + 32 + (r & 63);
    val += fmaf(sumq[idx], invnq[idx], sumk[idx] * invnk[idx]);
  }
  {
    const int idx = b * 256 + 96 + (r & 63);
    val += fmaf(sumq[idx], invnq[idx], sumk[idx] * invnk[idx]);
  }
  if (r < 192) {
    const int rm = (r < 96) ? r : r - 96;
    const int idx = b * 256 + 160 + rm;
    val += fmaf(sumq[idx], invnq[idx], sumk[idx] * invnk[idx]);
  }
  val *= (1.0f / 4096.f) * 0.25f * 0.9f;
  const float4 o = {val, val, val, val};
  float4* dst = reinterpret_cast<float4*>(out2 + ((size_t)b * C + r) * L);
  for (int i = threadIdx.x; i < 1024; i += 256) dst[i] = o;
}

// ---------------- launch ----------------
extern "C" void kernel_launch(void* const* d_in, const int* in_sizes, int n_in,
                              void* d_out, int out_size, void* d_ws, size_t ws_size,
                              hipStream_t stream)
{
  const float* x           = (const float*)d_in[0];
  const float* temperature = (const float*)d_in[1];
  const float* w_qkv       = (const float*)d_in[2];
  const float* w_dw        = (const float*)d_in[3];
  const float* w_proj      = (const float*)d_in[4];
  const float* w_gate      = (const float*)d_in[5];
  const float* b_gate      = (const float*)d_in[6];
  const float* w_down      = (const float*)d_in[7];
  const float* b_down      = (const float*)d_in[8];
  const float* w_up        = (const float*)d_in[9];
  const float* b_up        = (const float*)d_in[10];

  if (ws_size < 202548224ULL) return;

  char* ws = (char*)d_ws;
  // Region A [0, 96M): qkv_pre; after dwconv: Spart@0, attnb@19922944, zT@32M, outT@64M, gated@0
  float*        qkv_pre = (float*)(ws);
  float*        Spart   = (float*)(ws);
  float*        attnb   = (float*)(ws + 19922944);
  unsigned int* zT      = (unsigned int*)(ws + 33554432);
  unsigned int* outT    = (unsigned int*)(ws + 67108864);
  unsigned int* gatedT  = (unsigned int*)(ws);
  // Region B [96M, 192M): qkv_post; before dwconv: XThi/XTlo + Wqkv split; after pv: midT, preprojT
  float*          qkv_post = (float*)(ws + 100663296);
  unsigned short* XThi     = (unsigned short*)(ws + 100663296);   // 16MB
  unsigned short* XTlo     = (unsigned short*)(ws + 117440512);   // 16MB
  unsigned short* WqkvHi   = (unsigned short*)(ws + 134217728);   // 384KB
  unsigned short* WqkvLo   = (unsigned short*)(ws + 134610944);   // 384KB
  unsigned int*   midT     = (unsigned int*)(ws + 100663296);     // 16MB
  unsigned int*   preprojT = (unsigned int*)(ws + 117440512);     // 32MB
  // Region C [192M, ...): persistent weights + stats
  unsigned short* WmlpHi = (unsigned short*)(ws + 201326592);     // 384KB
  unsigned short* WmlpLo = (unsigned short*)(ws + 201719808);     // 384KB
  float* partial = (float*)(ws + 202113024);
  float* invnq   = (float*)(ws + 202121216);
  float* invnk   = (float*)(ws + 202129408);
  float* sumq    = (float*)(ws + 202137600);
  float* sumk    = (float*)(ws + 202145792);
  int*   order   = (int*)(ws + 202153984);

  float* out_all = (float*)d_out;
  float* qv_out  = out_all + (size_t)B * C * L;

  // 0. weight + input splits
  wsplit_kernel<<<1536, 256, 0, stream>>>(w_qkv, w_gate, w_down, w_up, w_proj,
                                          WqkvHi, WqkvLo, WmlpHi, WmlpLo);
  splitx_kernel<<<dim3(64, 4, 8), 256, 0, stream>>>(x, XThi, XTlo);
  // 1. qkv = w_qkv @ x  (MFMA, out fp32 [b][768][L])
  mgemm<256, 0, 0><<<dim3(32, 6, 8), 256, 0, stream>>>(
      XThi, XTlo, nullptr, WqkvHi, WqkvLo, qkv_pre, nullptr, nullptr, nullptr, 768);
  // 2. depthwise conv
  dwconv_kernel<<<dim3(768, 8), 256, 0, stream>>>(qkv_pre, w_dw, qkv_post);
  // 3. channel ordering
  qmean_kernel<<<2048, 256, 0, stream>>>(qkv_post, partial);
  rank_kernel<<<1, 256, 0, stream>>>(partial, order);
  // 4. norms
  norms_kernel<<<2048, 256, 0, stream>>>(qkv_post, order, invnq, invnk, sumq, sumk);
  // 5. attention
  scores_kernel<<<dim3(16, 8, 4), 256, 49920, stream>>>(qkv_post, order, Spart);
  softmax_kernel<<<dim3(8, 4), 256, 36864, stream>>>(Spart, invnq, invnk, temperature, attnb);
  pv_kernel<<<dim3(16, 8, 4), 256, 36864, stream>>>(qkv_post, attnb, order, invnq, invnk, zT, outT);
  // 6. MLP chain (MFMA, interleaved split-bf16 activations in [b][l][c])
  mgemm<256, 1, 2><<<dim3(32, 2, 8), 256, 0, stream>>>(
      nullptr, nullptr, zT, WmlpHi, WmlpLo, nullptr, gatedT, b_gate, zT, 256);
  mgemm<256, 1, 1><<<dim3(32, 1, 8), 256, 0, stream>>>(
      nullptr, nullptr, gatedT, WmlpHi + 65536, WmlpLo + 65536, nullptr, midT, b_down, nullptr, 128);
  mgemm<128, 1, 3><<<dim3(32, 2, 8), 256, 0, stream>>>(
      nullptr, nullptr, midT, WmlpHi + 98304, WmlpLo + 98304, nullptr, preprojT, b_up, outT, 256);
  // 7. final projection -> output 0 (fp32 [b][256][L])
  mgemm<256, 1, 0><<<dim3(32, 2, 8), 256, 0, stream>>>(
      nullptr, nullptr, preprojT, WmlpHi + 131072, WmlpLo + 131072, out_all, nullptr, nullptr, nullptr, 256);
  // 8. qv_cache -> output 1
  qv_kernel<<<2048, 256, 0, stream>>>(sumq, sumk, invnq, invnk, qv_out);
}

// Round 3
// 380.433 us; speedup vs baseline: 1.5778x; 1.1799x over previous
//
#include <hip/hip_runtime.h>
#include <math.h>

#define B 8
#define C 256
#define L 4096
#define OC3 768

typedef __attribute__((ext_vector_type(8))) short short8v;
typedef __attribute__((ext_vector_type(8))) unsigned short u16x8;
typedef __attribute__((ext_vector_type(4))) float f32x4;

// ---------------- helpers ----------------
__device__ __forceinline__ float gelu_exact(float x){
  return 0.5f * x * (1.0f + erff(x * 0.70710678118654752440f));
}
__device__ __forceinline__ float wave_sum(float v){
  #pragma unroll
  for (int off = 32; off > 0; off >>= 1) v += __shfl_down(v, off, 64);
  return v;
}
__device__ __forceinline__ unsigned short bf16_rne(float f){
  unsigned int u = __float_as_uint(f);
  unsigned int r = u + 0x7FFFu + ((u >> 16) & 1u);
  return (unsigned short)(r >> 16);
}
__device__ __forceinline__ float bf16_tof(unsigned short h){
  return __uint_as_float(((unsigned int)h) << 16);
}
// pack value as (hi, lo) bf16 pair in one u32: low16 = hi, high16 = lo
__device__ __forceinline__ unsigned int splitpack(float v){
  unsigned short hi = bf16_rne(v);
  float lof = v - bf16_tof(hi);
  unsigned short lo = bf16_rne(lof);
  return (unsigned int)hi | ((unsigned int)lo << 16);
}
__device__ __forceinline__ float unpack_sum(unsigned int p){
  return bf16_tof((unsigned short)(p & 0xFFFFu)) + bf16_tof((unsigned short)(p >> 16));
}
// deinterleave 4 packed u32 -> (hi0,hi1),(lo0,lo1) u32 pairs (each = 2 bf16)
__device__ __forceinline__ void deint4(const uint4 wv,
    unsigned int& h0, unsigned int& h1, unsigned int& l0, unsigned int& l1){
  h0 = (wv.x & 0xFFFFu) | (wv.y << 16);
  l0 = (wv.x >> 16) | (wv.y & 0xFFFF0000u);
  h1 = (wv.z & 0xFFFFu) | (wv.w << 16);
  l1 = (wv.z >> 16) | (wv.w & 0xFFFF0000u);
}

// ---------------- weight split: fp32 -> hi/lo bf16 ----------------
__global__ __launch_bounds__(256) void wsplit_kernel(
    const float* __restrict__ wqkv, const float* __restrict__ wgate,
    const float* __restrict__ wdown, const float* __restrict__ wup,
    const float* __restrict__ wproj,
    unsigned short* __restrict__ QH, unsigned short* __restrict__ QLo,
    unsigned short* __restrict__ MH, unsigned short* __restrict__ MLo)
{
  int idx = blockIdx.x * 256 + threadIdx.x;   // 0..393215
  if (idx < 196608) {
    unsigned int p = splitpack(wqkv[idx]);
    QH[idx] = (unsigned short)(p & 0xFFFFu); QLo[idx] = (unsigned short)(p >> 16);
  } else {
    int j = idx - 196608;
    float s;
    if (j < 65536)            s = wgate[j];
    else if (j < 98304)       s = wdown[j - 65536];
    else if (j < 131072)      s = wup[j - 98304];
    else                      s = wproj[j - 131072];
    unsigned int p = splitpack(s);
    MH[j] = (unsigned short)(p & 0xFFFFu); MLo[j] = (unsigned short)(p >> 16);
  }
}

// ---------------- x [b][c][l] fp32 -> xT hi/lo bf16 [b][l][c] ----------------
__global__ __launch_bounds__(256) void splitx_kernel(const float* __restrict__ x,
    unsigned short* __restrict__ XThi, unsigned short* __restrict__ XTlo)
{
  __shared__ float st[64][68];
  const int b = blockIdx.z, c0 = blockIdx.y * 64, lb = blockIdx.x * 64;
  const int t = threadIdx.x;
  #pragma unroll
  for (int i = 0; i < 4; i++) {
    int row = (t >> 4) + i * 16;
    int col = (t & 15) * 4;
    float4 v = *(const float4*)&x[((size_t)b * C + c0 + row) * L + lb + col];
    st[row][col] = v.x; st[row][col+1] = v.y; st[row][col+2] = v.z; st[row][col+3] = v.w;
  }
  __syncthreads();
  const int l = t >> 2, cq = t & 3;
  u16x8 hv0, hv1, lv0, lv1;
  #pragma unroll
  for (int i = 0; i < 16; i++) {
    unsigned int p = splitpack(st[cq * 16 + i][l]);
    if (i < 8) { hv0[i] = (unsigned short)(p & 0xFFFFu); lv0[i] = (unsigned short)(p >> 16); }
    else       { hv1[i-8] = (unsigned short)(p & 0xFFFFu); lv1[i-8] = (unsigned short)(p >> 16); }
  }
  size_t o = ((size_t)b * L + lb + l) * C + c0 + cq * 16;
  *(u16x8*)&XThi[o]     = hv0;
  *(u16x8*)&XThi[o + 8] = hv1;
  *(u16x8*)&XTlo[o]     = lv0;
  *(u16x8*)&XTlo[o + 8] = lv1;
}

// ---------------- split-bf16 MFMA GEMM (big dense chain) ----------------
template<int KTOT, int ASRC, int EPI>
__global__ __launch_bounds__(256) void mgemm(
    const unsigned short* __restrict__ Ahi_g, const unsigned short* __restrict__ Alo_g,
    const unsigned int* __restrict__ Aint,
    const unsigned short* __restrict__ Bhi_g, const unsigned short* __restrict__ Blo_g,
    float* __restrict__ outF, unsigned int* __restrict__ outI,
    const float* __restrict__ bias, const unsigned int* __restrict__ extraI,
    int Ntot)
{
  __shared__ unsigned short Ah[128 * 40];
  __shared__ unsigned short Al[128 * 40];
  __shared__ unsigned short Bh[128 * 40];
  __shared__ unsigned short Bl[128 * 40];
  const int t  = threadIdx.x;
  const int lb = blockIdx.x * 128;
  const int o0 = blockIdx.y * 128;
  const int b  = blockIdx.z;
  const int w  = t >> 6, lane = t & 63;
  const int wm = w >> 1, wn = w & 1;
  const int ln = lane & 15, lg = lane >> 4;

  f32x4 z4 = {0.f, 0.f, 0.f, 0.f};
  f32x4 acc[4][4];
  #pragma unroll
  for (int i = 0; i < 4; i++)
    #pragma unroll
    for (int j = 0; j < 4; j++) acc[i][j] = z4;

  for (int kt = 0; kt < KTOT / 32; ++kt) {
    const int k0 = kt * 32;
    #pragma unroll
    for (int i = 0; i < 2; i++) {
      int c = t + i * 256;
      int row = c >> 2, q = c & 3;
      const size_t g = (size_t)(o0 + row) * KTOT + k0 + q * 8;
      *(u16x8*)&Bh[row * 40 + q * 8] = *(const u16x8*)&Bhi_g[g];
      *(u16x8*)&Bl[row * 40 + q * 8] = *(const u16x8*)&Blo_g[g];
    }
    if (ASRC == 0) {
      #pragma unroll
      for (int i = 0; i < 2; i++) {
        int c = t + i * 256;
        int row = c >> 2, q = c & 3;
        const size_t g = ((size_t)b * L + lb + row) * KTOT + k0 + q * 8;
        *(u16x8*)&Ah[row * 40 + q * 8] = *(const u16x8*)&Ahi_g[g];
        *(u16x8*)&Al[row * 40 + q * 8] = *(const u16x8*)&Alo_g[g];
      }
    } else {
      #pragma unroll
      for (int i = 0; i < 4; i++) {
        int c = t + i * 256;
        int row = c >> 3, q = c & 7;
        const uint4 wv = *(const uint4*)(Aint + ((size_t)b * L + lb + row) * KTOT + k0 + q * 4);
        unsigned int h0, h1, l0, l1;
        deint4(wv, h0, h1, l0, l1);
        *(uint2*)&Ah[row * 40 + q * 4] = make_uint2(h0, h1);
        *(uint2*)&Al[row * 40 + q * 4] = make_uint2(l0, l1);
      }
    }
    __syncthreads();
    short8v bh[4], bl[4];
    #pragma unroll
    for (int nf = 0; nf < 4; nf++) {
      int row = wn * 64 + nf * 16 + ln;
      bh[nf] = *(const short8v*)&Bh[row * 40 + lg * 8];
      bl[nf] = *(const short8v*)&Bl[row * 40 + lg * 8];
    }
    #pragma unroll
    for (int mf = 0; mf < 4; mf++) {
      int row = wm * 64 + mf * 16 + ln;
      short8v ah = *(const short8v*)&Ah[row * 40 + lg * 8];
      short8v al = *(const short8v*)&Al[row * 40 + lg * 8];
      #pragma unroll
      for (int nf = 0; nf < 4; nf++) {
        acc[mf][nf] = __builtin_amdgcn_mfma_f32_16x16x32_bf16(ah, bh[nf], acc[mf][nf], 0, 0, 0);
        acc[mf][nf] = __builtin_amdgcn_mfma_f32_16x16x32_bf16(ah, bl[nf], acc[mf][nf], 0, 0, 0);
        acc[mf][nf] = __builtin_amdgcn_mfma_f32_16x16x32_bf16(al, bh[nf], acc[mf][nf], 0, 0, 0);
      }
    }
    __syncthreads();
  }
  #pragma unroll
  for (int mf = 0; mf < 4; mf++) {
    const int mbase = lb + wm * 64 + mf * 16 + lg * 4;
    #pragma unroll
    for (int nf = 0; nf < 4; nf++) {
      const int o = o0 + wn * 64 + nf * 16 + ln;
      if (EPI == 0) {
        float4 r;
        r.x = acc[mf][nf][0]; r.y = acc[mf][nf][1];
        r.z = acc[mf][nf][2]; r.w = acc[mf][nf][3];
        *(float4*)&outF[((size_t)b * Ntot + o) * L + mbase] = r;
      } else {
        const float bv = bias ? bias[o] : 0.0f;
        #pragma unroll
        for (int r = 0; r < 4; r++) {
          const size_t idx = ((size_t)b * L + mbase + r) * Ntot + o;
          float v = acc[mf][nf][r] + bv;
          if (EPI == 2) { v = gelu_exact(v) * unpack_sum(extraI[idx]); }
          if (EPI == 3) { v = v + unpack_sum(extraI[idx]); }
          outI[idx] = splitpack(v);
        }
      }
    }
  }
}

// ---------------- depthwise 3x3 conv + split-pack + channel stats ----------------
__global__ __launch_bounds__(256) void dwconv2_kernel(
    const float* __restrict__ in, const float* __restrict__ wdw,
    unsigned int* __restrict__ qkS, float* __restrict__ vbuf,
    float* __restrict__ csum, float* __restrict__ csumsq)
{
  __shared__ float p[64][65];
  __shared__ float rs[4][2];
  const int ch = blockIdx.x;
  const int b  = blockIdx.y;
  const int t  = threadIdx.x;
  const size_t base = ((size_t)b * OC3 + ch) * L;
  float wt[9];
  #pragma unroll
  for (int j = 0; j < 9; j++) wt[j] = wdw[ch * 9 + j];
  #pragma unroll
  for (int i = 0; i < 4; i++) {
    int pix = (i * 256 + t) * 4;
    const float4 v = *reinterpret_cast<const float4*>(&in[base + pix]);
    int h = pix >> 6, ww = pix & 63;
    p[h][ww] = v.x; p[h][ww+1] = v.y; p[h][ww+2] = v.z; p[h][ww+3] = v.w;
  }
  __syncthreads();
  float s = 0.f, s2 = 0.f;
  #pragma unroll
  for (int i = 0; i < 16; i++) {
    int pix = i * 256 + t;
    int h = pix >> 6, ww = pix & 63;
    float acc = 0.0f;
    #pragma unroll
    for (int ky = 0; ky < 3; ky++) {
      int hh = h + ky - 1;
      if (hh < 0 || hh > 63) continue;
      #pragma unroll
      for (int kx = 0; kx < 3; kx++) {
        int cc = ww + kx - 1;
        if (cc < 0 || cc > 63) continue;
        acc = fmaf(p[hh][cc], wt[ky * 3 + kx], acc);
      }
    }
    if (ch < 512) {
      qkS[((size_t)b * 512 + ch) * L + pix] = splitpack(acc);
      s += acc;
      s2 = fmaf(acc, acc, s2);
    } else {
      vbuf[((size_t)b * 256 + (ch - 512)) * L + pix] = acc;
    }
  }
  if (ch < 512) {
    s = wave_sum(s); s2 = wave_sum(s2);
    const int lane = t & 63, wid = t >> 6;
    if (lane == 0) { rs[wid][0] = s; rs[wid][1] = s2; }
    __syncthreads();
    if (t == 0) {
      csum[b * 512 + ch]   = rs[0][0] + rs[1][0] + rs[2][0] + rs[3][0];
      csumsq[b * 512 + ch] = rs[0][1] + rs[1][1] + rs[2][1] + rs[3][1];
    }
  }
}

// ---------------- stable descending rank over q-channel sums ----------------
__global__ __launch_bounds__(256) void rank_kernel(const float* __restrict__ csum,
                                                   int* __restrict__ order)
{
  const int c = threadIdx.x;
  float key = 0.f;
  #pragma unroll
  for (int b = 0; b < 8; b++) key += csum[b * 512 + c];
  __shared__ float keys[256];
  keys[c] = key;
  __syncthreads();
  int rank = 0;
  for (int j = 0; j < 256; j++) {
    float kj = keys[j];
    rank += (kj > key) || (kj == key && j < c);
  }
  order[rank] = c;
}

// ---------------- relabel stats into sorted order ----------------
__global__ __launch_bounds__(256) void stats_kernel(
    const float* __restrict__ csum, const float* __restrict__ csumsq,
    const int* __restrict__ order,
    float* __restrict__ sumq, float* __restrict__ sumk,
    float* __restrict__ invnq, float* __restrict__ invnk)
{
  const int b = blockIdx.x, r = threadIdx.x;
  const int ch = order[r];
  sumq[b * 256 + r]  = csum[b * 512 + ch];
  invnq[b * 256 + r] = 1.0f / fmaxf(sqrtf(csumsq[b * 512 + ch]), 1e-12f);
  sumk[b * 256 + r]  = csum[b * 512 + 256 + ch];
  invnk[b * 256 + r] = 1.0f / fmaxf(sqrtf(csumsq[b * 512 + 256 + ch]), 1e-12f);
}

// ---------------- pack: vTS = split(v^T sorted) [b][l][r]; zqT = split(qn+kn) [b][l][r] ----------------
__global__ __launch_bounds__(256) void vpack_kernel(
    const float* __restrict__ vbuf, const unsigned int* __restrict__ qkS,
    const int* __restrict__ order,
    const float* __restrict__ invnq, const float* __restrict__ invnk,
    unsigned int* __restrict__ vTS, unsigned int* __restrict__ zqT)
{
  __shared__ float vt[64][65];
  __shared__ float zt[64][65];
  __shared__ int   ordS[256];
  __shared__ float iqS[256], ikS[256];
  const int t = threadIdx.x, lb = blockIdx.x * 64, b = blockIdx.y;
  ordS[t] = order[t];
  iqS[t] = invnq[b * 256 + t];
  ikS[t] = invnk[b * 256 + t];
  __syncthreads();
  for (int cc = 0; cc < 4; cc++) {
    const int r0 = cc * 64;
    for (int i = t; i < 1024; i += 256) {
      const int row = i >> 4, q = i & 15;
      const int ch = ordS[r0 + row];
      const float4 v4 = *(const float4*)&vbuf[((size_t)b * 256 + ch) * L + lb + q * 4];
      vt[q*4+0][row] = v4.x; vt[q*4+1][row] = v4.y; vt[q*4+2][row] = v4.z; vt[q*4+3][row] = v4.w;
    }
    for (int i = t; i < 1024; i += 256) {
      const int row = i >> 4, q = i & 15;
      const int ch = ordS[r0 + row];
      const float iq = iqS[r0 + row], ik = ikS[r0 + row];
      const uint4 qv = *(const uint4*)&qkS[((size_t)b * 512 + ch) * L + lb + q * 4];
      const uint4 kv = *(const uint4*)&qkS[((size_t)b * 512 + 256 + ch) * L + lb + q * 4];
      zt[q*4+0][row] = unpack_sum(qv.x) * iq + unpack_sum(kv.x) * ik;
      zt[q*4+1][row] = unpack_sum(qv.y) * iq + unpack_sum(kv.y) * ik;
      zt[q*4+2][row] = unpack_sum(qv.z) * iq + unpack_sum(kv.z) * ik;
      zt[q*4+3][row] = unpack_sum(qv.w) * iq + unpack_sum(kv.w) * ik;
    }
    __syncthreads();
    const int l = t >> 2, qq = t & 3;
    const size_t ob = ((size_t)b * L + lb + l) * 256 + r0 + qq * 16;
    #pragma unroll
    for (int j = 0; j < 4; j++) {
      uint4 ov, zv;
      ov.x = splitpack(vt[l][qq*16 + j*4 + 0]); zv.x = splitpack(zt[l][qq*16 + j*4 + 0]);
      ov.y = splitpack(vt[l][qq*16 + j*4 + 1]); zv.y = splitpack(zt[l][qq*16 + j*4 + 1]);
      ov.z = splitpack(vt[l][qq*16 + j*4 + 2]); zv.z = splitpack(zt[l][qq*16 + j*4 + 2]);
      ov.w = splitpack(vt[l][qq*16 + j*4 + 3]); zv.w = splitpack(zt[l][qq*16 + j*4 + 3]);
      *(uint4*)&vTS[ob + j*4] = ov;
      *(uint4*)&zqT[ob + j*4] = zv;
    }
    __syncthreads();
  }
}

// ---------------- scores via MFMA: Spart[b][GI][ks][m][d] = sum over K-slice ----------------
// layout consts: per-b Spart stride 147456 floats; SPB = 8*GOFF[GI]
template<int G, int GI, int START, int MB, int SPB>
__device__ void scores_body(const unsigned int* __restrict__ qkS,
    const int* __restrict__ order, float* __restrict__ Spart,
    unsigned short* Ah, unsigned short* Al, unsigned short* Bh, unsigned short* Bl,
    int* ordS)
{
  constexpr int MR = (G - MB * 64 < 64) ? (G - MB * 64) : 64;
  constexpr int NF = G / 16;
  const int t = threadIdx.x, ks = blockIdx.x, b = blockIdx.y;
  const int w = t >> 6, lane = t & 63, ln = lane & 15, lg = lane >> 4;
  for (int i = t; i < G; i += 256) ordS[i] = order[START + i];
  __syncthreads();
  const int k0 = ks * 512;
  const bool act = (w * 16) < MR;
  f32x4 z4 = {0.f, 0.f, 0.f, 0.f};
  f32x4 acc[NF];
  #pragma unroll
  for (int i = 0; i < NF; i++) acc[i] = z4;
  for (int kc = 0; kc < 512; kc += 32) {
    for (int i = t; i < MR * 8; i += 256) {
      const int row = i >> 3, q = i & 7;
      const int gr = ordS[MB * 64 + row];
      const uint4 wv = *(const uint4*)&qkS[((size_t)b * 512 + gr) * L + k0 + kc + q * 4];
      unsigned int h0, h1, l0, l1;
      deint4(wv, h0, h1, l0, l1);
      *(uint2*)&Ah[row * 40 + q * 4] = make_uint2(h0, h1);
      *(uint2*)&Al[row * 40 + q * 4] = make_uint2(l0, l1);
    }
    for (int i = t; i < G * 8; i += 256) {
      const int row = i >> 3, q = i & 7;
      const int gr = 256 + ordS[row];
      const uint4 wv = *(const uint4*)&qkS[((size_t)b * 512 + gr) * L + k0 + kc + q * 4];
      unsigned int h0, h1, l0, l1;
      deint4(wv, h0, h1, l0, l1);
      *(uint2*)&Bh[row * 40 + q * 4] = make_uint2(h0, h1);
      *(uint2*)&Bl[row * 40 + q * 4] = make_uint2(l0, l1);
    }
    __syncthreads();
    if (act) {
      const short8v ah = *(const short8v*)&Ah[(w * 16 + ln) * 40 + lg * 8];
      const short8v al = *(const short8v*)&Al[(w * 16 + ln) * 40 + lg * 8];
      #pragma unroll
      for (int nf = 0; nf < NF; nf++) {
        const short8v bh = *(const short8v*)&Bh[(nf * 16 + ln) * 40 + lg * 8];
        const short8v bl = *(const short8v*)&Bl[(nf * 16 + ln) * 40 + lg * 8];
        acc[nf] = __builtin_amdgcn_mfma_f32_16x16x32_bf16(ah, bh, acc[nf], 0, 0, 0);
        acc[nf] = __builtin_amdgcn_mfma_f32_16x16x32_bf16(ah, bl, acc[nf], 0, 0, 0);
        acc[nf] = __builtin_amdgcn_mfma_f32_16x16x32_bf16(al, bh, acc[nf], 0, 0, 0);
      }
    }
    __syncthreads();
  }
  if (act) {
    float* dst = Spart + (size_t)b * 147456 + SPB + ks * G * G;
    #pragma unroll
    for (int nf = 0; nf < NF; nf++) {
      const int d = nf * 16 + ln;
      #pragma unroll
      for (int r = 0; r < 4; r++) {
        const int m = MB * 64 + w * 16 + lg * 4 + r;
        dst[m * G + d] = acc[nf][r];
      }
    }
  }
}

__global__ __launch_bounds__(256) void scores_kernel(const unsigned int* __restrict__ qkS,
    const int* __restrict__ order, float* __restrict__ Spart)
{
  __shared__ unsigned short Ah[64 * 40];
  __shared__ unsigned short Al[64 * 40];
  __shared__ unsigned short Bh[96 * 40];
  __shared__ unsigned short Bl[96 * 40];
  __shared__ int ordS[96];
  switch (blockIdx.z) {
    case 0:  scores_body<32, 0, 0,   0, 0    >(qkS, order, Spart, Ah, Al, Bh, Bl, ordS); break;
    case 1:  scores_body<64, 1, 32,  0, 8192 >(qkS, order, Spart, Ah, Al, Bh, Bl, ordS); break;
    case 2:  scores_body<64, 2, 96,  0, 40960>(qkS, order, Spart, Ah, Al, Bh, Bl, ordS); break;
    case 3:  scores_body<96, 3, 160, 0, 73728>(qkS, order, Spart, Ah, Al, Bh, Bl, ordS); break;
    default: scores_body<96, 3, 160, 1, 73728>(qkS, order, Spart, Ah, Al, Bh, Bl, ordS); break;
  }
}

// ---------------- reduce partials, scale, softmax, emit split-u32 attn ----------------
template<int G, int GI, int START, int SPB, int AOFF>
__device__ void softmax_body(const float* __restrict__ Spart, const float* __restrict__ invnq,
    const float* __restrict__ invnk, const float* __restrict__ temperature,
    unsigned int* __restrict__ attnP, float* Sm)
{
  const int t = threadIdx.x;
  const int b = blockIdx.x;
  const float temp = temperature[GI];
  for (int idx = t; idx < G * G; idx += 256) {
    float s = 0.f;
    #pragma unroll
    for (int ks = 0; ks < 8; ks++)
      s += Spart[(size_t)b * 147456 + SPB + ks * G * G + idx];
    const int c = idx / G, d = idx - c * G;
    Sm[idx] = s * invnq[b * 256 + START + c] * invnk[b * 256 + START + d] * temp;
  }
  __syncthreads();
  for (int r = t; r < G; r += 256) {
    float m = -INFINITY;
    for (int d = 0; d < G; d++) m = fmaxf(m, Sm[r * G + d]);
    float sum = 0.f;
    for (int d = 0; d < G; d++) { float e = expf(Sm[r * G + d] - m); Sm[r * G + d] = e; sum += e; }
    const float inv = 1.0f / sum;
    unsigned int* dst = attnP + (size_t)b * 18432 + AOFF + r * G;
    for (int d = 0; d < G; d++) dst[d] = splitpack(Sm[r * G + d] * inv);
  }
}

__global__ __launch_bounds__(256) void softmax_kernel(const float* __restrict__ Spart,
    const float* __restrict__ invnq, const float* __restrict__ invnk,
    const float* __restrict__ temperature, unsigned int* __restrict__ attnP)
{
  extern __shared__ float smem[];
  switch (blockIdx.y) {
    case 0:  softmax_body<32, 0, 0,   0,     0   >(Spart, invnq, invnk, temperature, attnP, smem); break;
    case 1:  softmax_body<64, 1, 32,  8192,  1024>(Spart, invnq, invnk, temperature, attnP, smem); break;
    case 2:  softmax_body<64, 2, 96,  40960, 5120>(Spart, invnq, invnk, temperature, attnP, smem); break;
    default: softmax_body<96, 3, 160, 73728, 9216>(Spart, invnq, invnk, temperature, attnP, smem); break;
  }
}

// ---------------- PV via MFMA + fused z epilogue ----------------
// out[l][r] = sum_d vTS[l][START+d] * attn[r][d]; write outT, zT = out + zq
template<int G, int GI, int START, int AOFF>
__device__ void pv_body(const unsigned int* __restrict__ vTS,
    const unsigned int* __restrict__ attnP, const unsigned int* __restrict__ zqT,
    unsigned int* __restrict__ outT, unsigned int* __restrict__ zT,
    unsigned short* Ah, unsigned short* Al, unsigned short* Bh, unsigned short* Bl)
{
  constexpr int NF = G / 16;
  const int t = threadIdx.x, b = blockIdx.y, l0 = blockIdx.x * 128;
  const int w = t >> 6, lane = t & 63, ln = lane & 15, lg = lane >> 4;
  f32x4 z4 = {0.f, 0.f, 0.f, 0.f};
  f32x4 acc[2][NF];
  #pragma unroll
  for (int i = 0; i < 2; i++)
    #pragma unroll
    for (int j = 0; j < NF; j++) acc[i][j] = z4;
  for (int kc = 0; kc < G; kc += 32) {
    for (int i = t; i < 128 * 8; i += 256) {
      const int row = i >> 3, q = i & 7;
      const uint4 wv = *(const uint4*)&vTS[((size_t)b * L + l0 + row) * 256 + START + kc + q * 4];
      unsigned int h0, h1, l0_, l1_;
      deint4(wv, h0, h1, l0_, l1_);
      *(uint2*)&Ah[row * 40 + q * 4] = make_uint2(h0, h1);
      *(uint2*)&Al[row * 40 + q * 4] = make_uint2(l0_, l1_);
    }
    for (int i = t; i < G * 8; i += 256) {
      const int row = i >> 3, q = i & 7;
      const uint4 wv = *(const uint4*)&attnP[(size_t)b * 18432 + AOFF + row * G + kc + q * 4];
      unsigned int h0, h1, l0_, l1_;
      deint4(wv, h0, h1, l0_, l1_);
      *(uint2*)&Bh[row * 40 + q * 4] = make_uint2(h0, h1);
      *(uint2*)&Bl[row * 40 + q * 4] = make_uint2(l0_, l1_);
    }
    __syncthreads();
    short8v bh[NF], bl[NF];
    #pragma unroll
    for (int nf = 0; nf < NF; nf++) {
      bh[nf] = *(const short8v*)&Bh[(nf * 16 + ln) * 40 + lg * 8];
      bl[nf] = *(const short8v*)&Bl[(nf * 16 + ln) * 40 + lg * 8];
    }
    #pragma unroll
    for (int mi = 0; mi < 2; mi++) {
      const int row = (w * 2 + mi) * 16 + ln;
      const short8v ah = *(const short8v*)&Ah[row * 40 + lg * 8];
      const short8v al = *(const short8v*)&Al[row * 40 + lg * 8];
      #pragma unroll
      for (int nf = 0; nf < NF; nf++) {
        acc[mi][nf] = __builtin_amdgcn_mfma_f32_16x16x32_bf16(ah, bh[nf], acc[mi][nf], 0, 0, 0);
        acc[mi][nf] = __builtin_amdgcn_mfma_f32_16x16x32_bf16(ah, bl[nf], acc[mi][nf], 0, 0, 0);
        acc[mi][nf] = __builtin_amdgcn_mfma_f32_16x16x32_bf16(al, bh[nf], acc[mi][nf], 0, 0, 0);
      }
    }
    __syncthreads();
  }
  #pragma unroll
  for (int mi = 0; mi < 2; mi++) {
    const int lbase = l0 + (w * 2 + mi) * 16 + lg * 4;
    #pragma unroll
    for (int nf = 0; nf < NF; nf++) {
      const int col = START + nf * 16 + ln;
      #pragma unroll
      for (int r = 0; r < 4; r++) {
        const size_t idx = ((size_t)b * L + lbase + r) * 256 + col;
        const float v = acc[mi][nf][r];
        outT[idx] = splitpack(v);
        zT[idx]   = splitpack(v + unpack_sum(zqT[idx]));
      }
    }
  }
}

__global__ __launch_bounds__(256) void pv_kernel(const unsigned int* __restrict__ vTS,
    const unsigned int* __restrict__ attnP, const unsigned int* __restrict__ zqT,
    unsigned int* __restrict__ outT, unsigned int* __restrict__ zT)
{
  __shared__ unsigned short Ah[128 * 40];
  __shared__ unsigned short Al[128 * 40];
  __shared__ unsigned short Bh[96 * 40];
  __shared__ unsigned short Bl[96 * 40];
  switch (blockIdx.z) {
    case 0:  pv_body<32, 0, 0,   0   >(vTS, attnP, zqT, outT, zT, Ah, Al, Bh, Bl); break;
    case 1:  pv_body<64, 1, 32,  1024>(vTS, attnP, zqT, outT, zT, Ah, Al, Bh, Bl); break;
    case 2:  pv_body<64, 2, 96,  5120>(vTS, attnP, zqT, outT, zT, Ah, Al, Bh, Bl); break;
    default: pv_body<96, 3, 160, 9216>(vTS, attnP, zqT, outT, zT, Ah, Al, Bh, Bl); break;
  }
}

// ---------------- qv_cache ----------------
__global__ __launch_bounds__(256) void qv_kernel(const float* __restrict__ sumq,
    const float* __restrict__ sumk, const float* __restrict__ invnq,
    const float* __restrict__ invnk, float* __restrict__ out2)
{
  const int b = blockIdx.x >> 8, r = blockIdx.x & 255;
  float val = 0.f;
  {
    const int idx = b * 256 + 0 + (r & 31);
    val += fmaf(sumq[idx], invnq[idx], sumk[idx] * invnk[idx]);
  }
  {
    const int idx = b * 256 + 32 + (r & 63);
    val += fmaf(sumq[idx], invnq[idx], sumk[idx] * invnk[idx]);
  }
  {
    const int idx = b * 256 + 96 + (r & 63);
    val += fmaf(sumq[idx], invnq[idx], sumk[idx] * invnk[idx]);
  }
  if (r < 192) {
    const int rm = (r < 96) ? r : r - 96;
    const int idx = b * 256 + 160 + rm;
    val += fmaf(sumq[idx], invnq[idx], sumk[idx] * invnk[idx]);
  }
  val *= (1.0f / 4096.f) * 0.25f * 0.9f;
  const float4 o = {val, val, val, val};
  float4* dst = reinterpret_cast<float4*>(out2 + ((size_t)b * C + r) * L);
  for (int i = threadIdx.x; i < 1024; i += 256) dst[i] = o;
}

// ---------------- launch ----------------
extern "C" void kernel_launch(void* const* d_in, const int* in_sizes, int n_in,
                              void* d_out, int out_size, void* d_ws, size_t ws_size,
                              hipStream_t stream)
{
  const float* x           = (const float*)d_in[0];
  const float* temperature = (const float*)d_in[1];
  const float* w_qkv       = (const float*)d_in[2];
  const float* w_dw        = (const float*)d_in[3];
  const float* w_proj      = (const float*)d_in[4];
  const float* w_gate      = (const float*)d_in[5];
  const float* b_gate      = (const float*)d_in[6];
  const float* w_down      = (const float*)d_in[7];
  const float* b_down      = (const float*)d_in[8];
  const float* w_up        = (const float*)d_in[9];
  const float* b_up        = (const float*)d_in[10];

  if (ws_size < 202548224ULL) return;

  char* ws = (char*)d_ws;
  // Region A [0, 96M):
  float*        qkv_pre  = (float*)(ws);                       // 96MB (dead after dwconv)
  unsigned int* vTS      = (unsigned int*)(ws);                // 32MB
  unsigned int* zqT      = (unsigned int*)(ws + 33554432);     // 32MB
  float*        Spart    = (float*)(ws + 67108864);            // 4.72MB
  unsigned int* attnP    = (unsigned int*)(ws + 71827456);     // 0.59MB
  unsigned int* preprojT = (unsigned int*)(ws);                // 32MB (after pv, vTS dead)
  // Region B [96M, 192M):
  unsigned short* XThi   = (unsigned short*)(ws + 100663296);  // 16MB
  unsigned short* XTlo   = (unsigned short*)(ws + 117440512);  // 16MB
  unsigned short* WqkvHi = (unsigned short*)(ws + 134217728);  // 384KB
  unsigned short* WqkvLo = (unsigned short*)(ws + 134610944);  // 384KB
  unsigned int*   qkS    = (unsigned int*)(ws + 100663296);    // 64MB (after qkv gemm)
  float*          vbuf   = (float*)(ws + 167772160);           // 32MB
  unsigned int*   outT   = (unsigned int*)(ws + 100663296);    // 32MB (after scores+softmax)
  unsigned int*   zT     = (unsigned int*)(ws + 134217728);    // 32MB
  unsigned int*   gatedT = (unsigned int*)(ws + 167772160);    // 32MB
  unsigned int*   midT   = (unsigned int*)(ws + 134217728);    // 16MB (after gate gemm)
  // Region C [192M, 193.2M):
  unsigned short* WmlpHi = (unsigned short*)(ws + 201326592);  // 384KB
  unsigned short* WmlpLo = (unsigned short*)(ws + 201719808);  // 384KB
  float* csum   = (float*)(ws + 202113024);                    // 16KB
  float* csumsq = (float*)(ws + 202129408);                    // 16KB
  float* sumq   = (float*)(ws + 202145792);                    // 8KB
  float* sumk   = (float*)(ws + 202153984);                    // 8KB
  float* invnq  = (float*)(ws + 202162176);                    // 8KB
  float* invnk  = (float*)(ws + 202170368);                    // 8KB
  int*   order  = (int*)(ws + 202178560);                      // 1KB

  float* out_all = (float*)d_out;
  float* qv_out  = out_all + (size_t)B * C * L;

  // 0. weight + input splits
  wsplit_kernel<<<1536, 256, 0, stream>>>(w_qkv, w_gate, w_down, w_up, w_proj,
                                          WqkvHi, WqkvLo, WmlpHi, WmlpLo);
  splitx_kernel<<<dim3(64, 4, 8), 256, 0, stream>>>(x, XThi, XTlo);
  // 1. qkv = w_qkv @ x  (MFMA, out fp32 [b][768][L])
  mgemm<256, 0, 0><<<dim3(32, 6, 8), 256, 0, stream>>>(
      XThi, XTlo, nullptr, WqkvHi, WqkvLo, qkv_pre, nullptr, nullptr, nullptr, 768);
  // 2. depthwise conv (+ split-pack q,k; v fp32; channel stats)
  dwconv2_kernel<<<dim3(768, 8), 256, 0, stream>>>(qkv_pre, w_dw, qkS, vbuf, csum, csumsq);
  // 3. channel ordering + stats relabel
  rank_kernel<<<1, 256, 0, stream>>>(csum, order);
  stats_kernel<<<8, 256, 0, stream>>>(csum, csumsq, order, sumq, sumk, invnq, invnk);
  // 4. pack v^T + zq
  vpack_kernel<<<dim3(64, 8), 256, 0, stream>>>(vbuf, qkS, order, invnq, invnk, vTS, zqT);
  // 5. attention
  scores_kernel<<<dim3(8, 8, 5), 256, 0, stream>>>(qkS, order, Spart);
  softmax_kernel<<<dim3(8, 4), 256, 36864, stream>>>(Spart, invnq, invnk, temperature, attnP);
  pv_kernel<<<dim3(32, 8, 4), 256, 0, stream>>>(vTS, attnP, zqT, outT, zT);
  // 6. MLP chain
  mgemm<256, 1, 2><<<dim3(32, 2, 8), 256, 0, stream>>>(
      nullptr, nullptr, zT, WmlpHi, WmlpLo, nullptr, gatedT, b_gate, zT, 256);
  mgemm<256, 1, 1><<<dim3(32, 1, 8), 256, 0, stream>>>(
      nullptr, nullptr, gatedT, WmlpHi + 65536, WmlpLo + 65536, nullptr, midT, b_down, nullptr, 128);
  mgemm<128, 1, 3><<<dim3(32, 2, 8), 256, 0, stream>>>(
      nullptr, nullptr, midT, WmlpHi + 98304, WmlpLo + 98304, nullptr, preprojT, b_up, outT, 256);
  // 7. final projection -> output 0
  mgemm<256, 1, 0><<<dim3(32, 2, 8), 256, 0, stream>>>(
      nullptr, nullptr, preprojT, WmlpHi + 131072, WmlpLo + 131072, out_all, nullptr, nullptr, nullptr, 256);
  // 8. qv_cache -> output 1
  qv_kernel<<<2048, 256, 0, stream>>>(sumq, sumk, invnq, invnk, qv_out);
}

// Round 4
// 346.674 us; speedup vs baseline: 1.7315x; 1.0974x over previous
//
#include <hip/hip_runtime.h>
#include <math.h>

#define B 8
#define C 256
#define L 4096
#define OC3 768

typedef __attribute__((ext_vector_type(8))) short short8v;
typedef __attribute__((ext_vector_type(8))) unsigned short u16x8;
typedef __attribute__((ext_vector_type(4))) float f32x4;

// ---------------- helpers ----------------
__device__ __forceinline__ float gelu_exact(float x){
  return 0.5f * x * (1.0f + erff(x * 0.70710678118654752440f));
}
__device__ __forceinline__ float wave_sum(float v){
  #pragma unroll
  for (int off = 32; off > 0; off >>= 1) v += __shfl_down(v, off, 64);
  return v;
}
__device__ __forceinline__ unsigned short bf16_rne(float f){
  unsigned int u = __float_as_uint(f);
  unsigned int r = u + 0x7FFFu + ((u >> 16) & 1u);
  return (unsigned short)(r >> 16);
}
__device__ __forceinline__ float bf16_tof(unsigned short h){
  return __uint_as_float(((unsigned int)h) << 16);
}
// pack value as (hi, lo) bf16 pair in one u32: low16 = hi, high16 = lo
__device__ __forceinline__ unsigned int splitpack(float v){
  unsigned short hi = bf16_rne(v);
  float lof = v - bf16_tof(hi);
  unsigned short lo = bf16_rne(lof);
  return (unsigned int)hi | ((unsigned int)lo << 16);
}
// async global->LDS 16B per lane; LDS dest must be wave-uniform base
__device__ __forceinline__ void gl16(const unsigned short* g, unsigned short* l){
  __builtin_amdgcn_global_load_lds(
      (const __attribute__((address_space(1))) void*)g,
      (__attribute__((address_space(3))) void*)l, 16, 0, 0);
}

// ---------------- weight split: fp32 -> hi/lo bf16 ----------------
__global__ __launch_bounds__(256) void wsplit_kernel(
    const float* __restrict__ wqkv, const float* __restrict__ wgate,
    const float* __restrict__ wdown, const float* __restrict__ wup,
    const float* __restrict__ wproj,
    unsigned short* __restrict__ QH, unsigned short* __restrict__ QLo,
    unsigned short* __restrict__ MH, unsigned short* __restrict__ MLo)
{
  int idx = blockIdx.x * 256 + threadIdx.x;   // 0..393215
  if (idx < 196608) {
    unsigned int p = splitpack(wqkv[idx]);
    QH[idx] = (unsigned short)(p & 0xFFFFu); QLo[idx] = (unsigned short)(p >> 16);
  } else {
    int j = idx - 196608;
    float s;
    if (j < 65536)            s = wgate[j];
    else if (j < 98304)       s = wdown[j - 65536];
    else if (j < 131072)      s = wup[j - 98304];
    else                      s = wproj[j - 131072];
    unsigned int p = splitpack(s);
    MH[j] = (unsigned short)(p & 0xFFFFu); MLo[j] = (unsigned short)(p >> 16);
  }
}

// ---------------- x [b][c][l] fp32 -> xT hi/lo bf16 [b][l][c] ----------------
__global__ __launch_bounds__(256) void splitx_kernel(const float* __restrict__ x,
    unsigned short* __restrict__ XThi, unsigned short* __restrict__ XTlo)
{
  __shared__ float st[64][68];
  const int b = blockIdx.z, c0 = blockIdx.y * 64, lb = blockIdx.x * 64;
  const int t = threadIdx.x;
  #pragma unroll
  for (int i = 0; i < 4; i++) {
    int row = (t >> 4) + i * 16;
    int col = (t & 15) * 4;
    float4 v = *(const float4*)&x[((size_t)b * C + c0 + row) * L + lb + col];
    st[row][col] = v.x; st[row][col+1] = v.y; st[row][col+2] = v.z; st[row][col+3] = v.w;
  }
  __syncthreads();
  const int l = t >> 2, cq = t & 3;
  u16x8 hv0, hv1, lv0, lv1;
  #pragma unroll
  for (int i = 0; i < 16; i++) {
    unsigned int p = splitpack(st[cq * 16 + i][l]);
    if (i < 8) { hv0[i] = (unsigned short)(p & 0xFFFFu); lv0[i] = (unsigned short)(p >> 16); }
    else       { hv1[i-8] = (unsigned short)(p & 0xFFFFu); lv1[i-8] = (unsigned short)(p >> 16); }
  }
  size_t o = ((size_t)b * L + lb + l) * C + c0 + cq * 16;
  *(u16x8*)&XThi[o]     = hv0;
  *(u16x8*)&XThi[o + 8] = hv1;
  *(u16x8*)&XTlo[o]     = lv0;
  *(u16x8*)&XTlo[o + 8] = lv1;
}

// ---------------- split-bf16 MFMA GEMM, global_load_lds staging ----------------
// D[l][o] = sum_k A[l][k]*W[o][k]; A,B as separate hi/lo bf16 planes, K contiguous.
// EPI: 0 = store fp32 transposed [b][o][L]
//      1 = +bias, store hi/lo [b][l][o]
//      2 = gelu(acc+bias)*extra, store hi/lo
//      3 = acc+bias+extra, store hi/lo
template<int KTOT, int EPI>
__global__ __launch_bounds__(256) void mgemm(
    const unsigned short* __restrict__ Ahi_g, const unsigned short* __restrict__ Alo_g,
    const unsigned short* __restrict__ Bhi_g, const unsigned short* __restrict__ Blo_g,
    float* __restrict__ outF,
    unsigned short* __restrict__ outH, unsigned short* __restrict__ outLo,
    const float* __restrict__ bias,
    const unsigned short* __restrict__ extraH, const unsigned short* __restrict__ extraLo,
    int Ntot)
{
  __shared__ unsigned short Ah[128 * 32];
  __shared__ unsigned short Al[128 * 32];
  __shared__ unsigned short Bh[128 * 32];
  __shared__ unsigned short Bl[128 * 32];
  const int t  = threadIdx.x;
  const int lb = blockIdx.x * 128;
  const int o0 = blockIdx.y * 128;
  const int b  = blockIdx.z;
  const int w  = t >> 6, lane = t & 63;
  const int wm = w >> 1, wn = w & 1;
  const int ln = lane & 15, lg = lane >> 4;
  const int lrow  = lane >> 2;                       // staging: row within 16-row group
  const int chunk = (lane & 3) ^ ((lane >> 4) & 3);  // pre-swizzled global source chunk
  const int slot  = lg ^ (ln >> 2);                  // swizzled read slot

  f32x4 z4 = {0.f, 0.f, 0.f, 0.f};
  f32x4 acc[4][4];
  #pragma unroll
  for (int i = 0; i < 4; i++)
    #pragma unroll
    for (int j = 0; j < 4; j++) acc[i][j] = z4;

  const size_t arow0 = (size_t)b * L + lb;
  for (int kt = 0; kt < KTOT / 32; ++kt) {
    const int k0 = kt * 32;
    #pragma unroll
    for (int i = 0; i < 2; i++) {
      const int rb = w * 32 + i * 16;
      const size_t ga = (arow0 + rb + lrow) * KTOT + k0 + chunk * 8;
      gl16(Ahi_g + ga, &Ah[rb * 32]);
      gl16(Alo_g + ga, &Al[rb * 32]);
      const size_t gb = (size_t)(o0 + rb + lrow) * KTOT + k0 + chunk * 8;
      gl16(Bhi_g + gb, &Bh[rb * 32]);
      gl16(Blo_g + gb, &Bl[rb * 32]);
    }
    __syncthreads();
    short8v bhf[4], blf[4];
    #pragma unroll
    for (int nf = 0; nf < 4; nf++) {
      const int off = (wn * 64 + nf * 16 + ln) * 32 + slot * 8;
      bhf[nf] = *(const short8v*)&Bh[off];
      blf[nf] = *(const short8v*)&Bl[off];
    }
    #pragma unroll
    for (int mf = 0; mf < 4; mf++) {
      const int off = (wm * 64 + mf * 16 + ln) * 32 + slot * 8;
      const short8v ah = *(const short8v*)&Ah[off];
      const short8v al = *(const short8v*)&Al[off];
      #pragma unroll
      for (int nf = 0; nf < 4; nf++) {
        acc[mf][nf] = __builtin_amdgcn_mfma_f32_16x16x32_bf16(ah, bhf[nf], acc[mf][nf], 0, 0, 0);
        acc[mf][nf] = __builtin_amdgcn_mfma_f32_16x16x32_bf16(ah, blf[nf], acc[mf][nf], 0, 0, 0);
        acc[mf][nf] = __builtin_amdgcn_mfma_f32_16x16x32_bf16(al, bhf[nf], acc[mf][nf], 0, 0, 0);
      }
    }
    __syncthreads();
  }
  #pragma unroll
  for (int mf = 0; mf < 4; mf++) {
    const int mbase = lb + wm * 64 + mf * 16 + lg * 4;
    #pragma unroll
    for (int nf = 0; nf < 4; nf++) {
      const int o = o0 + wn * 64 + nf * 16 + ln;
      if (EPI == 0) {
        float4 r;
        r.x = acc[mf][nf][0]; r.y = acc[mf][nf][1];
        r.z = acc[mf][nf][2]; r.w = acc[mf][nf][3];
        *(float4*)&outF[((size_t)b * Ntot + o) * L + mbase] = r;
      } else {
        const float bv = bias ? bias[o] : 0.0f;
        #pragma unroll
        for (int r = 0; r < 4; r++) {
          const size_t idx = ((size_t)b * L + mbase + r) * Ntot + o;
          float v = acc[mf][nf][r] + bv;
          if (EPI == 2) { v = gelu_exact(v) * (bf16_tof(extraH[idx]) + bf16_tof(extraLo[idx])); }
          if (EPI == 3) { v = v + bf16_tof(extraH[idx]) + bf16_tof(extraLo[idx]); }
          const unsigned int p = splitpack(v);
          outH[idx]  = (unsigned short)(p & 0xFFFFu);
          outLo[idx] = (unsigned short)(p >> 16);
        }
      }
    }
  }
}

// ---------------- depthwise 3x3 conv + split-pack + channel stats ----------------
__global__ __launch_bounds__(256) void dwconv2_kernel(
    const float* __restrict__ in, const float* __restrict__ wdw,
    unsigned short* __restrict__ qkSh, unsigned short* __restrict__ qkSl,
    float* __restrict__ vbuf,
    float* __restrict__ csum, float* __restrict__ csumsq)
{
  __shared__ float p[64][65];
  __shared__ float rs[4][2];
  const int ch = blockIdx.x;
  const int b  = blockIdx.y;
  const int t  = threadIdx.x;
  const size_t base = ((size_t)b * OC3 + ch) * L;
  float wt[9];
  #pragma unroll
  for (int j = 0; j < 9; j++) wt[j] = wdw[ch * 9 + j];
  #pragma unroll
  for (int i = 0; i < 4; i++) {
    int pix = (i * 256 + t) * 4;
    const float4 v = *reinterpret_cast<const float4*>(&in[base + pix]);
    int h = pix >> 6, ww = pix & 63;
    p[h][ww] = v.x; p[h][ww+1] = v.y; p[h][ww+2] = v.z; p[h][ww+3] = v.w;
  }
  __syncthreads();
  float s = 0.f, s2 = 0.f;
  #pragma unroll
  for (int i = 0; i < 16; i++) {
    int pix = i * 256 + t;
    int h = pix >> 6, ww = pix & 63;
    float acc = 0.0f;
    #pragma unroll
    for (int ky = 0; ky < 3; ky++) {
      int hh = h + ky - 1;
      if (hh < 0 || hh > 63) continue;
      #pragma unroll
      for (int kx = 0; kx < 3; kx++) {
        int cc = ww + kx - 1;
        if (cc < 0 || cc > 63) continue;
        acc = fmaf(p[hh][cc], wt[ky * 3 + kx], acc);
      }
    }
    if (ch < 512) {
      const size_t qi = ((size_t)b * 512 + ch) * L + pix;
      const unsigned int pk = splitpack(acc);
      qkSh[qi] = (unsigned short)(pk & 0xFFFFu);
      qkSl[qi] = (unsigned short)(pk >> 16);
      s += acc;
      s2 = fmaf(acc, acc, s2);
    } else {
      vbuf[((size_t)b * 256 + (ch - 512)) * L + pix] = acc;
    }
  }
  if (ch < 512) {
    s = wave_sum(s); s2 = wave_sum(s2);
    const int lane = t & 63, wid = t >> 6;
    if (lane == 0) { rs[wid][0] = s; rs[wid][1] = s2; }
    __syncthreads();
    if (t == 0) {
      csum[b * 512 + ch]   = rs[0][0] + rs[1][0] + rs[2][0] + rs[3][0];
      csumsq[b * 512 + ch] = rs[0][1] + rs[1][1] + rs[2][1] + rs[3][1];
    }
  }
}

// ---------------- stable descending rank over q-channel sums ----------------
__global__ __launch_bounds__(256) void rank_kernel(const float* __restrict__ csum,
                                                   int* __restrict__ order)
{
  const int c = threadIdx.x;
  float key = 0.f;
  #pragma unroll
  for (int b = 0; b < 8; b++) key += csum[b * 512 + c];
  __shared__ float keys[256];
  keys[c] = key;
  __syncthreads();
  int rank = 0;
  for (int j = 0; j < 256; j++) {
    float kj = keys[j];
    rank += (kj > key) || (kj == key && j < c);
  }
  order[rank] = c;
}

// ---------------- relabel stats into sorted order ----------------
__global__ __launch_bounds__(256) void stats_kernel(
    const float* __restrict__ csum, const float* __restrict__ csumsq,
    const int* __restrict__ order,
    float* __restrict__ sumq, float* __restrict__ sumk,
    float* __restrict__ invnq, float* __restrict__ invnk)
{
  const int b = blockIdx.x, r = threadIdx.x;
  const int ch = order[r];
  sumq[b * 256 + r]  = csum[b * 512 + ch];
  invnq[b * 256 + r] = 1.0f / fmaxf(sqrtf(csumsq[b * 512 + ch]), 1e-12f);
  sumk[b * 256 + r]  = csum[b * 512 + 256 + ch];
  invnk[b * 256 + r] = 1.0f / fmaxf(sqrtf(csumsq[b * 512 + 256 + ch]), 1e-12f);
}

// ---------------- pack: vTS = split(v^T sorted) [b][l][r]; zqT = split(qn+kn) [b][l][r] ----------------
__global__ __launch_bounds__(256) void vpack_kernel(
    const float* __restrict__ vbuf,
    const unsigned short* __restrict__ qkSh, const unsigned short* __restrict__ qkSl,
    const int* __restrict__ order,
    const float* __restrict__ invnq, const float* __restrict__ invnk,
    unsigned short* __restrict__ vTSh, unsigned short* __restrict__ vTSl,
    unsigned short* __restrict__ zqTh, unsigned short* __restrict__ zqTl)
{
  __shared__ float vt[64][65];
  __shared__ float zt[64][65];
  __shared__ int   ordS[256];
  __shared__ float iqS[256], ikS[256];
  const int t = threadIdx.x, lb = blockIdx.x * 64, b = blockIdx.y;
  ordS[t] = order[t];
  iqS[t] = invnq[b * 256 + t];
  ikS[t] = invnk[b * 256 + t];
  __syncthreads();
  for (int cc = 0; cc < 4; cc++) {
    const int r0 = cc * 64;
    for (int i = t; i < 1024; i += 256) {
      const int row = i >> 4, q = i & 15;
      const int ch = ordS[r0 + row];
      const float iq = iqS[r0 + row], ik = ikS[r0 + row];
      const float4 v4 = *(const float4*)&vbuf[((size_t)b * 256 + ch) * L + lb + q * 4];
      vt[q*4+0][row] = v4.x; vt[q*4+1][row] = v4.y; vt[q*4+2][row] = v4.z; vt[q*4+3][row] = v4.w;
      const size_t qi = ((size_t)b * 512 + ch) * L + lb + q * 4;
      const size_t ki = ((size_t)b * 512 + 256 + ch) * L + lb + q * 4;
      const ushort4 qh4 = *(const ushort4*)&qkSh[qi];
      const ushort4 ql4 = *(const ushort4*)&qkSl[qi];
      const ushort4 kh4 = *(const ushort4*)&qkSh[ki];
      const ushort4 kl4 = *(const ushort4*)&qkSl[ki];
      zt[q*4+0][row] = (bf16_tof(qh4.x)+bf16_tof(ql4.x))*iq + (bf16_tof(kh4.x)+bf16_tof(kl4.x))*ik;
      zt[q*4+1][row] = (bf16_tof(qh4.y)+bf16_tof(ql4.y))*iq + (bf16_tof(kh4.y)+bf16_tof(kl4.y))*ik;
      zt[q*4+2][row] = (bf16_tof(qh4.z)+bf16_tof(ql4.z))*iq + (bf16_tof(kh4.z)+bf16_tof(kl4.z))*ik;
      zt[q*4+3][row] = (bf16_tof(qh4.w)+bf16_tof(ql4.w))*iq + (bf16_tof(kh4.w)+bf16_tof(kl4.w))*ik;
    }
    __syncthreads();
    const int l = t >> 2, qq = t & 3;
    const size_t ob = ((size_t)b * L + lb + l) * 256 + r0 + qq * 16;
    #pragma unroll
    for (int j = 0; j < 4; j++) {
      ushort4 vh, vl, zh, zl;
      unsigned int p;
      p = splitpack(vt[l][qq*16 + j*4 + 0]); vh.x = p & 0xFFFFu; vl.x = p >> 16;
      p = splitpack(vt[l][qq*16 + j*4 + 1]); vh.y = p & 0xFFFFu; vl.y = p >> 16;
      p = splitpack(vt[l][qq*16 + j*4 + 2]); vh.z = p & 0xFFFFu; vl.z = p >> 16;
      p = splitpack(vt[l][qq*16 + j*4 + 3]); vh.w = p & 0xFFFFu; vl.w = p >> 16;
      p = splitpack(zt[l][qq*16 + j*4 + 0]); zh.x = p & 0xFFFFu; zl.x = p >> 16;
      p = splitpack(zt[l][qq*16 + j*4 + 1]); zh.y = p & 0xFFFFu; zl.y = p >> 16;
      p = splitpack(zt[l][qq*16 + j*4 + 2]); zh.z = p & 0xFFFFu; zl.z = p >> 16;
      p = splitpack(zt[l][qq*16 + j*4 + 3]); zh.w = p & 0xFFFFu; zl.w = p >> 16;
      *(ushort4*)&vTSh[ob + j*4] = vh;
      *(ushort4*)&vTSl[ob + j*4] = vl;
      *(ushort4*)&zqTh[ob + j*4] = zh;
      *(ushort4*)&zqTl[ob + j*4] = zl;
    }
    __syncthreads();
  }
}

// ---------------- scores via MFMA with global_load_lds gather staging ----------------
template<int G, int GI, int START, int MB, int SPB>
__device__ void scores_body(const unsigned short* __restrict__ qkSh,
    const unsigned short* __restrict__ qkSl,
    const int* __restrict__ order, float* __restrict__ Spart,
    unsigned short* Ah, unsigned short* Al, unsigned short* Bh, unsigned short* Bl,
    int* ordS)
{
  constexpr int MR = (G - MB * 64 < 64) ? (G - MB * 64) : 64;
  constexpr int NF = G / 16;
  const int t = threadIdx.x, ks = blockIdx.x, b = blockIdx.y;
  const int w = t >> 6, lane = t & 63, ln = lane & 15, lg = lane >> 4;
  const int lrow  = lane >> 2;
  const int chunk = (lane & 3) ^ ((lane >> 4) & 3);
  const int slot  = lg ^ (ln >> 2);
  for (int i = t; i < G; i += 256) ordS[i] = order[START + i];
  __syncthreads();
  const int k0 = ks * 512;
  const bool act = (w * 16) < MR;
  f32x4 z4 = {0.f, 0.f, 0.f, 0.f};
  f32x4 acc[NF];
  #pragma unroll
  for (int i = 0; i < NF; i++) acc[i] = z4;
  for (int kc = 0; kc < 512; kc += 32) {
    for (int i = w; i < MR / 16; i += 4) {
      const int rb = i * 16;
      const int ch = ordS[MB * 64 + rb + lrow];
      const size_t g = ((size_t)b * 512 + ch) * L + k0 + kc + chunk * 8;
      gl16(qkSh + g, &Ah[rb * 32]);
      gl16(qkSl + g, &Al[rb * 32]);
    }
    for (int i = w; i < G / 16; i += 4) {
      const int rb = i * 16;
      const int ch = 256 + ordS[rb + lrow];
      const size_t g = ((size_t)b * 512 + ch) * L + k0 + kc + chunk * 8;
      gl16(qkSh + g, &Bh[rb * 32]);
      gl16(qkSl + g, &Bl[rb * 32]);
    }
    __syncthreads();
    if (act) {
      const int aoff = (w * 16 + ln) * 32 + slot * 8;
      const short8v ah = *(const short8v*)&Ah[aoff];
      const short8v al = *(const short8v*)&Al[aoff];
      #pragma unroll
      for (int nf = 0; nf < NF; nf++) {
        const int boff = (nf * 16 + ln) * 32 + slot * 8;
        const short8v bh = *(const short8v*)&Bh[boff];
        const short8v bl = *(const short8v*)&Bl[boff];
        acc[nf] = __builtin_amdgcn_mfma_f32_16x16x32_bf16(ah, bh, acc[nf], 0, 0, 0);
        acc[nf] = __builtin_amdgcn_mfma_f32_16x16x32_bf16(ah, bl, acc[nf], 0, 0, 0);
        acc[nf] = __builtin_amdgcn_mfma_f32_16x16x32_bf16(al, bh, acc[nf], 0, 0, 0);
      }
    }
    __syncthreads();
  }
  if (act) {
    float* dst = Spart + (size_t)b * 147456 + SPB + ks * G * G;
    #pragma unroll
    for (int nf = 0; nf < NF; nf++) {
      const int d = nf * 16 + ln;
      #pragma unroll
      for (int r = 0; r < 4; r++) {
        const int m = MB * 64 + w * 16 + lg * 4 + r;
        dst[m * G + d] = acc[nf][r];
      }
    }
  }
}

__global__ __launch_bounds__(256) void scores_kernel(const unsigned short* __restrict__ qkSh,
    const unsigned short* __restrict__ qkSl,
    const int* __restrict__ order, float* __restrict__ Spart)
{
  __shared__ unsigned short Ah[64 * 32];
  __shared__ unsigned short Al[64 * 32];
  __shared__ unsigned short Bh[96 * 32];
  __shared__ unsigned short Bl[96 * 32];
  __shared__ int ordS[96];
  switch (blockIdx.z) {
    case 0:  scores_body<32, 0, 0,   0, 0    >(qkSh, qkSl, order, Spart, Ah, Al, Bh, Bl, ordS); break;
    case 1:  scores_body<64, 1, 32,  0, 8192 >(qkSh, qkSl, order, Spart, Ah, Al, Bh, Bl, ordS); break;
    case 2:  scores_body<64, 2, 96,  0, 40960>(qkSh, qkSl, order, Spart, Ah, Al, Bh, Bl, ordS); break;
    case 3:  scores_body<96, 3, 160, 0, 73728>(qkSh, qkSl, order, Spart, Ah, Al, Bh, Bl, ordS); break;
    default: scores_body<96, 3, 160, 1, 73728>(qkSh, qkSl, order, Spart, Ah, Al, Bh, Bl, ordS); break;
  }
}

// ---------------- reduce partials, scale, softmax, emit split hi/lo attn ----------------
template<int G, int GI, int START, int SPB, int AOFF>
__device__ void softmax_body(const float* __restrict__ Spart, const float* __restrict__ invnq,
    const float* __restrict__ invnk, const float* __restrict__ temperature,
    unsigned short* __restrict__ attnPh, unsigned short* __restrict__ attnPl, float* Sm)
{
  const int t = threadIdx.x;
  const int b = blockIdx.x;
  const float temp = temperature[GI];
  for (int idx = t; idx < G * G; idx += 256) {
    float s = 0.f;
    #pragma unroll
    for (int ks = 0; ks < 8; ks++)
      s += Spart[(size_t)b * 147456 + SPB + ks * G * G + idx];
    const int c = idx / G, d = idx - c * G;
    Sm[idx] = s * invnq[b * 256 + START + c] * invnk[b * 256 + START + d] * temp;
  }
  __syncthreads();
  for (int r = t; r < G; r += 256) {
    float m = -INFINITY;
    for (int d = 0; d < G; d++) m = fmaxf(m, Sm[r * G + d]);
    float sum = 0.f;
    for (int d = 0; d < G; d++) { float e = expf(Sm[r * G + d] - m); Sm[r * G + d] = e; sum += e; }
    const float inv = 1.0f / sum;
    const size_t base = (size_t)b * 18432 + AOFF + r * G;
    for (int d = 0; d < G; d++) {
      const unsigned int p = splitpack(Sm[r * G + d] * inv);
      attnPh[base + d] = (unsigned short)(p & 0xFFFFu);
      attnPl[base + d] = (unsigned short)(p >> 16);
    }
  }
}

__global__ __launch_bounds__(256) void softmax_kernel(const float* __restrict__ Spart,
    const float* __restrict__ invnq, const float* __restrict__ invnk,
    const float* __restrict__ temperature,
    unsigned short* __restrict__ attnPh, unsigned short* __restrict__ attnPl)
{
  extern __shared__ float smem[];
  switch (blockIdx.y) {
    case 0:  softmax_body<32, 0, 0,   0,     0   >(Spart, invnq, invnk, temperature, attnPh, attnPl, smem); break;
    case 1:  softmax_body<64, 1, 32,  8192,  1024>(Spart, invnq, invnk, temperature, attnPh, attnPl, smem); break;
    case 2:  softmax_body<64, 2, 96,  40960, 5120>(Spart, invnq, invnk, temperature, attnPh, attnPl, smem); break;
    default: softmax_body<96, 3, 160, 73728, 9216>(Spart, invnq, invnk, temperature, attnPh, attnPl, smem); break;
  }
}

// ---------------- PV via MFMA, global_load_lds staging, fused z epilogue ----------------
template<int G, int GI, int START, int AOFF>
__device__ void pv_body(
    const unsigned short* __restrict__ vTSh, const unsigned short* __restrict__ vTSl,
    const unsigned short* __restrict__ attnPh, const unsigned short* __restrict__ attnPl,
    const unsigned short* __restrict__ zqTh, const unsigned short* __restrict__ zqTl,
    unsigned short* __restrict__ outTh, unsigned short* __restrict__ outTl,
    unsigned short* __restrict__ zTh, unsigned short* __restrict__ zTl,
    unsigned short* Ah, unsigned short* Al, unsigned short* Bh, unsigned short* Bl)
{
  constexpr int NF = G / 16;
  const int t = threadIdx.x, b = blockIdx.y, l0 = blockIdx.x * 128;
  const int w = t >> 6, lane = t & 63, ln = lane & 15, lg = lane >> 4;
  const int lrow  = lane >> 2;
  const int chunk = (lane & 3) ^ ((lane >> 4) & 3);
  const int slot  = lg ^ (ln >> 2);
  f32x4 z4 = {0.f, 0.f, 0.f, 0.f};
  f32x4 acc[2][NF];
  #pragma unroll
  for (int i = 0; i < 2; i++)
    #pragma unroll
    for (int j = 0; j < NF; j++) acc[i][j] = z4;
  for (int kc = 0; kc < G; kc += 32) {
    #pragma unroll
    for (int i = 0; i < 2; i++) {
      const int rb = w * 32 + i * 16;
      const size_t g = ((size_t)b * L + l0 + rb + lrow) * 256 + START + kc + chunk * 8;
      gl16(vTSh + g, &Ah[rb * 32]);
      gl16(vTSl + g, &Al[rb * 32]);
    }
    for (int i = w; i < G / 16; i += 4) {
      const int rb = i * 16;
      const size_t g = (size_t)b * 18432 + AOFF + (size_t)(rb + lrow) * G + kc + chunk * 8;
      gl16(attnPh + g, &Bh[rb * 32]);
      gl16(attnPl + g, &Bl[rb * 32]);
    }
    __syncthreads();
    short8v bhf[NF], blf[NF];
    #pragma unroll
    for (int nf = 0; nf < NF; nf++) {
      const int boff = (nf * 16 + ln) * 32 + slot * 8;
      bhf[nf] = *(const short8v*)&Bh[boff];
      blf[nf] = *(const short8v*)&Bl[boff];
    }
    #pragma unroll
    for (int mi = 0; mi < 2; mi++) {
      const int aoff = ((w * 2 + mi) * 16 + ln) * 32 + slot * 8;
      const short8v ah = *(const short8v*)&Ah[aoff];
      const short8v al = *(const short8v*)&Al[aoff];
      #pragma unroll
      for (int nf = 0; nf < NF; nf++) {
        acc[mi][nf] = __builtin_amdgcn_mfma_f32_16x16x32_bf16(ah, bhf[nf], acc[mi][nf], 0, 0, 0);
        acc[mi][nf] = __builtin_amdgcn_mfma_f32_16x16x32_bf16(ah, blf[nf], acc[mi][nf], 0, 0, 0);
        acc[mi][nf] = __builtin_amdgcn_mfma_f32_16x16x32_bf16(al, bhf[nf], acc[mi][nf], 0, 0, 0);
      }
    }
    __syncthreads();
  }
  #pragma unroll
  for (int mi = 0; mi < 2; mi++) {
    const int lbase = l0 + (w * 2 + mi) * 16 + lg * 4;
    #pragma unroll
    for (int nf = 0; nf < NF; nf++) {
      const int col = START + nf * 16 + ln;
      #pragma unroll
      for (int r = 0; r < 4; r++) {
        const size_t idx = ((size_t)b * L + lbase + r) * 256 + col;
        const float v = acc[mi][nf][r];
        const unsigned int po = splitpack(v);
        outTh[idx] = (unsigned short)(po & 0xFFFFu);
        outTl[idx] = (unsigned short)(po >> 16);
        const float zq = bf16_tof(zqTh[idx]) + bf16_tof(zqTl[idx]);
        const unsigned int pz = splitpack(v + zq);
        zTh[idx] = (unsigned short)(pz & 0xFFFFu);
        zTl[idx] = (unsigned short)(pz >> 16);
      }
    }
  }
}

__global__ __launch_bounds__(256) void pv_kernel(
    const unsigned short* __restrict__ vTSh, const unsigned short* __restrict__ vTSl,
    const unsigned short* __restrict__ attnPh, const unsigned short* __restrict__ attnPl,
    const unsigned short* __restrict__ zqTh, const unsigned short* __restrict__ zqTl,
    unsigned short* __restrict__ outTh, unsigned short* __restrict__ outTl,
    unsigned short* __restrict__ zTh, unsigned short* __restrict__ zTl)
{
  __shared__ unsigned short Ah[128 * 32];
  __shared__ unsigned short Al[128 * 32];
  __shared__ unsigned short Bh[96 * 32];
  __shared__ unsigned short Bl[96 * 32];
  switch (blockIdx.z) {
    case 0:  pv_body<32, 0, 0,   0   >(vTSh, vTSl, attnPh, attnPl, zqTh, zqTl, outTh, outTl, zTh, zTl, Ah, Al, Bh, Bl); break;
    case 1:  pv_body<64, 1, 32,  1024>(vTSh, vTSl, attnPh, attnPl, zqTh, zqTl, outTh, outTl, zTh, zTl, Ah, Al, Bh, Bl); break;
    case 2:  pv_body<64, 2, 96,  5120>(vTSh, vTSl, attnPh, attnPl, zqTh, zqTl, outTh, outTl, zTh, zTl, Ah, Al, Bh, Bl); break;
    default: pv_body<96, 3, 160, 9216>(vTSh, vTSl, attnPh, attnPl, zqTh, zqTl, outTh, outTl, zTh, zTl, Ah, Al, Bh, Bl); break;
  }
}

// ---------------- qv_cache ----------------
__global__ __launch_bounds__(256) void qv_kernel(const float* __restrict__ sumq,
    const float* __restrict__ sumk, const float* __restrict__ invnq,
    const float* __restrict__ invnk, float* __restrict__ out2)
{
  const int b = blockIdx.x >> 8, r = blockIdx.x & 255;
  float val = 0.f;
  {
    const int idx = b * 256 + 0 + (r & 31);
    val += fmaf(sumq[idx], invnq[idx], sumk[idx] * invnk[idx]);
  }
  {
    const int idx = b * 256 + 32 + (r & 63);
    val += fmaf(sumq[idx], invnq[idx], sumk[idx] * invnk[idx]);
  }
  {
    const int idx = b * 256 + 96 + (r & 63);
    val += fmaf(sumq[idx], invnq[idx], sumk[idx] * invnk[idx]);
  }
  if (r < 192) {
    const int rm = (r < 96) ? r : r - 96;
    const int idx = b * 256 + 160 + rm;
    val += fmaf(sumq[idx], invnq[idx], sumk[idx] * invnk[idx]);
  }
  val *= (1.0f / 4096.f) * 0.25f * 0.9f;
  const float4 o = {val, val, val, val};
  float4* dst = reinterpret_cast<float4*>(out2 + ((size_t)b * C + r) * L);
  for (int i = threadIdx.x; i < 1024; i += 256) dst[i] = o;
}

// ---------------- launch ----------------
extern "C" void kernel_launch(void* const* d_in, const int* in_sizes, int n_in,
                              void* d_out, int out_size, void* d_ws, size_t ws_size,
                              hipStream_t stream)
{
  const float* x           = (const float*)d_in[0];
  const float* temperature = (const float*)d_in[1];
  const float* w_qkv       = (const float*)d_in[2];
  const float* w_dw        = (const float*)d_in[3];
  const float* w_proj      = (const float*)d_in[4];
  const float* w_gate      = (const float*)d_in[5];
  const float* b_gate      = (const float*)d_in[6];
  const float* w_down      = (const float*)d_in[7];
  const float* b_down      = (const float*)d_in[8];
  const float* w_up        = (const float*)d_in[9];
  const float* b_up        = (const float*)d_in[10];

  if (ws_size < 202548224ULL) return;

  char* ws = (char*)d_ws;
  // Region A [0, 96M):
  float*          qkv_pre  = (float*)(ws);                        // 96MB, dead after dwconv
  unsigned short* vTSh     = (unsigned short*)(ws);                // 16MB
  unsigned short* vTSl     = (unsigned short*)(ws + 16777216);     // 16MB
  unsigned short* zqTh     = (unsigned short*)(ws + 33554432);     // 16MB
  unsigned short* zqTl     = (unsigned short*)(ws + 50331648);     // 16MB
  float*          Spart    = (float*)(ws + 67108864);              // 4.72MB
  unsigned short* attnPh   = (unsigned short*)(ws + 73400320);     // 288KB
  unsigned short* attnPl   = (unsigned short*)(ws + 74448896);     // 288KB
  unsigned short* preprojh = (unsigned short*)(ws);                // 16MB (after pv)
  unsigned short* preprojl = (unsigned short*)(ws + 16777216);     // 16MB
  // Region B [96M, 192M):
  unsigned short* XThi     = (unsigned short*)(ws + 100663296);    // 16MB
  unsigned short* XTlo     = (unsigned short*)(ws + 117440512);    // 16MB
  unsigned short* WqkvHi   = (unsigned short*)(ws + 134217728);    // 384KB
  unsigned short* WqkvLo   = (unsigned short*)(ws + 134610944);    // 384KB
  unsigned short* qkSh     = (unsigned short*)(ws + 100663296);    // 32MB (after qkv gemm)
  unsigned short* qkSl     = (unsigned short*)(ws + 134217728);    // 32MB
  float*          vbuf     = (float*)(ws + 167772160);             // 32MB
  unsigned short* outTh    = (unsigned short*)(ws + 100663296);    // 16MB (after scores)
  unsigned short* outTl    = (unsigned short*)(ws + 117440512);    // 16MB
  unsigned short* zTh      = (unsigned short*)(ws + 134217728);    // 16MB
  unsigned short* zTl      = (unsigned short*)(ws + 150994944);    // 16MB
  unsigned short* gatedh   = (unsigned short*)(ws + 167772160);    // 16MB (after vpack)
  unsigned short* gatedl   = (unsigned short*)(ws + 184549376);    // 16MB
  unsigned short* midh     = (unsigned short*)(ws + 134217728);    // 8MB (after gate gemm)
  unsigned short* midl     = (unsigned short*)(ws + 142606336);    // 8MB
  // Region C [192M, 193.2M):
  unsigned short* WmlpHi = (unsigned short*)(ws + 201326592);      // 384KB
  unsigned short* WmlpLo = (unsigned short*)(ws + 201719808);      // 384KB
  float* csum   = (float*)(ws + 202113024);
  float* csumsq = (float*)(ws + 202129408);
  float* sumq   = (float*)(ws + 202145792);
  float* sumk   = (float*)(ws + 202153984);
  float* invnq  = (float*)(ws + 202162176);
  float* invnk  = (float*)(ws + 202170368);
  int*   order  = (int*)(ws + 202178560);

  float* out_all = (float*)d_out;
  float* qv_out  = out_all + (size_t)B * C * L;

  // 0. weight + input splits
  wsplit_kernel<<<1536, 256, 0, stream>>>(w_qkv, w_gate, w_down, w_up, w_proj,
                                          WqkvHi, WqkvLo, WmlpHi, WmlpLo);
  splitx_kernel<<<dim3(64, 4, 8), 256, 0, stream>>>(x, XThi, XTlo);
  // 1. qkv = w_qkv @ x  (MFMA, out fp32 [b][768][L])
  mgemm<256, 0><<<dim3(32, 6, 8), 256, 0, stream>>>(
      XThi, XTlo, WqkvHi, WqkvLo, qkv_pre, nullptr, nullptr, nullptr, nullptr, nullptr, 768);
  // 2. depthwise conv (+ split-pack q,k hi/lo; v fp32; channel stats)
  dwconv2_kernel<<<dim3(768, 8), 256, 0, stream>>>(qkv_pre, w_dw, qkSh, qkSl, vbuf, csum, csumsq);
  // 3. channel ordering + stats relabel
  rank_kernel<<<1, 256, 0, stream>>>(csum, order);
  stats_kernel<<<8, 256, 0, stream>>>(csum, csumsq, order, sumq, sumk, invnq, invnk);
  // 4. pack v^T + zq (hi/lo)
  vpack_kernel<<<dim3(64, 8), 256, 0, stream>>>(vbuf, qkSh, qkSl, order, invnq, invnk,
                                                vTSh, vTSl, zqTh, zqTl);
  // 5. attention
  scores_kernel<<<dim3(8, 8, 5), 256, 0, stream>>>(qkSh, qkSl, order, Spart);
  softmax_kernel<<<dim3(8, 4), 256, 36864, stream>>>(Spart, invnq, invnk, temperature, attnPh, attnPl);
  pv_kernel<<<dim3(32, 8, 4), 256, 0, stream>>>(vTSh, vTSl, attnPh, attnPl, zqTh, zqTl,
                                                outTh, outTl, zTh, zTl);
  // 6. MLP chain
  mgemm<256, 2><<<dim3(32, 2, 8), 256, 0, stream>>>(
      zTh, zTl, WmlpHi, WmlpLo, nullptr, gatedh, gatedl, b_gate, zTh, zTl, 256);
  mgemm<256, 1><<<dim3(32, 1, 8), 256, 0, stream>>>(
      gatedh, gatedl, WmlpHi + 65536, WmlpLo + 65536, nullptr, midh, midl, b_down, nullptr, nullptr, 128);
  mgemm<128, 3><<<dim3(32, 2, 8), 256, 0, stream>>>(
      midh, midl, WmlpHi + 98304, WmlpLo + 98304, nullptr, preprojh, preprojl, b_up, outTh, outTl, 256);
  // 7. final projection -> output 0
  mgemm<256, 0><<<dim3(32, 2, 8), 256, 0, stream>>>(
      preprojh, preprojl, WmlpHi + 131072, WmlpLo + 131072, out_all, nullptr, nullptr, nullptr, nullptr, nullptr, 256);
  // 8. qv_cache -> output 1
  qv_kernel<<<2048, 256, 0, stream>>>(sumq, sumk, invnq, invnk, qv_out);
}

// Round 5
// 337.841 us; speedup vs baseline: 1.7768x; 1.0261x over previous
//
#include <hip/hip_runtime.h>
#include <math.h>

#define B 8
#define C 256
#define L 4096
#define OC3 768

typedef __attribute__((ext_vector_type(8))) short short8v;
typedef __attribute__((ext_vector_type(8))) unsigned short u16x8;
typedef __attribute__((ext_vector_type(4))) float f32x4;

// ---------------- helpers ----------------
__device__ __forceinline__ float gelu_exact(float x){
  return 0.5f * x * (1.0f + erff(x * 0.70710678118654752440f));
}
__device__ __forceinline__ float wave_sum(float v){
  #pragma unroll
  for (int off = 32; off > 0; off >>= 1) v += __shfl_down(v, off, 64);
  return v;
}
__device__ __forceinline__ unsigned short bf16_rne(float f){
  unsigned int u = __float_as_uint(f);
  unsigned int r = u + 0x7FFFu + ((u >> 16) & 1u);
  return (unsigned short)(r >> 16);
}
__device__ __forceinline__ float bf16_tof(unsigned short h){
  return __uint_as_float(((unsigned int)h) << 16);
}
// pack value as (hi, lo) bf16 pair in one u32: low16 = hi, high16 = lo
__device__ __forceinline__ unsigned int splitpack(float v){
  unsigned short hi = bf16_rne(v);
  float lof = v - bf16_tof(hi);
  unsigned short lo = bf16_rne(lof);
  return (unsigned int)hi | ((unsigned int)lo << 16);
}
// async global->LDS 16B per lane; LDS dest must be wave-uniform base
__device__ __forceinline__ void gl16(const unsigned short* g, unsigned short* l){
  __builtin_amdgcn_global_load_lds(
      (const __attribute__((address_space(1))) void*)g,
      (__attribute__((address_space(3))) void*)l, 16, 0, 0);
}

// ---------------- weight split: fp32 -> hi/lo bf16 ----------------
__global__ __launch_bounds__(256) void wsplit_kernel(
    const float* __restrict__ wqkv, const float* __restrict__ wgate,
    const float* __restrict__ wdown, const float* __restrict__ wup,
    const float* __restrict__ wproj,
    unsigned short* __restrict__ QH, unsigned short* __restrict__ QLo,
    unsigned short* __restrict__ MH, unsigned short* __restrict__ MLo)
{
  int idx = blockIdx.x * 256 + threadIdx.x;   // 0..393215
  if (idx < 196608) {
    unsigned int p = splitpack(wqkv[idx]);
    QH[idx] = (unsigned short)(p & 0xFFFFu); QLo[idx] = (unsigned short)(p >> 16);
  } else {
    int j = idx - 196608;
    float s;
    if (j < 65536)            s = wgate[j];
    else if (j < 98304)       s = wdown[j - 65536];
    else if (j < 131072)      s = wup[j - 98304];
    else                      s = wproj[j - 131072];
    unsigned int p = splitpack(s);
    MH[j] = (unsigned short)(p & 0xFFFFu); MLo[j] = (unsigned short)(p >> 16);
  }
}

// ---------------- x [b][c][l] fp32 -> xT hi/lo bf16 [b][l][c] ----------------
__global__ __launch_bounds__(256) void splitx_kernel(const float* __restrict__ x,
    unsigned short* __restrict__ XThi, unsigned short* __restrict__ XTlo)
{
  __shared__ float st[64][68];
  const int b = blockIdx.z, c0 = blockIdx.y * 64, lb = blockIdx.x * 64;
  const int t = threadIdx.x;
  #pragma unroll
  for (int i = 0; i < 4; i++) {
    int row = (t >> 4) + i * 16;
    int col = (t & 15) * 4;
    float4 v = *(const float4*)&x[((size_t)b * C + c0 + row) * L + lb + col];
    st[row][col] = v.x; st[row][col+1] = v.y; st[row][col+2] = v.z; st[row][col+3] = v.w;
  }
  __syncthreads();
  const int l = t >> 2, cq = t & 3;
  u16x8 hv0, hv1, lv0, lv1;
  #pragma unroll
  for (int i = 0; i < 16; i++) {
    unsigned int p = splitpack(st[cq * 16 + i][l]);
    if (i < 8) { hv0[i] = (unsigned short)(p & 0xFFFFu); lv0[i] = (unsigned short)(p >> 16); }
    else       { hv1[i-8] = (unsigned short)(p & 0xFFFFu); lv1[i-8] = (unsigned short)(p >> 16); }
  }
  size_t o = ((size_t)b * L + lb + l) * C + c0 + cq * 16;
  *(u16x8*)&XThi[o]     = hv0;
  *(u16x8*)&XThi[o + 8] = hv1;
  *(u16x8*)&XTlo[o]     = lv0;
  *(u16x8*)&XTlo[o + 8] = lv1;
}

// ---------------- split-bf16 MFMA GEMM, 2-phase double-buffered ----------------
// D[l][o] = sum_k A[l][k]*W[o][k]; A,B as separate hi/lo bf16 planes, K contiguous.
// EPI: 0 = store fp32 transposed [b][o][L]
//      1 = +bias, store hi/lo [b][l][o]
//      2 = gelu(acc+bias)*extra, store hi/lo
//      3 = acc+bias+extra, store hi/lo
template<int KTOT, int EPI>
__global__ __launch_bounds__(256) void mgemm(
    const unsigned short* __restrict__ Ahi_g, const unsigned short* __restrict__ Alo_g,
    const unsigned short* __restrict__ Bhi_g, const unsigned short* __restrict__ Blo_g,
    float* __restrict__ outF,
    unsigned short* __restrict__ outH, unsigned short* __restrict__ outLo,
    const float* __restrict__ bias,
    const unsigned short* __restrict__ extraH, const unsigned short* __restrict__ extraLo,
    int Ntot)
{
  __shared__ unsigned short SB[2][4][128 * 32];   // [buf][Ah,Al,Bh,Bl]
  const int t  = threadIdx.x;
  const int lb = blockIdx.x * 128;
  const int o0 = blockIdx.y * 128;
  const int b  = blockIdx.z;
  const int w  = t >> 6, lane = t & 63;
  const int wm = w >> 1, wn = w & 1;
  const int ln = lane & 15, lg = lane >> 4;
  const int lrow  = lane >> 2;                       // staging: row within 16-row group
  const int chunk = (lane & 3) ^ ((lane >> 4) & 3);  // pre-swizzled global source chunk
  const int slot  = lg ^ (ln >> 2);                  // swizzled read slot

  f32x4 z4 = {0.f, 0.f, 0.f, 0.f};
  f32x4 acc[4][4];
  #pragma unroll
  for (int i = 0; i < 4; i++)
    #pragma unroll
    for (int j = 0; j < 4; j++) acc[i][j] = z4;

  const size_t arow0 = (size_t)b * L + lb;
  constexpr int NKT = KTOT / 32;

  auto stage = [&](int kt, int cb) {
    const int k0 = kt * 32;
    #pragma unroll
    for (int i = 0; i < 2; i++) {
      const int rb = w * 32 + i * 16;
      const size_t ga = (arow0 + rb + lrow) * KTOT + k0 + chunk * 8;
      gl16(Ahi_g + ga, &SB[cb][0][rb * 32]);
      gl16(Alo_g + ga, &SB[cb][1][rb * 32]);
      const size_t gb = (size_t)(o0 + rb + lrow) * KTOT + k0 + chunk * 8;
      gl16(Bhi_g + gb, &SB[cb][2][rb * 32]);
      gl16(Blo_g + gb, &SB[cb][3][rb * 32]);
    }
  };

  stage(0, 0);
  __syncthreads();
  int cur = 0;
  for (int kt = 0; kt < NKT; ++kt) {
    if (kt + 1 < NKT) stage(kt + 1, cur ^ 1);
    short8v bhf[4], blf[4];
    #pragma unroll
    for (int nf = 0; nf < 4; nf++) {
      const int off = (wn * 64 + nf * 16 + ln) * 32 + slot * 8;
      bhf[nf] = *(const short8v*)&SB[cur][2][off];
      blf[nf] = *(const short8v*)&SB[cur][3][off];
    }
    #pragma unroll
    for (int mf = 0; mf < 4; mf++) {
      const int off = (wm * 64 + mf * 16 + ln) * 32 + slot * 8;
      const short8v ah = *(const short8v*)&SB[cur][0][off];
      const short8v al = *(const short8v*)&SB[cur][1][off];
      #pragma unroll
      for (int nf = 0; nf < 4; nf++) {
        acc[mf][nf] = __builtin_amdgcn_mfma_f32_16x16x32_bf16(ah, bhf[nf], acc[mf][nf], 0, 0, 0);
        acc[mf][nf] = __builtin_amdgcn_mfma_f32_16x16x32_bf16(ah, blf[nf], acc[mf][nf], 0, 0, 0);
        acc[mf][nf] = __builtin_amdgcn_mfma_f32_16x16x32_bf16(al, bhf[nf], acc[mf][nf], 0, 0, 0);
      }
    }
    __syncthreads();
    cur ^= 1;
  }
  #pragma unroll
  for (int mf = 0; mf < 4; mf++) {
    const int mbase = lb + wm * 64 + mf * 16 + lg * 4;
    #pragma unroll
    for (int nf = 0; nf < 4; nf++) {
      const int o = o0 + wn * 64 + nf * 16 + ln;
      if (EPI == 0) {
        float4 r;
        r.x = acc[mf][nf][0]; r.y = acc[mf][nf][1];
        r.z = acc[mf][nf][2]; r.w = acc[mf][nf][3];
        *(float4*)&outF[((size_t)b * Ntot + o) * L + mbase] = r;
      } else {
        const float bv = bias ? bias[o] : 0.0f;
        #pragma unroll
        for (int r = 0; r < 4; r++) {
          const size_t idx = ((size_t)b * L + mbase + r) * Ntot + o;
          float v = acc[mf][nf][r] + bv;
          if (EPI == 2) { v = gelu_exact(v) * (bf16_tof(extraH[idx]) + bf16_tof(extraLo[idx])); }
          if (EPI == 3) { v = v + bf16_tof(extraH[idx]) + bf16_tof(extraLo[idx]); }
          const unsigned int p = splitpack(v);
          outH[idx]  = (unsigned short)(p & 0xFFFFu);
          outLo[idx] = (unsigned short)(p >> 16);
        }
      }
    }
  }
}

// ---------------- depthwise 3x3 conv + split-pack + channel stats ----------------
// thread = 16 consecutive pixels -> vectorized 32B hi/lo stores
__global__ __launch_bounds__(256) void dwconv2_kernel(
    const float* __restrict__ in, const float* __restrict__ wdw,
    unsigned short* __restrict__ qkSh, unsigned short* __restrict__ qkSl,
    float* __restrict__ vbuf,
    float* __restrict__ csum, float* __restrict__ csumsq)
{
  __shared__ float p[64][65];
  __shared__ float rs[4][2];
  const int ch = blockIdx.x;
  const int b  = blockIdx.y;
  const int t  = threadIdx.x;
  const size_t base = ((size_t)b * OC3 + ch) * L;
  float wt[9];
  #pragma unroll
  for (int j = 0; j < 9; j++) wt[j] = wdw[ch * 9 + j];
  #pragma unroll
  for (int i = 0; i < 4; i++) {
    int pix = (i * 256 + t) * 4;
    const float4 v = *reinterpret_cast<const float4*>(&in[base + pix]);
    int h = pix >> 6, ww = pix & 63;
    p[h][ww] = v.x; p[h][ww+1] = v.y; p[h][ww+2] = v.z; p[h][ww+3] = v.w;
  }
  __syncthreads();
  const int h  = t >> 2;
  const int w0 = (t & 3) * 16;
  float res[16];
  float s = 0.f, s2 = 0.f;
  #pragma unroll
  for (int j = 0; j < 16; j++) {
    const int ww = w0 + j;
    float acc = 0.0f;
    #pragma unroll
    for (int ky = 0; ky < 3; ky++) {
      const int hh = h + ky - 1;
      if (hh < 0 || hh > 63) continue;
      #pragma unroll
      for (int kx = 0; kx < 3; kx++) {
        const int cc = ww + kx - 1;
        if (cc < 0 || cc > 63) continue;
        acc = fmaf(p[hh][cc], wt[ky * 3 + kx], acc);
      }
    }
    res[j] = acc;
    s += acc;
    s2 = fmaf(acc, acc, s2);
  }
  if (ch < 512) {
    u16x8 hv0, hv1, lv0, lv1;
    #pragma unroll
    for (int j = 0; j < 16; j++) {
      const unsigned int pk = splitpack(res[j]);
      if (j < 8) { hv0[j] = (unsigned short)(pk & 0xFFFFu); lv0[j] = (unsigned short)(pk >> 16); }
      else       { hv1[j-8] = (unsigned short)(pk & 0xFFFFu); lv1[j-8] = (unsigned short)(pk >> 16); }
    }
    const size_t qi = ((size_t)b * 512 + ch) * L + t * 16;
    *(u16x8*)&qkSh[qi]     = hv0;
    *(u16x8*)&qkSh[qi + 8] = hv1;
    *(u16x8*)&qkSl[qi]     = lv0;
    *(u16x8*)&qkSl[qi + 8] = lv1;
    s = wave_sum(s); s2 = wave_sum(s2);
    const int lane = t & 63, wid = t >> 6;
    if (lane == 0) { rs[wid][0] = s; rs[wid][1] = s2; }
    __syncthreads();
    if (t == 0) {
      csum[b * 512 + ch]   = rs[0][0] + rs[1][0] + rs[2][0] + rs[3][0];
      csumsq[b * 512 + ch] = rs[0][1] + rs[1][1] + rs[2][1] + rs[3][1];
    }
  } else {
    const size_t vi = ((size_t)b * 256 + (ch - 512)) * L + t * 16;
    #pragma unroll
    for (int j = 0; j < 4; j++) {
      float4 v4;
      v4.x = res[j*4+0]; v4.y = res[j*4+1]; v4.z = res[j*4+2]; v4.w = res[j*4+3];
      *(float4*)&vbuf[vi + j * 4] = v4;
    }
  }
}

// ---------------- stable descending rank over q-channel sums ----------------
__global__ __launch_bounds__(256) void rank_kernel(const float* __restrict__ csum,
                                                   int* __restrict__ order)
{
  const int c = threadIdx.x;
  float key = 0.f;
  #pragma unroll
  for (int b = 0; b < 8; b++) key += csum[b * 512 + c];
  __shared__ float keys[256];
  keys[c] = key;
  __syncthreads();
  int rank = 0;
  for (int j = 0; j < 256; j++) {
    float kj = keys[j];
    rank += (kj > key) || (kj == key && j < c);
  }
  order[rank] = c;
}

// ---------------- relabel stats into sorted order ----------------
__global__ __launch_bounds__(256) void stats_kernel(
    const float* __restrict__ csum, const float* __restrict__ csumsq,
    const int* __restrict__ order,
    float* __restrict__ sumq, float* __restrict__ sumk,
    float* __restrict__ invnq, float* __restrict__ invnk)
{
  const int b = blockIdx.x, r = threadIdx.x;
  const int ch = order[r];
  sumq[b * 256 + r]  = csum[b * 512 + ch];
  invnq[b * 256 + r] = 1.0f / fmaxf(sqrtf(csumsq[b * 512 + ch]), 1e-12f);
  sumk[b * 256 + r]  = csum[b * 512 + 256 + ch];
  invnk[b * 256 + r] = 1.0f / fmaxf(sqrtf(csumsq[b * 512 + 256 + ch]), 1e-12f);
}

// ---------------- pack: vTS = split(v^T sorted) [b][l][r]; zqT = split(qn+kn) [b][l][r] ----------------
__global__ __launch_bounds__(256) void vpack_kernel(
    const float* __restrict__ vbuf,
    const unsigned short* __restrict__ qkSh, const unsigned short* __restrict__ qkSl,
    const int* __restrict__ order,
    const float* __restrict__ invnq, const float* __restrict__ invnk,
    unsigned short* __restrict__ vTSh, unsigned short* __restrict__ vTSl,
    unsigned short* __restrict__ zqTh, unsigned short* __restrict__ zqTl)
{
  __shared__ float vt[64][65];
  __shared__ float zt[64][65];
  __shared__ int   ordS[256];
  __shared__ float iqS[256], ikS[256];
  const int t = threadIdx.x, lb = blockIdx.x * 64, b = blockIdx.y;
  ordS[t] = order[t];
  iqS[t] = invnq[b * 256 + t];
  ikS[t] = invnk[b * 256 + t];
  __syncthreads();
  for (int cc = 0; cc < 4; cc++) {
    const int r0 = cc * 64;
    for (int i = t; i < 1024; i += 256) {
      const int row = i >> 4, q = i & 15;
      const int ch = ordS[r0 + row];
      const float iq = iqS[r0 + row], ik = ikS[r0 + row];
      const float4 v4 = *(const float4*)&vbuf[((size_t)b * 256 + ch) * L + lb + q * 4];
      vt[q*4+0][row] = v4.x; vt[q*4+1][row] = v4.y; vt[q*4+2][row] = v4.z; vt[q*4+3][row] = v4.w;
      const size_t qi = ((size_t)b * 512 + ch) * L + lb + q * 4;
      const size_t ki = ((size_t)b * 512 + 256 + ch) * L + lb + q * 4;
      const ushort4 qh4 = *(const ushort4*)&qkSh[qi];
      const ushort4 ql4 = *(const ushort4*)&qkSl[qi];
      const ushort4 kh4 = *(const ushort4*)&qkSh[ki];
      const ushort4 kl4 = *(const ushort4*)&qkSl[ki];
      zt[q*4+0][row] = (bf16_tof(qh4.x)+bf16_tof(ql4.x))*iq + (bf16_tof(kh4.x)+bf16_tof(kl4.x))*ik;
      zt[q*4+1][row] = (bf16_tof(qh4.y)+bf16_tof(ql4.y))*iq + (bf16_tof(kh4.y)+bf16_tof(kl4.y))*ik;
      zt[q*4+2][row] = (bf16_tof(qh4.z)+bf16_tof(ql4.z))*iq + (bf16_tof(kh4.z)+bf16_tof(kl4.z))*ik;
      zt[q*4+3][row] = (bf16_tof(qh4.w)+bf16_tof(ql4.w))*iq + (bf16_tof(kh4.w)+bf16_tof(kl4.w))*ik;
    }
    __syncthreads();
    const int l = t >> 2, qq = t & 3;
    const size_t ob = ((size_t)b * L + lb + l) * 256 + r0 + qq * 16;
    u16x8 vh[2], vl[2], zh[2], zl[2];
    #pragma unroll
    for (int j = 0; j < 16; j++) {
      unsigned int pv = splitpack(vt[l][qq*16 + j]);
      unsigned int pz = splitpack(zt[l][qq*16 + j]);
      vh[j>>3][j&7] = (unsigned short)(pv & 0xFFFFu);
      vl[j>>3][j&7] = (unsigned short)(pv >> 16);
      zh[j>>3][j&7] = (unsigned short)(pz & 0xFFFFu);
      zl[j>>3][j&7] = (unsigned short)(pz >> 16);
    }
    *(u16x8*)&vTSh[ob]     = vh[0]; *(u16x8*)&vTSh[ob + 8] = vh[1];
    *(u16x8*)&vTSl[ob]     = vl[0]; *(u16x8*)&vTSl[ob + 8] = vl[1];
    *(u16x8*)&zqTh[ob]     = zh[0]; *(u16x8*)&zqTh[ob + 8] = zh[1];
    *(u16x8*)&zqTl[ob]     = zl[0]; *(u16x8*)&zqTl[ob + 8] = zl[1];
    __syncthreads();
  }
}

// ---------------- scores via MFMA, 2-phase double-buffered gather staging ----------------
template<int G, int GI, int START, int MB, int SPB>
__device__ void scores_body(const unsigned short* __restrict__ qkSh,
    const unsigned short* __restrict__ qkSl,
    const int* __restrict__ order, float* __restrict__ Spart,
    unsigned short* Ah, unsigned short* Al, unsigned short* Bh, unsigned short* Bl,
    int* ordS)
{
  constexpr int MR = (G - MB * 64 < 64) ? (G - MB * 64) : 64;
  constexpr int NF = G / 16;
  const int t = threadIdx.x, ks = blockIdx.x, b = blockIdx.y;
  const int w = t >> 6, lane = t & 63, ln = lane & 15, lg = lane >> 4;
  const int lrow  = lane >> 2;
  const int chunk = (lane & 3) ^ ((lane >> 4) & 3);
  const int slot  = lg ^ (ln >> 2);
  for (int i = t; i < G; i += 256) ordS[i] = order[START + i];
  __syncthreads();
  const int k0 = ks * 512;
  const bool act = (w * 16) < MR;
  f32x4 z4 = {0.f, 0.f, 0.f, 0.f};
  f32x4 acc[NF];
  #pragma unroll
  for (int i = 0; i < NF; i++) acc[i] = z4;

  auto stage = [&](int kc, int cb) {
    for (int i = w; i < MR / 16; i += 4) {
      const int rb = i * 16;
      const int ch = ordS[MB * 64 + rb + lrow];
      const size_t g = ((size_t)b * 512 + ch) * L + k0 + kc + chunk * 8;
      gl16(qkSh + g, &Ah[cb * 2048 + rb * 32]);
      gl16(qkSl + g, &Al[cb * 2048 + rb * 32]);
    }
    for (int i = w; i < G / 16; i += 4) {
      const int rb = i * 16;
      const int ch = 256 + ordS[rb + lrow];
      const size_t g = ((size_t)b * 512 + ch) * L + k0 + kc + chunk * 8;
      gl16(qkSh + g, &Bh[cb * 3072 + rb * 32]);
      gl16(qkSl + g, &Bl[cb * 3072 + rb * 32]);
    }
  };

  stage(0, 0);
  __syncthreads();
  int cur = 0;
  for (int kc = 0; kc < 512; kc += 32) {
    if (kc + 32 < 512) stage(kc + 32, cur ^ 1);
    if (act) {
      const int aoff = cur * 2048 + (w * 16 + ln) * 32 + slot * 8;
      const short8v ah = *(const short8v*)&Ah[aoff];
      const short8v al = *(const short8v*)&Al[aoff];
      #pragma unroll
      for (int nf = 0; nf < NF; nf++) {
        const int boff = cur * 3072 + (nf * 16 + ln) * 32 + slot * 8;
        const short8v bh = *(const short8v*)&Bh[boff];
        const short8v bl = *(const short8v*)&Bl[boff];
        acc[nf] = __builtin_amdgcn_mfma_f32_16x16x32_bf16(ah, bh, acc[nf], 0, 0, 0);
        acc[nf] = __builtin_amdgcn_mfma_f32_16x16x32_bf16(ah, bl, acc[nf], 0, 0, 0);
        acc[nf] = __builtin_amdgcn_mfma_f32_16x16x32_bf16(al, bh, acc[nf], 0, 0, 0);
      }
    }
    __syncthreads();
    cur ^= 1;
  }
  if (act) {
    float* dst = Spart + (size_t)b * 147456 + SPB + ks * G * G;
    #pragma unroll
    for (int nf = 0; nf < NF; nf++) {
      const int d = nf * 16 + ln;
      #pragma unroll
      for (int r = 0; r < 4; r++) {
        const int m = MB * 64 + w * 16 + lg * 4 + r;
        dst[m * G + d] = acc[nf][r];
      }
    }
  }
}

__global__ __launch_bounds__(256) void scores_kernel(const unsigned short* __restrict__ qkSh,
    const unsigned short* __restrict__ qkSl,
    const int* __restrict__ order, float* __restrict__ Spart)
{
  __shared__ unsigned short Ah[2 * 64 * 32];
  __shared__ unsigned short Al[2 * 64 * 32];
  __shared__ unsigned short Bh[2 * 96 * 32];
  __shared__ unsigned short Bl[2 * 96 * 32];
  __shared__ int ordS[96];
  switch (blockIdx.z) {
    case 0:  scores_body<32, 0, 0,   0, 0    >(qkSh, qkSl, order, Spart, Ah, Al, Bh, Bl, ordS); break;
    case 1:  scores_body<64, 1, 32,  0, 8192 >(qkSh, qkSl, order, Spart, Ah, Al, Bh, Bl, ordS); break;
    case 2:  scores_body<64, 2, 96,  0, 40960>(qkSh, qkSl, order, Spart, Ah, Al, Bh, Bl, ordS); break;
    case 3:  scores_body<96, 3, 160, 0, 73728>(qkSh, qkSl, order, Spart, Ah, Al, Bh, Bl, ordS); break;
    default: scores_body<96, 3, 160, 1, 73728>(qkSh, qkSl, order, Spart, Ah, Al, Bh, Bl, ordS); break;
  }
}

// ---------------- reduce partials, scale, wave-parallel softmax, emit hi/lo attn ----------------
template<int G, int GI, int START, int SPB, int AOFF>
__device__ void softmax_body(const float* __restrict__ Spart, const float* __restrict__ invnq,
    const float* __restrict__ invnk, const float* __restrict__ temperature,
    unsigned short* __restrict__ attnPh, unsigned short* __restrict__ attnPl, float* Sm)
{
  const int t = threadIdx.x;
  const int b = blockIdx.x;
  const float temp = temperature[GI];
  for (int idx = t; idx < G * G; idx += 256) {
    float s = 0.f;
    #pragma unroll
    for (int ks = 0; ks < 8; ks++)
      s += Spart[(size_t)b * 147456 + SPB + ks * G * G + idx];
    const int c = idx / G, d = idx - c * G;
    Sm[idx] = s * invnq[b * 256 + START + c] * invnk[b * 256 + START + d] * temp;
  }
  __syncthreads();
  const int wv = t >> 6, lane = t & 63;
  for (int r = wv; r < G; r += 4) {
    const float v0 = (lane < G) ? Sm[r * G + lane] : -INFINITY;
    const float v1 = (64 + lane < G) ? Sm[r * G + 64 + lane] : -INFINITY;
    float m = fmaxf(v0, v1);
    #pragma unroll
    for (int off = 32; off > 0; off >>= 1) m = fmaxf(m, __shfl_xor(m, off, 64));
    const float e0 = (lane < G) ? expf(v0 - m) : 0.f;
    const float e1 = (64 + lane < G) ? expf(v1 - m) : 0.f;
    float s = e0 + e1;
    #pragma unroll
    for (int off = 32; off > 0; off >>= 1) s += __shfl_xor(s, off, 64);
    const float inv = 1.0f / s;
    const size_t base = (size_t)b * 18432 + AOFF + r * G;
    if (lane < G) {
      const unsigned int p = splitpack(e0 * inv);
      attnPh[base + lane] = (unsigned short)(p & 0xFFFFu);
      attnPl[base + lane] = (unsigned short)(p >> 16);
    }
    if (64 + lane < G) {
      const unsigned int p = splitpack(e1 * inv);
      attnPh[base + 64 + lane] = (unsigned short)(p & 0xFFFFu);
      attnPl[base + 64 + lane] = (unsigned short)(p >> 16);
    }
  }
}

__global__ __launch_bounds__(256) void softmax_kernel(const float* __restrict__ Spart,
    const float* __restrict__ invnq, const float* __restrict__ invnk,
    const float* __restrict__ temperature,
    unsigned short* __restrict__ attnPh, unsigned short* __restrict__ attnPl)
{
  extern __shared__ float smem[];
  switch (blockIdx.y) {
    case 0:  softmax_body<32, 0, 0,   0,     0   >(Spart, invnq, invnk, temperature, attnPh, attnPl, smem); break;
    case 1:  softmax_body<64, 1, 32,  8192,  1024>(Spart, invnq, invnk, temperature, attnPh, attnPl, smem); break;
    case 2:  softmax_body<64, 2, 96,  40960, 5120>(Spart, invnq, invnk, temperature, attnPh, attnPl, smem); break;
    default: softmax_body<96, 3, 160, 73728, 9216>(Spart, invnq, invnk, temperature, attnPh, attnPl, smem); break;
  }
}

// ---------------- PV via MFMA, global_load_lds staging, fused z epilogue ----------------
template<int G, int GI, int START, int AOFF>
__device__ void pv_body(
    const unsigned short* __restrict__ vTSh, const unsigned short* __restrict__ vTSl,
    const unsigned short* __restrict__ attnPh, const unsigned short* __restrict__ attnPl,
    const unsigned short* __restrict__ zqTh, const unsigned short* __restrict__ zqTl,
    unsigned short* __restrict__ outTh, unsigned short* __restrict__ outTl,
    unsigned short* __restrict__ zTh, unsigned short* __restrict__ zTl,
    unsigned short* Ah, unsigned short* Al, unsigned short* Bh, unsigned short* Bl)
{
  constexpr int NF = G / 16;
  const int t = threadIdx.x, b = blockIdx.y, l0 = blockIdx.x * 128;
  const int w = t >> 6, lane = t & 63, ln = lane & 15, lg = lane >> 4;
  const int lrow  = lane >> 2;
  const int chunk = (lane & 3) ^ ((lane >> 4) & 3);
  const int slot  = lg ^ (ln >> 2);
  f32x4 z4 = {0.f, 0.f, 0.f, 0.f};
  f32x4 acc[2][NF];
  #pragma unroll
  for (int i = 0; i < 2; i++)
    #pragma unroll
    for (int j = 0; j < NF; j++) acc[i][j] = z4;
  for (int kc = 0; kc < G; kc += 32) {
    #pragma unroll
    for (int i = 0; i < 2; i++) {
      const int rb = w * 32 + i * 16;
      const size_t g = ((size_t)b * L + l0 + rb + lrow) * 256 + START + kc + chunk * 8;
      gl16(vTSh + g, &Ah[rb * 32]);
      gl16(vTSl + g, &Al[rb * 32]);
    }
    for (int i = w; i < G / 16; i += 4) {
      const int rb = i * 16;
      const size_t g = (size_t)b * 18432 + AOFF + (size_t)(rb + lrow) * G + kc + chunk * 8;
      gl16(attnPh + g, &Bh[rb * 32]);
      gl16(attnPl + g, &Bl[rb * 32]);
    }
    __syncthreads();
    short8v bhf[NF], blf[NF];
    #pragma unroll
    for (int nf = 0; nf < NF; nf++) {
      const int boff = (nf * 16 + ln) * 32 + slot * 8;
      bhf[nf] = *(const short8v*)&Bh[boff];
      blf[nf] = *(const short8v*)&Bl[boff];
    }
    #pragma unroll
    for (int mi = 0; mi < 2; mi++) {
      const int aoff = ((w * 2 + mi) * 16 + ln) * 32 + slot * 8;
      const short8v ah = *(const short8v*)&Ah[aoff];
      const short8v al = *(const short8v*)&Al[aoff];
      #pragma unroll
      for (int nf = 0; nf < NF; nf++) {
        acc[mi][nf] = __builtin_amdgcn_mfma_f32_16x16x32_bf16(ah, bhf[nf], acc[mi][nf], 0, 0, 0);
        acc[mi][nf] = __builtin_amdgcn_mfma_f32_16x16x32_bf16(ah, blf[nf], acc[mi][nf], 0, 0, 0);
        acc[mi][nf] = __builtin_amdgcn_mfma_f32_16x16x32_bf16(al, bhf[nf], acc[mi][nf], 0, 0, 0);
      }
    }
    __syncthreads();
  }
  #pragma unroll
  for (int mi = 0; mi < 2; mi++) {
    const int lbase = l0 + (w * 2 + mi) * 16 + lg * 4;
    #pragma unroll
    for (int nf = 0; nf < NF; nf++) {
      const int col = START + nf * 16 + ln;
      #pragma unroll
      for (int r = 0; r < 4; r++) {
        const size_t idx = ((size_t)b * L + lbase + r) * 256 + col;
        const float v = acc[mi][nf][r];
        const unsigned int po = splitpack(v);
        outTh[idx] = (unsigned short)(po & 0xFFFFu);
        outTl[idx] = (unsigned short)(po >> 16);
        const float zq = bf16_tof(zqTh[idx]) + bf16_tof(zqTl[idx]);
        const unsigned int pz = splitpack(v + zq);
        zTh[idx] = (unsigned short)(pz & 0xFFFFu);
        zTl[idx] = (unsigned short)(pz >> 16);
      }
    }
  }
}

__global__ __launch_bounds__(256) void pv_kernel(
    const unsigned short* __restrict__ vTSh, const unsigned short* __restrict__ vTSl,
    const unsigned short* __restrict__ attnPh, const unsigned short* __restrict__ attnPl,
    const unsigned short* __restrict__ zqTh, const unsigned short* __restrict__ zqTl,
    unsigned short* __restrict__ outTh, unsigned short* __restrict__ outTl,
    unsigned short* __restrict__ zTh, unsigned short* __restrict__ zTl)
{
  __shared__ unsigned short Ah[128 * 32];
  __shared__ unsigned short Al[128 * 32];
  __shared__ unsigned short Bh[96 * 32];
  __shared__ unsigned short Bl[96 * 32];
  switch (blockIdx.z) {
    case 0:  pv_body<32, 0, 0,   0   >(vTSh, vTSl, attnPh, attnPl, zqTh, zqTl, outTh, outTl, zTh, zTl, Ah, Al, Bh, Bl); break;
    case 1:  pv_body<64, 1, 32,  1024>(vTSh, vTSl, attnPh, attnPl, zqTh, zqTl, outTh, outTl, zTh, zTl, Ah, Al, Bh, Bl); break;
    case 2:  pv_body<64, 2, 96,  5120>(vTSh, vTSl, attnPh, attnPl, zqTh, zqTl, outTh, outTl, zTh, zTl, Ah, Al, Bh, Bl); break;
    default: pv_body<96, 3, 160, 9216>(vTSh, vTSl, attnPh, attnPl, zqTh, zqTl, outTh, outTl, zTh, zTl, Ah, Al, Bh, Bl); break;
  }
}

// ---------------- qv_cache ----------------
__global__ __launch_bounds__(256) void qv_kernel(const float* __restrict__ sumq,
    const float* __restrict__ sumk, const float* __restrict__ invnq,
    const float* __restrict__ invnk, float* __restrict__ out2)
{
  const int b = blockIdx.x >> 8, r = blockIdx.x & 255;
  float val = 0.f;
  {
    const int idx = b * 256 + 0 + (r & 31);
    val += fmaf(sumq[idx], invnq[idx], sumk[idx] * invnk[idx]);
  }
  {
    const int idx = b * 256 + 32 + (r & 63);
    val += fmaf(sumq[idx], invnq[idx], sumk[idx] * invnk[idx]);
  }
  {
    const int idx = b * 256 + 96 + (r & 63);
    val += fmaf(sumq[idx], invnq[idx], sumk[idx] * invnk[idx]);
  }
  if (r < 192) {
    const int rm = (r < 96) ? r : r - 96;
    const int idx = b * 256 + 160 + rm;
    val += fmaf(sumq[idx], invnq[idx], sumk[idx] * invnk[idx]);
  }
  val *= (1.0f / 4096.f) * 0.25f * 0.9f;
  const float4 o = {val, val, val, val};
  float4* dst = reinterpret_cast<float4*>(out2 + ((size_t)b * C + r) * L);
  for (int i = threadIdx.x; i < 1024; i += 256) dst[i] = o;
}

// ---------------- launch ----------------
extern "C" void kernel_launch(void* const* d_in, const int* in_sizes, int n_in,
                              void* d_out, int out_size, void* d_ws, size_t ws_size,
                              hipStream_t stream)
{
  const float* x           = (const float*)d_in[0];
  const float* temperature = (const float*)d_in[1];
  const float* w_qkv       = (const float*)d_in[2];
  const float* w_dw        = (const float*)d_in[3];
  const float* w_proj      = (const float*)d_in[4];
  const float* w_gate      = (const float*)d_in[5];
  const float* b_gate      = (const float*)d_in[6];
  const float* w_down      = (const float*)d_in[7];
  const float* b_down      = (const float*)d_in[8];
  const float* w_up        = (const float*)d_in[9];
  const float* b_up        = (const float*)d_in[10];

  if (ws_size < 202548224ULL) return;

  char* ws = (char*)d_ws;
  // Region A [0, 96M):
  float*          qkv_pre  = (float*)(ws);                        // 96MB, dead after dwconv
  unsigned short* vTSh     = (unsigned short*)(ws);                // 16MB
  unsigned short* vTSl     = (unsigned short*)(ws + 16777216);     // 16MB
  unsigned short* zqTh     = (unsigned short*)(ws + 33554432);     // 16MB
  unsigned short* zqTl     = (unsigned short*)(ws + 50331648);     // 16MB
  float*          Spart    = (float*)(ws + 67108864);              // 4.72MB
  unsigned short* attnPh   = (unsigned short*)(ws + 73400320);     // 288KB
  unsigned short* attnPl   = (unsigned short*)(ws + 74448896);     // 288KB
  unsigned short* preprojh = (unsigned short*)(ws);                // 16MB (after pv)
  unsigned short* preprojl = (unsigned short*)(ws + 16777216);     // 16MB
  // Region B [96M, 192M):
  unsigned short* XThi     = (unsigned short*)(ws + 100663296);    // 16MB
  unsigned short* XTlo     = (unsigned short*)(ws + 117440512);    // 16MB
  unsigned short* WqkvHi   = (unsigned short*)(ws + 134217728);    // 384KB
  unsigned short* WqkvLo   = (unsigned short*)(ws + 134610944);    // 384KB
  unsigned short* qkSh     = (unsigned short*)(ws + 100663296);    // 32MB (after qkv gemm)
  unsigned short* qkSl     = (unsigned short*)(ws + 134217728);    // 32MB
  float*          vbuf     = (float*)(ws + 167772160);             // 32MB
  unsigned short* outTh    = (unsigned short*)(ws + 100663296);    // 16MB (after scores)
  unsigned short* outTl    = (unsigned short*)(ws + 117440512);    // 16MB
  unsigned short* zTh      = (unsigned short*)(ws + 134217728);    // 16MB
  unsigned short* zTl      = (unsigned short*)(ws + 150994944);    // 16MB
  unsigned short* gatedh   = (unsigned short*)(ws + 167772160);    // 16MB (after vpack)
  unsigned short* gatedl   = (unsigned short*)(ws + 184549376);    // 16MB
  unsigned short* midh     = (unsigned short*)(ws + 134217728);    // 8MB (after gate gemm)
  unsigned short* midl     = (unsigned short*)(ws + 142606336);    // 8MB
  // Region C [192M, 193.2M):
  unsigned short* WmlpHi = (unsigned short*)(ws + 201326592);      // 384KB
  unsigned short* WmlpLo = (unsigned short*)(ws + 201719808);      // 384KB
  float* csum   = (float*)(ws + 202113024);
  float* csumsq = (float*)(ws + 202129408);
  float* sumq   = (float*)(ws + 202145792);
  float* sumk   = (float*)(ws + 202153984);
  float* invnq  = (float*)(ws + 202162176);
  float* invnk  = (float*)(ws + 202170368);
  int*   order  = (int*)(ws + 202178560);

  float* out_all = (float*)d_out;
  float* qv_out  = out_all + (size_t)B * C * L;

  // 0. weight + input splits
  wsplit_kernel<<<1536, 256, 0, stream>>>(w_qkv, w_gate, w_down, w_up, w_proj,
                                          WqkvHi, WqkvLo, WmlpHi, WmlpLo);
  splitx_kernel<<<dim3(64, 4, 8), 256, 0, stream>>>(x, XThi, XTlo);
  // 1. qkv = w_qkv @ x  (MFMA, out fp32 [b][768][L])
  mgemm<256, 0><<<dim3(32, 6, 8), 256, 0, stream>>>(
      XThi, XTlo, WqkvHi, WqkvLo, qkv_pre, nullptr, nullptr, nullptr, nullptr, nullptr, 768);
  // 2. depthwise conv (+ split-pack q,k hi/lo; v fp32; channel stats)
  dwconv2_kernel<<<dim3(768, 8), 256, 0, stream>>>(qkv_pre, w_dw, qkSh, qkSl, vbuf, csum, csumsq);
  // 3. channel ordering + stats relabel
  rank_kernel<<<1, 256, 0, stream>>>(csum, order);
  stats_kernel<<<8, 256, 0, stream>>>(csum, csumsq, order, sumq, sumk, invnq, invnk);
  // 4. pack v^T + zq (hi/lo)
  vpack_kernel<<<dim3(64, 8), 256, 0, stream>>>(vbuf, qkSh, qkSl, order, invnq, invnk,
                                                vTSh, vTSl, zqTh, zqTl);
  // 5. attention
  scores_kernel<<<dim3(8, 8, 5), 256, 0, stream>>>(qkSh, qkSl, order, Spart);
  softmax_kernel<<<dim3(8, 4), 256, 36864, stream>>>(Spart, invnq, invnk, temperature, attnPh, attnPl);
  pv_kernel<<<dim3(32, 8, 4), 256, 0, stream>>>(vTSh, vTSl, attnPh, attnPl, zqTh, zqTl,
                                                outTh, outTl, zTh, zTl);
  // 6. MLP chain
  mgemm<256, 2><<<dim3(32, 2, 8), 256, 0, stream>>>(
      zTh, zTl, WmlpHi, WmlpLo, nullptr, gatedh, gatedl, b_gate, zTh, zTl, 256);
  mgemm<256, 1><<<dim3(32, 1, 8), 256, 0, stream>>>(
      gatedh, gatedl, WmlpHi + 65536, WmlpLo + 65536, nullptr, midh, midl, b_down, nullptr, nullptr, 128);
  mgemm<128, 3><<<dim3(32, 2, 8), 256, 0, stream>>>(
      midh, midl, WmlpHi + 98304, WmlpLo + 98304, nullptr, preprojh, preprojl, b_up, outTh, outTl, 256);
  // 7. final projection -> output 0
  mgemm<256, 0><<<dim3(32, 2, 8), 256, 0, stream>>>(
      preprojh, preprojl, WmlpHi + 131072, WmlpLo + 131072, out_all, nullptr, nullptr, nullptr, nullptr, nullptr, 256);
  // 8. qv_cache -> output 1
  qv_kernel<<<2048, 256, 0, stream>>>(sumq, sumk, invnq, invnk, qv_out);
}

// Round 6
// 322.349 us; speedup vs baseline: 1.8622x; 1.0481x over previous
//
#include <hip/hip_runtime.h>
#include <hip/hip_fp16.h>
#include <math.h>

#define B 8
#define C 256
#define L 4096
#define OC3 768

typedef __attribute__((ext_vector_type(8))) short short8v;
typedef __attribute__((ext_vector_type(8))) unsigned short u16x8;
typedef __attribute__((ext_vector_type(4))) float f32x4;

// ---------------- helpers ----------------
__device__ __forceinline__ float gelu_exact(float x){
  return 0.5f * x * (1.0f + erff(x * 0.70710678118654752440f));
}
__device__ __forceinline__ float wave_sum(float v){
  #pragma unroll
  for (int off = 32; off > 0; off >>= 1) v += __shfl_down(v, off, 64);
  return v;
}
__device__ __forceinline__ unsigned short bf16_rne(float f){
  unsigned int u = __float_as_uint(f);
  unsigned int r = u + 0x7FFFu + ((u >> 16) & 1u);
  return (unsigned short)(r >> 16);
}
__device__ __forceinline__ float bf16_tof(unsigned short h){
  return __uint_as_float(((unsigned int)h) << 16);
}
// bf16 split pair in one u32: low16 = hi, high16 = lo
__device__ __forceinline__ unsigned int splitpack(float v){
  unsigned short hi = bf16_rne(v);
  float lof = v - bf16_tof(hi);
  unsigned short lo = bf16_rne(lof);
  return (unsigned int)hi | ((unsigned int)lo << 16);
}
// f16 helpers
__device__ __forceinline__ unsigned short f16b(float f){
  return __half_as_ushort(__float2half_rn(f));
}
__device__ __forceinline__ float f16tof(unsigned short u){
  return __half2float(__ushort_as_half(u));
}
// f16 split pair in one u32: low16 = hi, high16 = lo
__device__ __forceinline__ unsigned int splitpackh(float v){
  unsigned short hi = f16b(v);
  float lof = v - f16tof(hi);
  unsigned short lo = f16b(lof);
  return (unsigned int)hi | ((unsigned int)lo << 16);
}
// async global->LDS 16B per lane; LDS dest must be wave-uniform base
__device__ __forceinline__ void gl16(const unsigned short* g, unsigned short* l){
  __builtin_amdgcn_global_load_lds(
      (const __attribute__((address_space(1))) void*)g,
      (__attribute__((address_space(3))) void*)l, 16, 0, 0);
}

// ---------------- weight split ----------------
// Wf16: qkv@0 (196608), gate@196608 (65536), down@262144 (32768), up@294912 (32768) -- f16 single plane
// proj -> bf16 hi/lo planes (65536 each)
__global__ __launch_bounds__(256) void wsplit_kernel(
    const float* __restrict__ wqkv, const float* __restrict__ wgate,
    const float* __restrict__ wdown, const float* __restrict__ wup,
    const float* __restrict__ wproj,
    unsigned short* __restrict__ Wf16,
    unsigned short* __restrict__ PH, unsigned short* __restrict__ PLo)
{
  int idx = blockIdx.x * 256 + threadIdx.x;   // 0..393215
  if (idx < 327680) {
    float s;
    if (idx < 196608)      s = wqkv[idx];
    else if (idx < 262144) s = wgate[idx - 196608];
    else if (idx < 294912) s = wdown[idx - 262144];
    else                   s = wup[idx - 294912];
    Wf16[idx] = f16b(s);
  } else {
    int j = idx - 327680;   // 0..65535
    unsigned int p = splitpack(wproj[j]);
    PH[j] = (unsigned short)(p & 0xFFFFu); PLo[j] = (unsigned short)(p >> 16);
  }
}

// ---------------- x [b][c][l] fp32 -> xT hi/lo f16 [b][l][c] ----------------
__global__ __launch_bounds__(256) void splitx_kernel(const float* __restrict__ x,
    unsigned short* __restrict__ XThi, unsigned short* __restrict__ XTlo)
{
  __shared__ float st[64][68];
  const int b = blockIdx.z, c0 = blockIdx.y * 64, lb = blockIdx.x * 64;
  const int t = threadIdx.x;
  #pragma unroll
  for (int i = 0; i < 4; i++) {
    int row = (t >> 4) + i * 16;
    int col = (t & 15) * 4;
    float4 v = *(const float4*)&x[((size_t)b * C + c0 + row) * L + lb + col];
    st[row][col] = v.x; st[row][col+1] = v.y; st[row][col+2] = v.z; st[row][col+3] = v.w;
  }
  __syncthreads();
  const int l = t >> 2, cq = t & 3;
  u16x8 hv0, hv1, lv0, lv1;
  #pragma unroll
  for (int i = 0; i < 16; i++) {
    unsigned int p = splitpackh(st[cq * 16 + i][l]);
    if (i < 8) { hv0[i] = (unsigned short)(p & 0xFFFFu); lv0[i] = (unsigned short)(p >> 16); }
    else       { hv1[i-8] = (unsigned short)(p & 0xFFFFu); lv1[i-8] = (unsigned short)(p >> 16); }
  }
  size_t o = ((size_t)b * L + lb + l) * C + c0 + cq * 16;
  *(u16x8*)&XThi[o]     = hv0;
  *(u16x8*)&XThi[o + 8] = hv1;
  *(u16x8*)&XTlo[o]     = lv0;
  *(u16x8*)&XTlo[o + 8] = lv1;
}

// ---------------- f16 2-pass MFMA GEMM, 2-phase double-buffered ----------------
// D[l][o] = sum_k (Ahi+Alo)[l][k] * Wf16[o][k]
// EPI: 0 = store fp32 transposed [b][o][L]
//      1 = +bias, store f16 hi/lo [b][l][o]
//      2 = gelu(acc+bias)*extra(f16 pair), store f16 hi/lo
//      5 = acc+bias+extra(f16 pair), store BF16 hi/lo (feeds bf16 proj)
template<int KTOT, int EPI>
__global__ __launch_bounds__(256) void hgemm(
    const unsigned short* __restrict__ Ahi_g, const unsigned short* __restrict__ Alo_g,
    const unsigned short* __restrict__ Bw_g,
    float* __restrict__ outF,
    unsigned short* __restrict__ outH, unsigned short* __restrict__ outLo,
    const float* __restrict__ bias,
    const unsigned short* __restrict__ extraH, const unsigned short* __restrict__ extraLo,
    int Ntot)
{
  __shared__ unsigned short SB[2][3][128 * 32];   // [buf][Ah,Al,Bw]
  const int t  = threadIdx.x;
  const int lb = blockIdx.x * 128;
  const int o0 = blockIdx.y * 128;
  const int b  = blockIdx.z;
  const int w  = t >> 6, lane = t & 63;
  const int wm = w >> 1, wn = w & 1;
  const int ln = lane & 15, lg = lane >> 4;
  const int lrow  = lane >> 2;
  const int chunk = (lane & 3) ^ ((lane >> 4) & 3);
  const int slot  = lg ^ (ln >> 2);

  f32x4 z4 = {0.f, 0.f, 0.f, 0.f};
  f32x4 acc[4][4];
  #pragma unroll
  for (int i = 0; i < 4; i++)
    #pragma unroll
    for (int j = 0; j < 4; j++) acc[i][j] = z4;

  const size_t arow0 = (size_t)b * L + lb;
  constexpr int NKT = KTOT / 32;

  auto stage = [&](int kt, int cb) {
    const int k0 = kt * 32;
    #pragma unroll
    for (int i = 0; i < 2; i++) {
      const int rb = w * 32 + i * 16;
      const size_t ga = (arow0 + rb + lrow) * KTOT + k0 + chunk * 8;
      gl16(Ahi_g + ga, &SB[cb][0][rb * 32]);
      gl16(Alo_g + ga, &SB[cb][1][rb * 32]);
      const size_t gb = (size_t)(o0 + rb + lrow) * KTOT + k0 + chunk * 8;
      gl16(Bw_g + gb, &SB[cb][2][rb * 32]);
    }
  };

  stage(0, 0);
  __syncthreads();
  int cur = 0;
  for (int kt = 0; kt < NKT; ++kt) {
    if (kt + 1 < NKT) stage(kt + 1, cur ^ 1);
    short8v bwf[4];
    #pragma unroll
    for (int nf = 0; nf < 4; nf++) {
      const int off = (wn * 64 + nf * 16 + ln) * 32 + slot * 8;
      bwf[nf] = *(const short8v*)&SB[cur][2][off];
    }
    #pragma unroll
    for (int mf = 0; mf < 4; mf++) {
      const int off = (wm * 64 + mf * 16 + ln) * 32 + slot * 8;
      const short8v ah = *(const short8v*)&SB[cur][0][off];
      const short8v al = *(const short8v*)&SB[cur][1][off];
      #pragma unroll
      for (int nf = 0; nf < 4; nf++) {
        acc[mf][nf] = __builtin_amdgcn_mfma_f32_16x16x32_f16(ah, bwf[nf], acc[mf][nf], 0, 0, 0);
        acc[mf][nf] = __builtin_amdgcn_mfma_f32_16x16x32_f16(al, bwf[nf], acc[mf][nf], 0, 0, 0);
      }
    }
    __syncthreads();
    cur ^= 1;
  }
  #pragma unroll
  for (int mf = 0; mf < 4; mf++) {
    const int mbase = lb + wm * 64 + mf * 16 + lg * 4;
    #pragma unroll
    for (int nf = 0; nf < 4; nf++) {
      const int o = o0 + wn * 64 + nf * 16 + ln;
      if (EPI == 0) {
        float4 r;
        r.x = acc[mf][nf][0]; r.y = acc[mf][nf][1];
        r.z = acc[mf][nf][2]; r.w = acc[mf][nf][3];
        *(float4*)&outF[((size_t)b * Ntot + o) * L + mbase] = r;
      } else {
        const float bv = bias ? bias[o] : 0.0f;
        #pragma unroll
        for (int r = 0; r < 4; r++) {
          const size_t idx = ((size_t)b * L + mbase + r) * Ntot + o;
          float v = acc[mf][nf][r] + bv;
          if (EPI == 2) { v = gelu_exact(v) * (f16tof(extraH[idx]) + f16tof(extraLo[idx])); }
          if (EPI == 5) { v = v + f16tof(extraH[idx]) + f16tof(extraLo[idx]); }
          unsigned int p;
          if (EPI == 5) p = splitpack(v);   // bf16 pair for proj
          else          p = splitpackh(v);  // f16 pair
          outH[idx]  = (unsigned short)(p & 0xFFFFu);
          outLo[idx] = (unsigned short)(p >> 16);
        }
      }
    }
  }
}

// ---------------- bf16 3-pass MFMA GEMM (proj only), 2-phase double-buffered ----------------
template<int KTOT>
__global__ __launch_bounds__(256) void mgemm(
    const unsigned short* __restrict__ Ahi_g, const unsigned short* __restrict__ Alo_g,
    const unsigned short* __restrict__ Bhi_g, const unsigned short* __restrict__ Blo_g,
    float* __restrict__ outF, int Ntot)
{
  __shared__ unsigned short SB[2][4][128 * 32];
  const int t  = threadIdx.x;
  const int lb = blockIdx.x * 128;
  const int o0 = blockIdx.y * 128;
  const int b  = blockIdx.z;
  const int w  = t >> 6, lane = t & 63;
  const int wm = w >> 1, wn = w & 1;
  const int ln = lane & 15, lg = lane >> 4;
  const int lrow  = lane >> 2;
  const int chunk = (lane & 3) ^ ((lane >> 4) & 3);
  const int slot  = lg ^ (ln >> 2);

  f32x4 z4 = {0.f, 0.f, 0.f, 0.f};
  f32x4 acc[4][4];
  #pragma unroll
  for (int i = 0; i < 4; i++)
    #pragma unroll
    for (int j = 0; j < 4; j++) acc[i][j] = z4;

  const size_t arow0 = (size_t)b * L + lb;
  constexpr int NKT = KTOT / 32;

  auto stage = [&](int kt, int cb) {
    const int k0 = kt * 32;
    #pragma unroll
    for (int i = 0; i < 2; i++) {
      const int rb = w * 32 + i * 16;
      const size_t ga = (arow0 + rb + lrow) * KTOT + k0 + chunk * 8;
      gl16(Ahi_g + ga, &SB[cb][0][rb * 32]);
      gl16(Alo_g + ga, &SB[cb][1][rb * 32]);
      const size_t gb = (size_t)(o0 + rb + lrow) * KTOT + k0 + chunk * 8;
      gl16(Bhi_g + gb, &SB[cb][2][rb * 32]);
      gl16(Blo_g + gb, &SB[cb][3][rb * 32]);
    }
  };

  stage(0, 0);
  __syncthreads();
  int cur = 0;
  for (int kt = 0; kt < NKT; ++kt) {
    if (kt + 1 < NKT) stage(kt + 1, cur ^ 1);
    short8v bhf[4], blf[4];
    #pragma unroll
    for (int nf = 0; nf < 4; nf++) {
      const int off = (wn * 64 + nf * 16 + ln) * 32 + slot * 8;
      bhf[nf] = *(const short8v*)&SB[cur][2][off];
      blf[nf] = *(const short8v*)&SB[cur][3][off];
    }
    #pragma unroll
    for (int mf = 0; mf < 4; mf++) {
      const int off = (wm * 64 + mf * 16 + ln) * 32 + slot * 8;
      const short8v ah = *(const short8v*)&SB[cur][0][off];
      const short8v al = *(const short8v*)&SB[cur][1][off];
      #pragma unroll
      for (int nf = 0; nf < 4; nf++) {
        acc[mf][nf] = __builtin_amdgcn_mfma_f32_16x16x32_bf16(ah, bhf[nf], acc[mf][nf], 0, 0, 0);
        acc[mf][nf] = __builtin_amdgcn_mfma_f32_16x16x32_bf16(ah, blf[nf], acc[mf][nf], 0, 0, 0);
        acc[mf][nf] = __builtin_amdgcn_mfma_f32_16x16x32_bf16(al, bhf[nf], acc[mf][nf], 0, 0, 0);
      }
    }
    __syncthreads();
    cur ^= 1;
  }
  #pragma unroll
  for (int mf = 0; mf < 4; mf++) {
    const int mbase = lb + wm * 64 + mf * 16 + lg * 4;
    #pragma unroll
    for (int nf = 0; nf < 4; nf++) {
      const int o = o0 + wn * 64 + nf * 16 + ln;
      float4 r;
      r.x = acc[mf][nf][0]; r.y = acc[mf][nf][1];
      r.z = acc[mf][nf][2]; r.w = acc[mf][nf][3];
      *(float4*)&outF[((size_t)b * Ntot + o) * L + mbase] = r;
    }
  }
}

// ---------------- depthwise 3x3 conv + split-pack + channel stats ----------------
__global__ __launch_bounds__(256) void dwconv2_kernel(
    const float* __restrict__ in, const float* __restrict__ wdw,
    unsigned short* __restrict__ qkSh, unsigned short* __restrict__ qkSl,
    float* __restrict__ vbuf,
    float* __restrict__ csum, float* __restrict__ csumsq)
{
  __shared__ float p[64][65];
  __shared__ float rs[4][2];
  const int ch = blockIdx.x;
  const int b  = blockIdx.y;
  const int t  = threadIdx.x;
  const size_t base = ((size_t)b * OC3 + ch) * L;
  float wt[9];
  #pragma unroll
  for (int j = 0; j < 9; j++) wt[j] = wdw[ch * 9 + j];
  #pragma unroll
  for (int i = 0; i < 4; i++) {
    int pix = (i * 256 + t) * 4;
    const float4 v = *reinterpret_cast<const float4*>(&in[base + pix]);
    int h = pix >> 6, ww = pix & 63;
    p[h][ww] = v.x; p[h][ww+1] = v.y; p[h][ww+2] = v.z; p[h][ww+3] = v.w;
  }
  __syncthreads();
  const int h  = t >> 2;
  const int w0 = (t & 3) * 16;
  float res[16];
  float s = 0.f, s2 = 0.f;
  #pragma unroll
  for (int j = 0; j < 16; j++) {
    const int ww = w0 + j;
    float acc = 0.0f;
    #pragma unroll
    for (int ky = 0; ky < 3; ky++) {
      const int hh = h + ky - 1;
      if (hh < 0 || hh > 63) continue;
      #pragma unroll
      for (int kx = 0; kx < 3; kx++) {
        const int cc = ww + kx - 1;
        if (cc < 0 || cc > 63) continue;
        acc = fmaf(p[hh][cc], wt[ky * 3 + kx], acc);
      }
    }
    res[j] = acc;
    s += acc;
    s2 = fmaf(acc, acc, s2);
  }
  if (ch < 512) {
    u16x8 hv0, hv1, lv0, lv1;
    #pragma unroll
    for (int j = 0; j < 16; j++) {
      const unsigned int pk = splitpack(res[j]);
      if (j < 8) { hv0[j] = (unsigned short)(pk & 0xFFFFu); lv0[j] = (unsigned short)(pk >> 16); }
      else       { hv1[j-8] = (unsigned short)(pk & 0xFFFFu); lv1[j-8] = (unsigned short)(pk >> 16); }
    }
    const size_t qi = ((size_t)b * 512 + ch) * L + t * 16;
    *(u16x8*)&qkSh[qi]     = hv0;
    *(u16x8*)&qkSh[qi + 8] = hv1;
    *(u16x8*)&qkSl[qi]     = lv0;
    *(u16x8*)&qkSl[qi + 8] = lv1;
    s = wave_sum(s); s2 = wave_sum(s2);
    const int lane = t & 63, wid = t >> 6;
    if (lane == 0) { rs[wid][0] = s; rs[wid][1] = s2; }
    __syncthreads();
    if (t == 0) {
      csum[b * 512 + ch]   = rs[0][0] + rs[1][0] + rs[2][0] + rs[3][0];
      csumsq[b * 512 + ch] = rs[0][1] + rs[1][1] + rs[2][1] + rs[3][1];
    }
  } else {
    const size_t vi = ((size_t)b * 256 + (ch - 512)) * L + t * 16;
    #pragma unroll
    for (int j = 0; j < 4; j++) {
      float4 v4;
      v4.x = res[j*4+0]; v4.y = res[j*4+1]; v4.z = res[j*4+2]; v4.w = res[j*4+3];
      *(float4*)&vbuf[vi + j * 4] = v4;
    }
  }
}

// ---------------- rank (stable descending) + sorted stats, one dispatch ----------------
__global__ __launch_bounds__(256) void rankstats_kernel(
    const float* __restrict__ csum, const float* __restrict__ csumsq,
    int* __restrict__ order,
    float* __restrict__ sumq, float* __restrict__ sumk,
    float* __restrict__ invnq, float* __restrict__ invnk)
{
  const int c = threadIdx.x;
  float key = 0.f;
  #pragma unroll
  for (int b = 0; b < 8; b++) key += csum[b * 512 + c];
  __shared__ float keys[256];
  __shared__ int ordS[256];
  keys[c] = key;
  __syncthreads();
  int rank = 0;
  for (int j = 0; j < 256; j++) {
    float kj = keys[j];
    rank += (kj > key) || (kj == key && j < c);
  }
  order[rank] = c;
  ordS[rank] = c;
  __syncthreads();
  const int ch = ordS[c];
  #pragma unroll
  for (int b = 0; b < 8; b++) {
    sumq[b * 256 + c]  = csum[b * 512 + ch];
    invnq[b * 256 + c] = 1.0f / fmaxf(sqrtf(csumsq[b * 512 + ch]), 1e-12f);
    sumk[b * 256 + c]  = csum[b * 512 + 256 + ch];
    invnk[b * 256 + c] = 1.0f / fmaxf(sqrtf(csumsq[b * 512 + 256 + ch]), 1e-12f);
  }
}

// ---------------- pack: vTS = split(v^T sorted) [b][l][r]; zqT = split(qn+kn) [b][l][r] (bf16) ----------------
__global__ __launch_bounds__(256) void vpack_kernel(
    const float* __restrict__ vbuf,
    const unsigned short* __restrict__ qkSh, const unsigned short* __restrict__ qkSl,
    const int* __restrict__ order,
    const float* __restrict__ invnq, const float* __restrict__ invnk,
    unsigned short* __restrict__ vTSh, unsigned short* __restrict__ vTSl,
    unsigned short* __restrict__ zqTh, unsigned short* __restrict__ zqTl)
{
  __shared__ float vt[64][65];
  __shared__ float zt[64][65];
  __shared__ int   ordS[256];
  __shared__ float iqS[256], ikS[256];
  const int t = threadIdx.x, lb = blockIdx.x * 64, b = blockIdx.y;
  ordS[t] = order[t];
  iqS[t] = invnq[b * 256 + t];
  ikS[t] = invnk[b * 256 + t];
  __syncthreads();
  for (int cc = 0; cc < 4; cc++) {
    const int r0 = cc * 64;
    for (int i = t; i < 1024; i += 256) {
      const int row = i >> 4, q = i & 15;
      const int ch = ordS[r0 + row];
      const float iq = iqS[r0 + row], ik = ikS[r0 + row];
      const float4 v4 = *(const float4*)&vbuf[((size_t)b * 256 + ch) * L + lb + q * 4];
      vt[q*4+0][row] = v4.x; vt[q*4+1][row] = v4.y; vt[q*4+2][row] = v4.z; vt[q*4+3][row] = v4.w;
      const size_t qi = ((size_t)b * 512 + ch) * L + lb + q * 4;
      const size_t ki = ((size_t)b * 512 + 256 + ch) * L + lb + q * 4;
      const ushort4 qh4 = *(const ushort4*)&qkSh[qi];
      const ushort4 ql4 = *(const ushort4*)&qkSl[qi];
      const ushort4 kh4 = *(const ushort4*)&qkSh[ki];
      const ushort4 kl4 = *(const ushort4*)&qkSl[ki];
      zt[q*4+0][row] = (bf16_tof(qh4.x)+bf16_tof(ql4.x))*iq + (bf16_tof(kh4.x)+bf16_tof(kl4.x))*ik;
      zt[q*4+1][row] = (bf16_tof(qh4.y)+bf16_tof(ql4.y))*iq + (bf16_tof(kh4.y)+bf16_tof(kl4.y))*ik;
      zt[q*4+2][row] = (bf16_tof(qh4.z)+bf16_tof(ql4.z))*iq + (bf16_tof(kh4.z)+bf16_tof(kl4.z))*ik;
      zt[q*4+3][row] = (bf16_tof(qh4.w)+bf16_tof(ql4.w))*iq + (bf16_tof(kh4.w)+bf16_tof(kl4.w))*ik;
    }
    __syncthreads();
    const int l = t >> 2, qq = t & 3;
    const size_t ob = ((size_t)b * L + lb + l) * 256 + r0 + qq * 16;
    u16x8 vh[2], vl[2], zh[2], zl[2];
    #pragma unroll
    for (int j = 0; j < 16; j++) {
      unsigned int pv = splitpack(vt[l][qq*16 + j]);
      unsigned int pz = splitpack(zt[l][qq*16 + j]);
      vh[j>>3][j&7] = (unsigned short)(pv & 0xFFFFu);
      vl[j>>3][j&7] = (unsigned short)(pv >> 16);
      zh[j>>3][j&7] = (unsigned short)(pz & 0xFFFFu);
      zl[j>>3][j&7] = (unsigned short)(pz >> 16);
    }
    *(u16x8*)&vTSh[ob]     = vh[0]; *(u16x8*)&vTSh[ob + 8] = vh[1];
    *(u16x8*)&vTSl[ob]     = vl[0]; *(u16x8*)&vTSl[ob + 8] = vl[1];
    *(u16x8*)&zqTh[ob]     = zh[0]; *(u16x8*)&zqTh[ob + 8] = zh[1];
    *(u16x8*)&zqTl[ob]     = zl[0]; *(u16x8*)&zqTl[ob + 8] = zl[1];
    __syncthreads();
  }
}

// ---------------- scores via MFMA (bf16 3-pass), 2-phase double-buffered gather staging ----------------
template<int G, int GI, int START, int MB, int SPB>
__device__ void scores_body(const unsigned short* __restrict__ qkSh,
    const unsigned short* __restrict__ qkSl,
    const int* __restrict__ order, float* __restrict__ Spart,
    unsigned short* Ah, unsigned short* Al, unsigned short* Bh, unsigned short* Bl,
    int* ordS)
{
  constexpr int MR = (G - MB * 64 < 64) ? (G - MB * 64) : 64;
  constexpr int NF = G / 16;
  const int t = threadIdx.x, ks = blockIdx.x, b = blockIdx.y;
  const int w = t >> 6, lane = t & 63, ln = lane & 15, lg = lane >> 4;
  const int lrow  = lane >> 2;
  const int chunk = (lane & 3) ^ ((lane >> 4) & 3);
  const int slot  = lg ^ (ln >> 2);
  for (int i = t; i < G; i += 256) ordS[i] = order[START + i];
  __syncthreads();
  const int k0 = ks * 512;
  const bool act = (w * 16) < MR;
  f32x4 z4 = {0.f, 0.f, 0.f, 0.f};
  f32x4 acc[NF];
  #pragma unroll
  for (int i = 0; i < NF; i++) acc[i] = z4;

  auto stage = [&](int kc, int cb) {
    for (int i = w; i < MR / 16; i += 4) {
      const int rb = i * 16;
      const int ch = ordS[MB * 64 + rb + lrow];
      const size_t g = ((size_t)b * 512 + ch) * L + k0 + kc + chunk * 8;
      gl16(qkSh + g, &Ah[cb * 2048 + rb * 32]);
      gl16(qkSl + g, &Al[cb * 2048 + rb * 32]);
    }
    for (int i = w; i < G / 16; i += 4) {
      const int rb = i * 16;
      const int ch = 256 + ordS[rb + lrow];
      const size_t g = ((size_t)b * 512 + ch) * L + k0 + kc + chunk * 8;
      gl16(qkSh + g, &Bh[cb * 3072 + rb * 32]);
      gl16(qkSl + g, &Bl[cb * 3072 + rb * 32]);
    }
  };

  stage(0, 0);
  __syncthreads();
  int cur = 0;
  for (int kc = 0; kc < 512; kc += 32) {
    if (kc + 32 < 512) stage(kc + 32, cur ^ 1);
    if (act) {
      const int aoff = cur * 2048 + (w * 16 + ln) * 32 + slot * 8;
      const short8v ah = *(const short8v*)&Ah[aoff];
      const short8v al = *(const short8v*)&Al[aoff];
      #pragma unroll
      for (int nf = 0; nf < NF; nf++) {
        const int boff = cur * 3072 + (nf * 16 + ln) * 32 + slot * 8;
        const short8v bh = *(const short8v*)&Bh[boff];
        const short8v bl = *(const short8v*)&Bl[boff];
        acc[nf] = __builtin_amdgcn_mfma_f32_16x16x32_bf16(ah, bh, acc[nf], 0, 0, 0);
        acc[nf] = __builtin_amdgcn_mfma_f32_16x16x32_bf16(ah, bl, acc[nf], 0, 0, 0);
        acc[nf] = __builtin_amdgcn_mfma_f32_16x16x32_bf16(al, bh, acc[nf], 0, 0, 0);
      }
    }
    __syncthreads();
    cur ^= 1;
  }
  if (act) {
    float* dst = Spart + (size_t)b * 147456 + SPB + ks * G * G;
    #pragma unroll
    for (int nf = 0; nf < NF; nf++) {
      const int d = nf * 16 + ln;
      #pragma unroll
      for (int r = 0; r < 4; r++) {
        const int m = MB * 64 + w * 16 + lg * 4 + r;
        dst[m * G + d] = acc[nf][r];
      }
    }
  }
}

__global__ __launch_bounds__(256) void scores_kernel(const unsigned short* __restrict__ qkSh,
    const unsigned short* __restrict__ qkSl,
    const int* __restrict__ order, float* __restrict__ Spart)
{
  __shared__ unsigned short Ah[2 * 64 * 32];
  __shared__ unsigned short Al[2 * 64 * 32];
  __shared__ unsigned short Bh[2 * 96 * 32];
  __shared__ unsigned short Bl[2 * 96 * 32];
  __shared__ int ordS[96];
  switch (blockIdx.z) {
    case 0:  scores_body<32, 0, 0,   0, 0    >(qkSh, qkSl, order, Spart, Ah, Al, Bh, Bl, ordS); break;
    case 1:  scores_body<64, 1, 32,  0, 8192 >(qkSh, qkSl, order, Spart, Ah, Al, Bh, Bl, ordS); break;
    case 2:  scores_body<64, 2, 96,  0, 40960>(qkSh, qkSl, order, Spart, Ah, Al, Bh, Bl, ordS); break;
    case 3:  scores_body<96, 3, 160, 0, 73728>(qkSh, qkSl, order, Spart, Ah, Al, Bh, Bl, ordS); break;
    default: scores_body<96, 3, 160, 1, 73728>(qkSh, qkSl, order, Spart, Ah, Al, Bh, Bl, ordS); break;
  }
}

// ---------------- reduce partials, scale, wave-parallel softmax, emit hi/lo bf16 attn ----------------
template<int G, int GI, int START, int SPB, int AOFF>
__device__ void softmax_body(const float* __restrict__ Spart, const float* __restrict__ invnq,
    const float* __restrict__ invnk, const float* __restrict__ temperature,
    unsigned short* __restrict__ attnPh, unsigned short* __restrict__ attnPl, float* Sm)
{
  const int t = threadIdx.x;
  const int b = blockIdx.x;
  const float temp = temperature[GI];
  for (int idx = t; idx < G * G; idx += 256) {
    float s = 0.f;
    #pragma unroll
    for (int ks = 0; ks < 8; ks++)
      s += Spart[(size_t)b * 147456 + SPB + ks * G * G + idx];
    const int c = idx / G, d = idx - c * G;
    Sm[idx] = s * invnq[b * 256 + START + c] * invnk[b * 256 + START + d] * temp;
  }
  __syncthreads();
  const int wv = t >> 6, lane = t & 63;
  for (int r = wv; r < G; r += 4) {
    const float v0 = (lane < G) ? Sm[r * G + lane] : -INFINITY;
    const float v1 = (64 + lane < G) ? Sm[r * G + 64 + lane] : -INFINITY;
    float m = fmaxf(v0, v1);
    #pragma unroll
    for (int off = 32; off > 0; off >>= 1) m = fmaxf(m, __shfl_xor(m, off, 64));
    const float e0 = (lane < G) ? expf(v0 - m) : 0.f;
    const float e1 = (64 + lane < G) ? expf(v1 - m) : 0.f;
    float s = e0 + e1;
    #pragma unroll
    for (int off = 32; off > 0; off >>= 1) s += __shfl_xor(s, off, 64);
    const float inv = 1.0f / s;
    const size_t base = (size_t)b * 18432 + AOFF + r * G;
    if (lane < G) {
      const unsigned int p = splitpack(e0 * inv);
      attnPh[base + lane] = (unsigned short)(p & 0xFFFFu);
      attnPl[base + lane] = (unsigned short)(p >> 16);
    }
    if (64 + lane < G) {
      const unsigned int p = splitpack(e1 * inv);
      attnPh[base + 64 + lane] = (unsigned short)(p & 0xFFFFu);
      attnPl[base + 64 + lane] = (unsigned short)(p >> 16);
    }
  }
}

__global__ __launch_bounds__(256) void softmax_kernel(const float* __restrict__ Spart,
    const float* __restrict__ invnq, const float* __restrict__ invnk,
    const float* __restrict__ temperature,
    unsigned short* __restrict__ attnPh, unsigned short* __restrict__ attnPl)
{
  extern __shared__ float smem[];
  switch (blockIdx.y) {
    case 0:  softmax_body<32, 0, 0,   0,     0   >(Spart, invnq, invnk, temperature, attnPh, attnPl, smem); break;
    case 1:  softmax_body<64, 1, 32,  8192,  1024>(Spart, invnq, invnk, temperature, attnPh, attnPl, smem); break;
    case 2:  softmax_body<64, 2, 96,  40960, 5120>(Spart, invnq, invnk, temperature, attnPh, attnPl, smem); break;
    default: softmax_body<96, 3, 160, 73728, 9216>(Spart, invnq, invnk, temperature, attnPh, attnPl, smem); break;
  }
}

// ---------------- PV via MFMA (bf16 3-pass), fused z epilogue -> f16 pairs ----------------
template<int G, int GI, int START, int AOFF>
__device__ void pv_body(
    const unsigned short* __restrict__ vTSh, const unsigned short* __restrict__ vTSl,
    const unsigned short* __restrict__ attnPh, const unsigned short* __restrict__ attnPl,
    const unsigned short* __restrict__ zqTh, const unsigned short* __restrict__ zqTl,
    unsigned short* __restrict__ outTh, unsigned short* __restrict__ outTl,
    unsigned short* __restrict__ zTh, unsigned short* __restrict__ zTl,
    unsigned short* Ah, unsigned short* Al, unsigned short* Bh, unsigned short* Bl)
{
  constexpr int NF = G / 16;
  const int t = threadIdx.x, b = blockIdx.y, l0 = blockIdx.x * 128;
  const int w = t >> 6, lane = t & 63, ln = lane & 15, lg = lane >> 4;
  const int lrow  = lane >> 2;
  const int chunk = (lane & 3) ^ ((lane >> 4) & 3);
  const int slot  = lg ^ (ln >> 2);
  f32x4 z4 = {0.f, 0.f, 0.f, 0.f};
  f32x4 acc[2][NF];
  #pragma unroll
  for (int i = 0; i < 2; i++)
    #pragma unroll
    for (int j = 0; j < NF; j++) acc[i][j] = z4;
  for (int kc = 0; kc < G; kc += 32) {
    #pragma unroll
    for (int i = 0; i < 2; i++) {
      const int rb = w * 32 + i * 16;
      const size_t g = ((size_t)b * L + l0 + rb + lrow) * 256 + START + kc + chunk * 8;
      gl16(vTSh + g, &Ah[rb * 32]);
      gl16(vTSl + g, &Al[rb * 32]);
    }
    for (int i = w; i < G / 16; i += 4) {
      const int rb = i * 16;
      const size_t g = (size_t)b * 18432 + AOFF + (size_t)(rb + lrow) * G + kc + chunk * 8;
      gl16(attnPh + g, &Bh[rb * 32]);
      gl16(attnPl + g, &Bl[rb * 32]);
    }
    __syncthreads();
    short8v bhf[NF], blf[NF];
    #pragma unroll
    for (int nf = 0; nf < NF; nf++) {
      const int boff = (nf * 16 + ln) * 32 + slot * 8;
      bhf[nf] = *(const short8v*)&Bh[boff];
      blf[nf] = *(const short8v*)&Bl[boff];
    }
    #pragma unroll
    for (int mi = 0; mi < 2; mi++) {
      const int aoff = ((w * 2 + mi) * 16 + ln) * 32 + slot * 8;
      const short8v ah = *(const short8v*)&Ah[aoff];
      const short8v al = *(const short8v*)&Al[aoff];
      #pragma unroll
      for (int nf = 0; nf < NF; nf++) {
        acc[mi][nf] = __builtin_amdgcn_mfma_f32_16x16x32_bf16(ah, bhf[nf], acc[mi][nf], 0, 0, 0);
        acc[mi][nf] = __builtin_amdgcn_mfma_f32_16x16x32_bf16(ah, blf[nf], acc[mi][nf], 0, 0, 0);
        acc[mi][nf] = __builtin_amdgcn_mfma_f32_16x16x32_bf16(al, bhf[nf], acc[mi][nf], 0, 0, 0);
      }
    }
    __syncthreads();
  }
  #pragma unroll
  for (int mi = 0; mi < 2; mi++) {
    const int lbase = l0 + (w * 2 + mi) * 16 + lg * 4;
    #pragma unroll
    for (int nf = 0; nf < NF; nf++) {
      const int col = START + nf * 16 + ln;
      #pragma unroll
      for (int r = 0; r < 4; r++) {
        const size_t idx = ((size_t)b * L + lbase + r) * 256 + col;
        const float v = acc[mi][nf][r];
        const unsigned int po = splitpackh(v);
        outTh[idx] = (unsigned short)(po & 0xFFFFu);
        outTl[idx] = (unsigned short)(po >> 16);
        const float zq = bf16_tof(zqTh[idx]) + bf16_tof(zqTl[idx]);
        const unsigned int pz = splitpackh(v + zq);
        zTh[idx] = (unsigned short)(pz & 0xFFFFu);
        zTl[idx] = (unsigned short)(pz >> 16);
      }
    }
  }
}

__global__ __launch_bounds__(256) void pv_kernel(
    const unsigned short* __restrict__ vTSh, const unsigned short* __restrict__ vTSl,
    const unsigned short* __restrict__ attnPh, const unsigned short* __restrict__ attnPl,
    const unsigned short* __restrict__ zqTh, const unsigned short* __restrict__ zqTl,
    unsigned short* __restrict__ outTh, unsigned short* __restrict__ outTl,
    unsigned short* __restrict__ zTh, unsigned short* __restrict__ zTl)
{
  __shared__ unsigned short Ah[128 * 32];
  __shared__ unsigned short Al[128 * 32];
  __shared__ unsigned short Bh[96 * 32];
  __shared__ unsigned short Bl[96 * 32];
  switch (blockIdx.z) {
    case 0:  pv_body<32, 0, 0,   0   >(vTSh, vTSl, attnPh, attnPl, zqTh, zqTl, outTh, outTl, zTh, zTl, Ah, Al, Bh, Bl); break;
    case 1:  pv_body<64, 1, 32,  1024>(vTSh, vTSl, attnPh, attnPl, zqTh, zqTl, outTh, outTl, zTh, zTl, Ah, Al, Bh, Bl); break;
    case 2:  pv_body<64, 2, 96,  5120>(vTSh, vTSl, attnPh, attnPl, zqTh, zqTl, outTh, outTl, zTh, zTl, Ah, Al, Bh, Bl); break;
    default: pv_body<96, 3, 160, 9216>(vTSh, vTSl, attnPh, attnPl, zqTh, zqTl, outTh, outTl, zTh, zTl, Ah, Al, Bh, Bl); break;
  }
}

// ---------------- qv_cache ----------------
__global__ __launch_bounds__(256) void qv_kernel(const float* __restrict__ sumq,
    const float* __restrict__ sumk, const float* __restrict__ invnq,
    const float* __restrict__ invnk, float* __restrict__ out2)
{
  const int b = blockIdx.x >> 8, r = blockIdx.x & 255;
  float val = 0.f;
  {
    const int idx = b * 256 + 0 + (r & 31);
    val += fmaf(sumq[idx], invnq[idx], sumk[idx] * invnk[idx]);
  }
  {
    const int idx = b * 256 + 32 + (r & 63);
    val += fmaf(sumq[idx], invnq[idx], sumk[idx] * invnk[idx]);
  }
  {
    const int idx = b * 256 + 96 + (r & 63);
    val += fmaf(sumq[idx], invnq[idx], sumk[idx] * invnk[idx]);
  }
  if (r < 192) {
    const int rm = (r < 96) ? r : r - 96;
    const int idx = b * 256 + 160 + rm;
    val += fmaf(sumq[idx], invnq[idx], sumk[idx] * invnk[idx]);
  }
  val *= (1.0f / 4096.f) * 0.25f * 0.9f;
  const float4 o = {val, val, val, val};
  float4* dst = reinterpret_cast<float4*>(out2 + ((size_t)b * C + r) * L);
  for (int i = threadIdx.x; i < 1024; i += 256) dst[i] = o;
}

// ---------------- launch ----------------
extern "C" void kernel_launch(void* const* d_in, const int* in_sizes, int n_in,
                              void* d_out, int out_size, void* d_ws, size_t ws_size,
                              hipStream_t stream)
{
  const float* x           = (const float*)d_in[0];
  const float* temperature = (const float*)d_in[1];
  const float* w_qkv       = (const float*)d_in[2];
  const float* w_dw        = (const float*)d_in[3];
  const float* w_proj      = (const float*)d_in[4];
  const float* w_gate      = (const float*)d_in[5];
  const float* b_gate      = (const float*)d_in[6];
  const float* w_down      = (const float*)d_in[7];
  const float* b_down      = (const float*)d_in[8];
  const float* w_up        = (const float*)d_in[9];
  const float* b_up        = (const float*)d_in[10];

  if (ws_size < 202548224ULL) return;

  char* ws = (char*)d_ws;
  // Region A [0, 96M):
  float*          qkv_pre  = (float*)(ws);                        // 96MB, dead after dwconv
  unsigned short* vTSh     = (unsigned short*)(ws);                // 16MB
  unsigned short* vTSl     = (unsigned short*)(ws + 16777216);     // 16MB
  unsigned short* zqTh     = (unsigned short*)(ws + 33554432);     // 16MB
  unsigned short* zqTl     = (unsigned short*)(ws + 50331648);     // 16MB
  float*          Spart    = (float*)(ws + 67108864);              // 4.72MB
  unsigned short* attnPh   = (unsigned short*)(ws + 73400320);     // 288KB
  unsigned short* attnPl   = (unsigned short*)(ws + 74448896);     // 288KB
  unsigned short* preprojh = (unsigned short*)(ws);                // 16MB (after pv; bf16)
  unsigned short* preprojl = (unsigned short*)(ws + 16777216);     // 16MB
  // Region B [96M, 192M):
  unsigned short* XThi     = (unsigned short*)(ws + 100663296);    // 16MB (f16)
  unsigned short* XTlo     = (unsigned short*)(ws + 117440512);    // 16MB
  unsigned short* qkSh     = (unsigned short*)(ws + 100663296);    // 32MB (after qkv gemm; bf16)
  unsigned short* qkSl     = (unsigned short*)(ws + 134217728);    // 32MB
  float*          vbuf     = (float*)(ws + 167772160);             // 32MB
  unsigned short* outTh    = (unsigned short*)(ws + 100663296);    // 16MB (after scores; f16)
  unsigned short* outTl    = (unsigned short*)(ws + 117440512);    // 16MB
  unsigned short* zTh      = (unsigned short*)(ws + 134217728);    // 16MB (f16)
  unsigned short* zTl      = (unsigned short*)(ws + 150994944);    // 16MB
  unsigned short* gatedh   = (unsigned short*)(ws + 167772160);    // 16MB (after vpack; f16)
  unsigned short* gatedl   = (unsigned short*)(ws + 184549376);    // 16MB
  unsigned short* midh     = (unsigned short*)(ws + 134217728);    // 8MB (after gate gemm; f16)
  unsigned short* midl     = (unsigned short*)(ws + 142606336);    // 8MB
  // Region C [192M+, persistent):
  unsigned short* Wf16   = (unsigned short*)(ws + 201326592);      // 655360 B (327680 f16)
  unsigned short* WprojH = (unsigned short*)(ws + 201981952);      // 128KB
  unsigned short* WprojL = (unsigned short*)(ws + 202113024);      // 128KB
  float* csum   = (float*)(ws + 202244096);                        // 16KB
  float* csumsq = (float*)(ws + 202260480);                        // 16KB
  float* sumq   = (float*)(ws + 202276864);                        // 8KB
  float* sumk   = (float*)(ws + 202285056);                        // 8KB
  float* invnq  = (float*)(ws + 202293248);                        // 8KB
  float* invnk  = (float*)(ws + 202301440);                        // 8KB
  int*   order  = (int*)(ws + 202309632);                          // 1KB

  float* out_all = (float*)d_out;
  float* qv_out  = out_all + (size_t)B * C * L;

  // 0. weight + input splits
  wsplit_kernel<<<1536, 256, 0, stream>>>(w_qkv, w_gate, w_down, w_up, w_proj,
                                          Wf16, WprojH, WprojL);
  splitx_kernel<<<dim3(64, 4, 8), 256, 0, stream>>>(x, XThi, XTlo);
  // 1. qkv = w_qkv @ x  (f16 2-pass MFMA, out fp32 [b][768][L])
  hgemm<256, 0><<<dim3(32, 6, 8), 256, 0, stream>>>(
      XThi, XTlo, Wf16, qkv_pre, nullptr, nullptr, nullptr, nullptr, nullptr, 768);
  // 2. depthwise conv (+ split-pack q,k bf16 hi/lo; v fp32; channel stats)
  dwconv2_kernel<<<dim3(768, 8), 256, 0, stream>>>(qkv_pre, w_dw, qkSh, qkSl, vbuf, csum, csumsq);
  // 3. channel ordering + sorted stats (one dispatch)
  rankstats_kernel<<<1, 256, 0, stream>>>(csum, csumsq, order, sumq, sumk, invnq, invnk);
  // 4. pack v^T + zq (bf16 hi/lo)
  vpack_kernel<<<dim3(64, 8), 256, 0, stream>>>(vbuf, qkSh, qkSl, order, invnq, invnk,
                                                vTSh, vTSl, zqTh, zqTl);
  // 5. attention
  scores_kernel<<<dim3(8, 8, 5), 256, 0, stream>>>(qkSh, qkSl, order, Spart);
  softmax_kernel<<<dim3(8, 4), 256, 36864, stream>>>(Spart, invnq, invnk, temperature, attnPh, attnPl);
  pv_kernel<<<dim3(32, 8, 4), 256, 0, stream>>>(vTSh, vTSl, attnPh, attnPl, zqTh, zqTl,
                                                outTh, outTl, zTh, zTl);
  // 6. MLP chain (f16 2-pass)
  hgemm<256, 2><<<dim3(32, 2, 8), 256, 0, stream>>>(
      zTh, zTl, Wf16 + 196608, nullptr, gatedh, gatedl, b_gate, zTh, zTl, 256);
  hgemm<256, 1><<<dim3(32, 1, 8), 256, 0, stream>>>(
      gatedh, gatedl, Wf16 + 262144, nullptr, midh, midl, b_down, nullptr, nullptr, 128);
  hgemm<128, 5><<<dim3(32, 2, 8), 256, 0, stream>>>(
      midh, midl, Wf16 + 294912, nullptr, preprojh, preprojl, b_up, outTh, outTl, 256);
  // 7. final projection (bf16 3-pass precision firewall) -> output 0
  mgemm<256><<<dim3(32, 2, 8), 256, 0, stream>>>(
      preprojh, preprojl, WprojH, WprojL, out_all, 256);
  // 8. qv_cache -> output 1
  qv_kernel<<<2048, 256, 0, stream>>>(sumq, sumk, invnq, invnk, qv_out);
}

// Round 7
// 300.045 us; speedup vs baseline: 2.0006x; 1.0743x over previous
//
#include <hip/hip_runtime.h>
#include <hip/hip_fp16.h>
#include <math.h>

#define B 8
#define C 256
#define L 4096
#define OC3 768

typedef __attribute__((ext_vector_type(8))) short short8v;
typedef __attribute__((ext_vector_type(8))) unsigned short u16x8;
typedef __attribute__((ext_vector_type(4))) float f32x4;

// ---------------- helpers ----------------
__device__ __forceinline__ float gelu_exact(float x){
  return 0.5f * x * (1.0f + erff(x * 0.70710678118654752440f));
}
__device__ __forceinline__ float wave_sum(float v){
  #pragma unroll
  for (int off = 32; off > 0; off >>= 1) v += __shfl_down(v, off, 64);
  return v;
}
__device__ __forceinline__ unsigned short bf16_rne(float f){
  unsigned int u = __float_as_uint(f);
  unsigned int r = u + 0x7FFFu + ((u >> 16) & 1u);
  return (unsigned short)(r >> 16);
}
__device__ __forceinline__ float bf16_tof(unsigned short h){
  return __uint_as_float(((unsigned int)h) << 16);
}
// bf16 split pair in one u32: low16 = hi, high16 = lo
__device__ __forceinline__ unsigned int splitpack(float v){
  unsigned short hi = bf16_rne(v);
  float lof = v - bf16_tof(hi);
  unsigned short lo = bf16_rne(lof);
  return (unsigned int)hi | ((unsigned int)lo << 16);
}
// f16 helpers
__device__ __forceinline__ unsigned short f16b(float f){
  return __half_as_ushort(__float2half_rn(f));
}
__device__ __forceinline__ float f16tof(unsigned short u){
  return __half2float(__ushort_as_half(u));
}
// f16 split pair in one u32: low16 = hi, high16 = lo
__device__ __forceinline__ unsigned int splitpackh(float v){
  unsigned short hi = f16b(v);
  float lof = v - f16tof(hi);
  unsigned short lo = f16b(lof);
  return (unsigned int)hi | ((unsigned int)lo << 16);
}
// async global->LDS 16B per lane; LDS dest must be wave-uniform base
__device__ __forceinline__ void gl16(const unsigned short* g, unsigned short* l){
  __builtin_amdgcn_global_load_lds(
      (const __attribute__((address_space(1))) void*)g,
      (__attribute__((address_space(3))) void*)l, 16, 0, 0);
}

// ---------------- weight split ----------------
__global__ __launch_bounds__(256) void wsplit_kernel(
    const float* __restrict__ wqkv, const float* __restrict__ wgate,
    const float* __restrict__ wdown, const float* __restrict__ wup,
    const float* __restrict__ wproj,
    unsigned short* __restrict__ Wf16,
    unsigned short* __restrict__ PH, unsigned short* __restrict__ PLo)
{
  int idx = blockIdx.x * 256 + threadIdx.x;   // 0..393215
  if (idx < 327680) {
    float s;
    if (idx < 196608)      s = wqkv[idx];
    else if (idx < 262144) s = wgate[idx - 196608];
    else if (idx < 294912) s = wdown[idx - 262144];
    else                   s = wup[idx - 294912];
    Wf16[idx] = f16b(s);
  } else {
    int j = idx - 327680;   // 0..65535
    unsigned int p = splitpack(wproj[j]);
    PH[j] = (unsigned short)(p & 0xFFFFu); PLo[j] = (unsigned short)(p >> 16);
  }
}

// ---------------- x [b][c][l] fp32 -> xT hi/lo f16 [b][l][c] ----------------
__global__ __launch_bounds__(256) void splitx_kernel(const float* __restrict__ x,
    unsigned short* __restrict__ XThi, unsigned short* __restrict__ XTlo)
{
  __shared__ float st[64][68];
  const int b = blockIdx.z, c0 = blockIdx.y * 64, lb = blockIdx.x * 64;
  const int t = threadIdx.x;
  #pragma unroll
  for (int i = 0; i < 4; i++) {
    int row = (t >> 4) + i * 16;
    int col = (t & 15) * 4;
    float4 v = *(const float4*)&x[((size_t)b * C + c0 + row) * L + lb + col];
    st[row][col] = v.x; st[row][col+1] = v.y; st[row][col+2] = v.z; st[row][col+3] = v.w;
  }
  __syncthreads();
  const int l = t >> 2, cq = t & 3;
  u16x8 hv0, hv1, lv0, lv1;
  #pragma unroll
  for (int i = 0; i < 16; i++) {
    unsigned int p = splitpackh(st[cq * 16 + i][l]);
    if (i < 8) { hv0[i] = (unsigned short)(p & 0xFFFFu); lv0[i] = (unsigned short)(p >> 16); }
    else       { hv1[i-8] = (unsigned short)(p & 0xFFFFu); lv1[i-8] = (unsigned short)(p >> 16); }
  }
  size_t o = ((size_t)b * L + lb + l) * C + c0 + cq * 16;
  *(u16x8*)&XThi[o]     = hv0;
  *(u16x8*)&XThi[o + 8] = hv1;
  *(u16x8*)&XTlo[o]     = lv0;
  *(u16x8*)&XTlo[o + 8] = lv1;
}

// ---------------- f16 2-pass MFMA GEMM, 2-phase double-buffered ----------------
template<int KTOT, int EPI>
__global__ __launch_bounds__(256) void hgemm(
    const unsigned short* __restrict__ Ahi_g, const unsigned short* __restrict__ Alo_g,
    const unsigned short* __restrict__ Bw_g,
    float* __restrict__ outF,
    unsigned short* __restrict__ outH, unsigned short* __restrict__ outLo,
    const float* __restrict__ bias,
    const unsigned short* __restrict__ extraH, const unsigned short* __restrict__ extraLo,
    int Ntot)
{
  __shared__ unsigned short SB[2][3][128 * 32];   // [buf][Ah,Al,Bw]
  const int t  = threadIdx.x;
  const int lb = blockIdx.x * 128;
  const int o0 = blockIdx.y * 128;
  const int b  = blockIdx.z;
  const int w  = t >> 6, lane = t & 63;
  const int wm = w >> 1, wn = w & 1;
  const int ln = lane & 15, lg = lane >> 4;
  const int lrow  = lane >> 2;
  const int chunk = (lane & 3) ^ ((lane >> 4) & 3);
  const int slot  = lg ^ (ln >> 2);

  f32x4 z4 = {0.f, 0.f, 0.f, 0.f};
  f32x4 acc[4][4];
  #pragma unroll
  for (int i = 0; i < 4; i++)
    #pragma unroll
    for (int j = 0; j < 4; j++) acc[i][j] = z4;

  const size_t arow0 = (size_t)b * L + lb;
  constexpr int NKT = KTOT / 32;

  auto stage = [&](int kt, int cb) {
    const int k0 = kt * 32;
    #pragma unroll
    for (int i = 0; i < 2; i++) {
      const int rb = w * 32 + i * 16;
      const size_t ga = (arow0 + rb + lrow) * KTOT + k0 + chunk * 8;
      gl16(Ahi_g + ga, &SB[cb][0][rb * 32]);
      gl16(Alo_g + ga, &SB[cb][1][rb * 32]);
      const size_t gb = (size_t)(o0 + rb + lrow) * KTOT + k0 + chunk * 8;
      gl16(Bw_g + gb, &SB[cb][2][rb * 32]);
    }
  };

  stage(0, 0);
  __syncthreads();
  int cur = 0;
  for (int kt = 0; kt < NKT; ++kt) {
    if (kt + 1 < NKT) stage(kt + 1, cur ^ 1);
    short8v bwf[4];
    #pragma unroll
    for (int nf = 0; nf < 4; nf++) {
      const int off = (wn * 64 + nf * 16 + ln) * 32 + slot * 8;
      bwf[nf] = *(const short8v*)&SB[cur][2][off];
    }
    #pragma unroll
    for (int mf = 0; mf < 4; mf++) {
      const int off = (wm * 64 + mf * 16 + ln) * 32 + slot * 8;
      const short8v ah = *(const short8v*)&SB[cur][0][off];
      const short8v al = *(const short8v*)&SB[cur][1][off];
      #pragma unroll
      for (int nf = 0; nf < 4; nf++) {
        acc[mf][nf] = __builtin_amdgcn_mfma_f32_16x16x32_f16(ah, bwf[nf], acc[mf][nf], 0, 0, 0);
        acc[mf][nf] = __builtin_amdgcn_mfma_f32_16x16x32_f16(al, bwf[nf], acc[mf][nf], 0, 0, 0);
      }
    }
    __syncthreads();
    cur ^= 1;
  }
  #pragma unroll
  for (int mf = 0; mf < 4; mf++) {
    const int mbase = lb + wm * 64 + mf * 16 + lg * 4;
    #pragma unroll
    for (int nf = 0; nf < 4; nf++) {
      const int o = o0 + wn * 64 + nf * 16 + ln;
      if (EPI == 0) {
        float4 r;
        r.x = acc[mf][nf][0]; r.y = acc[mf][nf][1];
        r.z = acc[mf][nf][2]; r.w = acc[mf][nf][3];
        *(float4*)&outF[((size_t)b * Ntot + o) * L + mbase] = r;
      } else {
        const float bv = bias ? bias[o] : 0.0f;
        #pragma unroll
        for (int r = 0; r < 4; r++) {
          const size_t idx = ((size_t)b * L + mbase + r) * Ntot + o;
          float v = acc[mf][nf][r] + bv;
          if (EPI == 2) { v = gelu_exact(v) * (f16tof(extraH[idx]) + f16tof(extraLo[idx])); }
          if (EPI == 5) { v = v + f16tof(extraH[idx]) + f16tof(extraLo[idx]); }
          unsigned int p;
          if (EPI == 5) p = splitpack(v);   // bf16 pair for proj
          else          p = splitpackh(v);  // f16 pair
          outH[idx]  = (unsigned short)(p & 0xFFFFu);
          outLo[idx] = (unsigned short)(p >> 16);
        }
      }
    }
  }
}

// ---------------- bf16 3-pass MFMA GEMM (proj only), 2-phase double-buffered ----------------
template<int KTOT>
__global__ __launch_bounds__(256) void mgemm(
    const unsigned short* __restrict__ Ahi_g, const unsigned short* __restrict__ Alo_g,
    const unsigned short* __restrict__ Bhi_g, const unsigned short* __restrict__ Blo_g,
    float* __restrict__ outF, int Ntot)
{
  __shared__ unsigned short SB[2][4][128 * 32];
  const int t  = threadIdx.x;
  const int lb = blockIdx.x * 128;
  const int o0 = blockIdx.y * 128;
  const int b  = blockIdx.z;
  const int w  = t >> 6, lane = t & 63;
  const int wm = w >> 1, wn = w & 1;
  const int ln = lane & 15, lg = lane >> 4;
  const int lrow  = lane >> 2;
  const int chunk = (lane & 3) ^ ((lane >> 4) & 3);
  const int slot  = lg ^ (ln >> 2);

  f32x4 z4 = {0.f, 0.f, 0.f, 0.f};
  f32x4 acc[4][4];
  #pragma unroll
  for (int i = 0; i < 4; i++)
    #pragma unroll
    for (int j = 0; j < 4; j++) acc[i][j] = z4;

  const size_t arow0 = (size_t)b * L + lb;
  constexpr int NKT = KTOT / 32;

  auto stage = [&](int kt, int cb) {
    const int k0 = kt * 32;
    #pragma unroll
    for (int i = 0; i < 2; i++) {
      const int rb = w * 32 + i * 16;
      const size_t ga = (arow0 + rb + lrow) * KTOT + k0 + chunk * 8;
      gl16(Ahi_g + ga, &SB[cb][0][rb * 32]);
      gl16(Alo_g + ga, &SB[cb][1][rb * 32]);
      const size_t gb = (size_t)(o0 + rb + lrow) * KTOT + k0 + chunk * 8;
      gl16(Bhi_g + gb, &SB[cb][2][rb * 32]);
      gl16(Blo_g + gb, &SB[cb][3][rb * 32]);
    }
  };

  stage(0, 0);
  __syncthreads();
  int cur = 0;
  for (int kt = 0; kt < NKT; ++kt) {
    if (kt + 1 < NKT) stage(kt + 1, cur ^ 1);
    short8v bhf[4], blf[4];
    #pragma unroll
    for (int nf = 0; nf < 4; nf++) {
      const int off = (wn * 64 + nf * 16 + ln) * 32 + slot * 8;
      bhf[nf] = *(const short8v*)&SB[cur][2][off];
      blf[nf] = *(const short8v*)&SB[cur][3][off];
    }
    #pragma unroll
    for (int mf = 0; mf < 4; mf++) {
      const int off = (wm * 64 + mf * 16 + ln) * 32 + slot * 8;
      const short8v ah = *(const short8v*)&SB[cur][0][off];
      const short8v al = *(const short8v*)&SB[cur][1][off];
      #pragma unroll
      for (int nf = 0; nf < 4; nf++) {
        acc[mf][nf] = __builtin_amdgcn_mfma_f32_16x16x32_bf16(ah, bhf[nf], acc[mf][nf], 0, 0, 0);
        acc[mf][nf] = __builtin_amdgcn_mfma_f32_16x16x32_bf16(ah, blf[nf], acc[mf][nf], 0, 0, 0);
        acc[mf][nf] = __builtin_amdgcn_mfma_f32_16x16x32_bf16(al, bhf[nf], acc[mf][nf], 0, 0, 0);
      }
    }
    __syncthreads();
    cur ^= 1;
  }
  #pragma unroll
  for (int mf = 0; mf < 4; mf++) {
    const int mbase = lb + wm * 64 + mf * 16 + lg * 4;
    #pragma unroll
    for (int nf = 0; nf < 4; nf++) {
      const int o = o0 + wn * 64 + nf * 16 + ln;
      float4 r;
      r.x = acc[mf][nf][0]; r.y = acc[mf][nf][1];
      r.z = acc[mf][nf][2]; r.w = acc[mf][nf][3];
      *(float4*)&outF[((size_t)b * Ntot + o) * L + mbase] = r;
    }
  }
}

// ---------------- depthwise 3x3 conv: halo-padded branchless, conflict-free LDS ----------------
// LDS p[66][73]: image pixel (h,w) -> p[h+1][w+4]; stride 73 (odd) => <=2-way banks
__global__ __launch_bounds__(256) void dwconv2_kernel(
    const float* __restrict__ in, const float* __restrict__ wdw,
    unsigned short* __restrict__ qkSh, unsigned short* __restrict__ qkSl,
    float* __restrict__ vbuf,
    float* __restrict__ csum, float* __restrict__ csumsq)
{
  __shared__ float p[66][73];
  __shared__ float rs[4][2];
  const int ch = blockIdx.x;
  const int b  = blockIdx.y;
  const int t  = threadIdx.x;
  const size_t base = ((size_t)b * OC3 + ch) * L;
  float wt[9];
  #pragma unroll
  for (int j = 0; j < 9; j++) wt[j] = wdw[ch * 9 + j];
  // halo zeroing (rows 0,65 cols 3..68; cols 3,68 rows 1..64)
  if (t < 66) { p[0][3 + t] = 0.f; p[65][3 + t] = 0.f; }
  if (t < 64) { p[1 + t][3] = 0.f; p[1 + t][68] = 0.f; }
  // main plane load
  #pragma unroll
  for (int i = 0; i < 4; i++) {
    int pix = (i * 256 + t) * 4;
    const float4 v = *reinterpret_cast<const float4*>(&in[base + pix]);
    int h = pix >> 6, ww = pix & 63;
    p[1+h][4+ww] = v.x; p[1+h][5+ww] = v.y; p[1+h][6+ww] = v.z; p[1+h][7+ww] = v.w;
  }
  __syncthreads();
  const int h  = t >> 2;
  const int w0 = (t & 3) * 16;
  // register rows: 3 x 18 cols, loaded once
  float r0a[18], r1a[18], r2a[18];
  #pragma unroll
  for (int c = 0; c < 18; c++) {
    r0a[c] = p[h][w0 + 3 + c];
    r1a[c] = p[h + 1][w0 + 3 + c];
    r2a[c] = p[h + 2][w0 + 3 + c];
  }
  float res[16];
  float s = 0.f, s2 = 0.f;
  #pragma unroll
  for (int j = 0; j < 16; j++) {
    float acc;
    acc = r0a[j] * wt[0];
    acc = fmaf(r0a[j+1], wt[1], acc);
    acc = fmaf(r0a[j+2], wt[2], acc);
    acc = fmaf(r1a[j],   wt[3], acc);
    acc = fmaf(r1a[j+1], wt[4], acc);
    acc = fmaf(r1a[j+2], wt[5], acc);
    acc = fmaf(r2a[j],   wt[6], acc);
    acc = fmaf(r2a[j+1], wt[7], acc);
    acc = fmaf(r2a[j+2], wt[8], acc);
    res[j] = acc;
    s += acc;
    s2 = fmaf(acc, acc, s2);
  }
  if (ch < 512) {
    u16x8 hv0, hv1, lv0, lv1;
    #pragma unroll
    for (int j = 0; j < 16; j++) {
      const unsigned int pk = splitpack(res[j]);
      if (j < 8) { hv0[j] = (unsigned short)(pk & 0xFFFFu); lv0[j] = (unsigned short)(pk >> 16); }
      else       { hv1[j-8] = (unsigned short)(pk & 0xFFFFu); lv1[j-8] = (unsigned short)(pk >> 16); }
    }
    const size_t qi = ((size_t)b * 512 + ch) * L + t * 16;
    *(u16x8*)&qkSh[qi]     = hv0;
    *(u16x8*)&qkSh[qi + 8] = hv1;
    *(u16x8*)&qkSl[qi]     = lv0;
    *(u16x8*)&qkSl[qi + 8] = lv1;
    s = wave_sum(s); s2 = wave_sum(s2);
    const int lane = t & 63, wid = t >> 6;
    if (lane == 0) { rs[wid][0] = s; rs[wid][1] = s2; }
    __syncthreads();
    if (t == 0) {
      csum[b * 512 + ch]   = rs[0][0] + rs[1][0] + rs[2][0] + rs[3][0];
      csumsq[b * 512 + ch] = rs[0][1] + rs[1][1] + rs[2][1] + rs[3][1];
    }
  } else {
    const size_t vi = ((size_t)b * 256 + (ch - 512)) * L + t * 16;
    #pragma unroll
    for (int j = 0; j < 4; j++) {
      float4 v4;
      v4.x = res[j*4+0]; v4.y = res[j*4+1]; v4.z = res[j*4+2]; v4.w = res[j*4+3];
      *(float4*)&vbuf[vi + j * 4] = v4;
    }
  }
}

// ---------------- rank (stable descending) + sorted stats, one dispatch ----------------
__global__ __launch_bounds__(256) void rankstats_kernel(
    const float* __restrict__ csum, const float* __restrict__ csumsq,
    int* __restrict__ order,
    float* __restrict__ sumq, float* __restrict__ sumk,
    float* __restrict__ invnq, float* __restrict__ invnk)
{
  const int c = threadIdx.x;
  float key = 0.f;
  #pragma unroll
  for (int b = 0; b < 8; b++) key += csum[b * 512 + c];
  __shared__ float keys[256];
  __shared__ int ordS[256];
  keys[c] = key;
  __syncthreads();
  int rank = 0;
  for (int j = 0; j < 256; j++) {
    float kj = keys[j];
    rank += (kj > key) || (kj == key && j < c);
  }
  order[rank] = c;
  ordS[rank] = c;
  __syncthreads();
  const int ch = ordS[c];
  #pragma unroll
  for (int b = 0; b < 8; b++) {
    sumq[b * 256 + c]  = csum[b * 512 + ch];
    invnq[b * 256 + c] = 1.0f / fmaxf(sqrtf(csumsq[b * 512 + ch]), 1e-12f);
    sumk[b * 256 + c]  = csum[b * 512 + 256 + ch];
    invnk[b * 256 + c] = 1.0f / fmaxf(sqrtf(csumsq[b * 512 + 256 + ch]), 1e-12f);
  }
}

// ---------------- pack: vTS = split(v^T sorted) [b][l][r]; zqT = split(qn+kn) [b][l][r] (bf16) ----------------
__global__ __launch_bounds__(256) void vpack_kernel(
    const float* __restrict__ vbuf,
    const unsigned short* __restrict__ qkSh, const unsigned short* __restrict__ qkSl,
    const int* __restrict__ order,
    const float* __restrict__ invnq, const float* __restrict__ invnk,
    unsigned short* __restrict__ vTSh, unsigned short* __restrict__ vTSl,
    unsigned short* __restrict__ zqTh, unsigned short* __restrict__ zqTl)
{
  __shared__ float vt[64][65];
  __shared__ float zt[64][65];
  __shared__ int   ordS[256];
  __shared__ float iqS[256], ikS[256];
  const int t = threadIdx.x, lb = blockIdx.x * 64, b = blockIdx.y;
  ordS[t] = order[t];
  iqS[t] = invnq[b * 256 + t];
  ikS[t] = invnk[b * 256 + t];
  __syncthreads();
  for (int cc = 0; cc < 4; cc++) {
    const int r0 = cc * 64;
    for (int i = t; i < 1024; i += 256) {
      const int row = i >> 4, q = i & 15;
      const int ch = ordS[r0 + row];
      const float iq = iqS[r0 + row], ik = ikS[r0 + row];
      const float4 v4 = *(const float4*)&vbuf[((size_t)b * 256 + ch) * L + lb + q * 4];
      vt[q*4+0][row] = v4.x; vt[q*4+1][row] = v4.y; vt[q*4+2][row] = v4.z; vt[q*4+3][row] = v4.w;
      const size_t qi = ((size_t)b * 512 + ch) * L + lb + q * 4;
      const size_t ki = ((size_t)b * 512 + 256 + ch) * L + lb + q * 4;
      const ushort4 qh4 = *(const ushort4*)&qkSh[qi];
      const ushort4 ql4 = *(const ushort4*)&qkSl[qi];
      const ushort4 kh4 = *(const ushort4*)&qkSh[ki];
      const ushort4 kl4 = *(const ushort4*)&qkSl[ki];
      zt[q*4+0][row] = (bf16_tof(qh4.x)+bf16_tof(ql4.x))*iq + (bf16_tof(kh4.x)+bf16_tof(kl4.x))*ik;
      zt[q*4+1][row] = (bf16_tof(qh4.y)+bf16_tof(ql4.y))*iq + (bf16_tof(kh4.y)+bf16_tof(kl4.y))*ik;
      zt[q*4+2][row] = (bf16_tof(qh4.z)+bf16_tof(ql4.z))*iq + (bf16_tof(kh4.z)+bf16_tof(kl4.z))*ik;
      zt[q*4+3][row] = (bf16_tof(qh4.w)+bf16_tof(ql4.w))*iq + (bf16_tof(kh4.w)+bf16_tof(kl4.w))*ik;
    }
    __syncthreads();
    const int l = t >> 2, qq = t & 3;
    const size_t ob = ((size_t)b * L + lb + l) * 256 + r0 + qq * 16;
    u16x8 vh[2], vl[2], zh[2], zl[2];
    #pragma unroll
    for (int j = 0; j < 16; j++) {
      unsigned int pv = splitpack(vt[l][qq*16 + j]);
      unsigned int pz = splitpack(zt[l][qq*16 + j]);
      vh[j>>3][j&7] = (unsigned short)(pv & 0xFFFFu);
      vl[j>>3][j&7] = (unsigned short)(pv >> 16);
      zh[j>>3][j&7] = (unsigned short)(pz & 0xFFFFu);
      zl[j>>3][j&7] = (unsigned short)(pz >> 16);
    }
    *(u16x8*)&vTSh[ob]     = vh[0]; *(u16x8*)&vTSh[ob + 8] = vh[1];
    *(u16x8*)&vTSl[ob]     = vl[0]; *(u16x8*)&vTSl[ob + 8] = vl[1];
    *(u16x8*)&zqTh[ob]     = zh[0]; *(u16x8*)&zqTh[ob + 8] = zh[1];
    *(u16x8*)&zqTl[ob]     = zl[0]; *(u16x8*)&zqTl[ob + 8] = zl[1];
    __syncthreads();
  }
}

// ---------------- scores via MFMA (bf16 3-pass), 2-phase double-buffered gather staging ----------------
template<int G, int GI, int START, int MB, int SPB>
__device__ void scores_body(const unsigned short* __restrict__ qkSh,
    const unsigned short* __restrict__ qkSl,
    const int* __restrict__ order, float* __restrict__ Spart,
    unsigned short* Ah, unsigned short* Al, unsigned short* Bh, unsigned short* Bl,
    int* ordS)
{
  constexpr int MR = (G - MB * 64 < 64) ? (G - MB * 64) : 64;
  constexpr int NF = G / 16;
  const int t = threadIdx.x, ks = blockIdx.x, b = blockIdx.y;
  const int w = t >> 6, lane = t & 63, ln = lane & 15, lg = lane >> 4;
  const int lrow  = lane >> 2;
  const int chunk = (lane & 3) ^ ((lane >> 4) & 3);
  const int slot  = lg ^ (ln >> 2);
  for (int i = t; i < G; i += 256) ordS[i] = order[START + i];
  __syncthreads();
  const int k0 = ks * 512;
  const bool act = (w * 16) < MR;
  f32x4 z4 = {0.f, 0.f, 0.f, 0.f};
  f32x4 acc[NF];
  #pragma unroll
  for (int i = 0; i < NF; i++) acc[i] = z4;

  auto stage = [&](int kc, int cb) {
    for (int i = w; i < MR / 16; i += 4) {
      const int rb = i * 16;
      const int ch = ordS[MB * 64 + rb + lrow];
      const size_t g = ((size_t)b * 512 + ch) * L + k0 + kc + chunk * 8;
      gl16(qkSh + g, &Ah[cb * 2048 + rb * 32]);
      gl16(qkSl + g, &Al[cb * 2048 + rb * 32]);
    }
    for (int i = w; i < G / 16; i += 4) {
      const int rb = i * 16;
      const int ch = 256 + ordS[rb + lrow];
      const size_t g = ((size_t)b * 512 + ch) * L + k0 + kc + chunk * 8;
      gl16(qkSh + g, &Bh[cb * 3072 + rb * 32]);
      gl16(qkSl + g, &Bl[cb * 3072 + rb * 32]);
    }
  };

  stage(0, 0);
  __syncthreads();
  int cur = 0;
  for (int kc = 0; kc < 512; kc += 32) {
    if (kc + 32 < 512) stage(kc + 32, cur ^ 1);
    if (act) {
      const int aoff = cur * 2048 + (w * 16 + ln) * 32 + slot * 8;
      const short8v ah = *(const short8v*)&Ah[aoff];
      const short8v al = *(const short8v*)&Al[aoff];
      #pragma unroll
      for (int nf = 0; nf < NF; nf++) {
        const int boff = cur * 3072 + (nf * 16 + ln) * 32 + slot * 8;
        const short8v bh = *(const short8v*)&Bh[boff];
        const short8v bl = *(const short8v*)&Bl[boff];
        acc[nf] = __builtin_amdgcn_mfma_f32_16x16x32_bf16(ah, bh, acc[nf], 0, 0, 0);
        acc[nf] = __builtin_amdgcn_mfma_f32_16x16x32_bf16(ah, bl, acc[nf], 0, 0, 0);
        acc[nf] = __builtin_amdgcn_mfma_f32_16x16x32_bf16(al, bh, acc[nf], 0, 0, 0);
      }
    }
    __syncthreads();
    cur ^= 1;
  }
  if (act) {
    float* dst = Spart + (size_t)b * 147456 + SPB + ks * G * G;
    #pragma unroll
    for (int nf = 0; nf < NF; nf++) {
      const int d = nf * 16 + ln;
      #pragma unroll
      for (int r = 0; r < 4; r++) {
        const int m = MB * 64 + w * 16 + lg * 4 + r;
        dst[m * G + d] = acc[nf][r];
      }
    }
  }
}

__global__ __launch_bounds__(256) void scores_kernel(const unsigned short* __restrict__ qkSh,
    const unsigned short* __restrict__ qkSl,
    const int* __restrict__ order, float* __restrict__ Spart)
{
  __shared__ unsigned short Ah[2 * 64 * 32];
  __shared__ unsigned short Al[2 * 64 * 32];
  __shared__ unsigned short Bh[2 * 96 * 32];
  __shared__ unsigned short Bl[2 * 96 * 32];
  __shared__ int ordS[96];
  switch (blockIdx.z) {
    case 0:  scores_body<32, 0, 0,   0, 0    >(qkSh, qkSl, order, Spart, Ah, Al, Bh, Bl, ordS); break;
    case 1:  scores_body<64, 1, 32,  0, 8192 >(qkSh, qkSl, order, Spart, Ah, Al, Bh, Bl, ordS); break;
    case 2:  scores_body<64, 2, 96,  0, 40960>(qkSh, qkSl, order, Spart, Ah, Al, Bh, Bl, ordS); break;
    case 3:  scores_body<96, 3, 160, 0, 73728>(qkSh, qkSl, order, Spart, Ah, Al, Bh, Bl, ordS); break;
    default: scores_body<96, 3, 160, 1, 73728>(qkSh, qkSl, order, Spart, Ah, Al, Bh, Bl, ordS); break;
  }
}

// ---------------- reduce partials, scale, wave-parallel softmax (row-quarter split) ----------------
template<int G, int GI, int START, int SPB, int AOFF>
__device__ void softmax_body(const float* __restrict__ Spart, const float* __restrict__ invnq,
    const float* __restrict__ invnk, const float* __restrict__ temperature,
    unsigned short* __restrict__ attnPh, unsigned short* __restrict__ attnPl, float* Sm)
{
  constexpr int RQ = G / 4;          // rows per block
  const int t = threadIdx.x;
  const int b = blockIdx.x;
  const int r0 = blockIdx.z * RQ;
  const float temp = temperature[GI];
  for (int idx = t; idx < RQ * G; idx += 256) {
    const int rl = idx / G, d = idx - rl * G;
    const int gidx = (r0 + rl) * G + d;
    float s = 0.f;
    #pragma unroll
    for (int ks = 0; ks < 8; ks++)
      s += Spart[(size_t)b * 147456 + SPB + ks * G * G + gidx];
    Sm[idx] = s * invnq[b * 256 + START + r0 + rl] * invnk[b * 256 + START + d] * temp;
  }
  __syncthreads();
  const int wv = t >> 6, lane = t & 63;
  for (int r = wv; r < RQ; r += 4) {
    const float v0 = (lane < G) ? Sm[r * G + lane] : -INFINITY;
    const float v1 = (64 + lane < G) ? Sm[r * G + 64 + lane] : -INFINITY;
    float m = fmaxf(v0, v1);
    #pragma unroll
    for (int off = 32; off > 0; off >>= 1) m = fmaxf(m, __shfl_xor(m, off, 64));
    const float e0 = (lane < G) ? expf(v0 - m) : 0.f;
    const float e1 = (64 + lane < G) ? expf(v1 - m) : 0.f;
    float s = e0 + e1;
    #pragma unroll
    for (int off = 32; off > 0; off >>= 1) s += __shfl_xor(s, off, 64);
    const float inv = 1.0f / s;
    const size_t base = (size_t)b * 18432 + AOFF + (size_t)(r0 + r) * G;
    if (lane < G) {
      const unsigned int p = splitpack(e0 * inv);
      attnPh[base + lane] = (unsigned short)(p & 0xFFFFu);
      attnPl[base + lane] = (unsigned short)(p >> 16);
    }
    if (64 + lane < G) {
      const unsigned int p = splitpack(e1 * inv);
      attnPh[base + 64 + lane] = (unsigned short)(p & 0xFFFFu);
      attnPl[base + 64 + lane] = (unsigned short)(p >> 16);
    }
  }
}

__global__ __launch_bounds__(256) void softmax_kernel(const float* __restrict__ Spart,
    const float* __restrict__ invnq, const float* __restrict__ invnk,
    const float* __restrict__ temperature,
    unsigned short* __restrict__ attnPh, unsigned short* __restrict__ attnPl)
{
  extern __shared__ float smem[];
  switch (blockIdx.y) {
    case 0:  softmax_body<32, 0, 0,   0,     0   >(Spart, invnq, invnk, temperature, attnPh, attnPl, smem); break;
    case 1:  softmax_body<64, 1, 32,  8192,  1024>(Spart, invnq, invnk, temperature, attnPh, attnPl, smem); break;
    case 2:  softmax_body<64, 2, 96,  40960, 5120>(Spart, invnq, invnk, temperature, attnPh, attnPl, smem); break;
    default: softmax_body<96, 3, 160, 73728, 9216>(Spart, invnq, invnk, temperature, attnPh, attnPl, smem); break;
  }
}

// ---------------- PV via MFMA (bf16 3-pass), fused z epilogue -> f16 pairs ----------------
template<int G, int GI, int START, int AOFF>
__device__ void pv_body(
    const unsigned short* __restrict__ vTSh, const unsigned short* __restrict__ vTSl,
    const unsigned short* __restrict__ attnPh, const unsigned short* __restrict__ attnPl,
    const unsigned short* __restrict__ zqTh, const unsigned short* __restrict__ zqTl,
    unsigned short* __restrict__ outTh, unsigned short* __restrict__ outTl,
    unsigned short* __restrict__ zTh, unsigned short* __restrict__ zTl,
    unsigned short* Ah, unsigned short* Al, unsigned short* Bh, unsigned short* Bl)
{
  constexpr int NF = G / 16;
  const int t = threadIdx.x, b = blockIdx.y, l0 = blockIdx.x * 128;
  const int w = t >> 6, lane = t & 63, ln = lane & 15, lg = lane >> 4;
  const int lrow  = lane >> 2;
  const int chunk = (lane & 3) ^ ((lane >> 4) & 3);
  const int slot  = lg ^ (ln >> 2);
  f32x4 z4 = {0.f, 0.f, 0.f, 0.f};
  f32x4 acc[2][NF];
  #pragma unroll
  for (int i = 0; i < 2; i++)
    #pragma unroll
    for (int j = 0; j < NF; j++) acc[i][j] = z4;
  for (int kc = 0; kc < G; kc += 32) {
    #pragma unroll
    for (int i = 0; i < 2; i++) {
      const int rb = w * 32 + i * 16;
      const size_t g = ((size_t)b * L + l0 + rb + lrow) * 256 + START + kc + chunk * 8;
      gl16(vTSh + g, &Ah[rb * 32]);
      gl16(vTSl + g, &Al[rb * 32]);
    }
    for (int i = w; i < G / 16; i += 4) {
      const int rb = i * 16;
      const size_t g = (size_t)b * 18432 + AOFF + (size_t)(rb + lrow) * G + kc + chunk * 8;
      gl16(attnPh + g, &Bh[rb * 32]);
      gl16(attnPl + g, &Bl[rb * 32]);
    }
    __syncthreads();
    short8v bhf[NF], blf[NF];
    #pragma unroll
    for (int nf = 0; nf < NF; nf++) {
      const int boff = (nf * 16 + ln) * 32 + slot * 8;
      bhf[nf] = *(const short8v*)&Bh[boff];
      blf[nf] = *(const short8v*)&Bl[boff];
    }
    #pragma unroll
    for (int mi = 0; mi < 2; mi++) {
      const int aoff = ((w * 2 + mi) * 16 + ln) * 32 + slot * 8;
      const short8v ah = *(const short8v*)&Ah[aoff];
      const short8v al = *(const short8v*)&Al[aoff];
      #pragma unroll
      for (int nf = 0; nf < NF; nf++) {
        acc[mi][nf] = __builtin_amdgcn_mfma_f32_16x16x32_bf16(ah, bhf[nf], acc[mi][nf], 0, 0, 0);
        acc[mi][nf] = __builtin_amdgcn_mfma_f32_16x16x32_bf16(ah, blf[nf], acc[mi][nf], 0, 0, 0);
        acc[mi][nf] = __builtin_amdgcn_mfma_f32_16x16x32_bf16(al, bhf[nf], acc[mi][nf], 0, 0, 0);
      }
    }
    __syncthreads();
  }
  #pragma unroll
  for (int mi = 0; mi < 2; mi++) {
    const int lbase = l0 + (w * 2 + mi) * 16 + lg * 4;
    #pragma unroll
    for (int nf = 0; nf < NF; nf++) {
      const int col = START + nf * 16 + ln;
      #pragma unroll
      for (int r = 0; r < 4; r++) {
        const size_t idx = ((size_t)b * L + lbase + r) * 256 + col;
        const float v = acc[mi][nf][r];
        const unsigned int po = splitpackh(v);
        outTh[idx] = (unsigned short)(po & 0xFFFFu);
        outTl[idx] = (unsigned short)(po >> 16);
        const float zq = bf16_tof(zqTh[idx]) + bf16_tof(zqTl[idx]);
        const unsigned int pz = splitpackh(v + zq);
        zTh[idx] = (unsigned short)(pz & 0xFFFFu);
        zTl[idx] = (unsigned short)(pz >> 16);
      }
    }
  }
}

__global__ __launch_bounds__(256) void pv_kernel(
    const unsigned short* __restrict__ vTSh, const unsigned short* __restrict__ vTSl,
    const unsigned short* __restrict__ attnPh, const unsigned short* __restrict__ attnPl,
    const unsigned short* __restrict__ zqTh, const unsigned short* __restrict__ zqTl,
    unsigned short* __restrict__ outTh, unsigned short* __restrict__ outTl,
    unsigned short* __restrict__ zTh, unsigned short* __restrict__ zTl)
{
  __shared__ unsigned short Ah[128 * 32];
  __shared__ unsigned short Al[128 * 32];
  __shared__ unsigned short Bh[96 * 32];
  __shared__ unsigned short Bl[96 * 32];
  switch (blockIdx.z) {
    case 0:  pv_body<32, 0, 0,   0   >(vTSh, vTSl, attnPh, attnPl, zqTh, zqTl, outTh, outTl, zTh, zTl, Ah, Al, Bh, Bl); break;
    case 1:  pv_body<64, 1, 32,  1024>(vTSh, vTSl, attnPh, attnPl, zqTh, zqTl, outTh, outTl, zTh, zTl, Ah, Al, Bh, Bl); break;
    case 2:  pv_body<64, 2, 96,  5120>(vTSh, vTSl, attnPh, attnPl, zqTh, zqTl, outTh, outTl, zTh, zTl, Ah, Al, Bh, Bl); break;
    default: pv_body<96, 3, 160, 9216>(vTSh, vTSl, attnPh, attnPl, zqTh, zqTl, outTh, outTl, zTh, zTl, Ah, Al, Bh, Bl); break;
  }
}

// ---------------- qv_cache ----------------
__global__ __launch_bounds__(256) void qv_kernel(const float* __restrict__ sumq,
    const float* __restrict__ sumk, const float* __restrict__ invnq,
    const float* __restrict__ invnk, float* __restrict__ out2)
{
  const int b = blockIdx.x >> 8, r = blockIdx.x & 255;
  float val = 0.f;
  {
    const int idx = b * 256 + 0 + (r & 31);
    val += fmaf(sumq[idx], invnq[idx], sumk[idx] * invnk[idx]);
  }
  {
    const int idx = b * 256 + 32 + (r & 63);
    val += fmaf(sumq[idx], invnq[idx], sumk[idx] * invnk[idx]);
  }
  {
    const int idx = b * 256 + 96 + (r & 63);
    val += fmaf(sumq[idx], invnq[idx], sumk[idx] * invnk[idx]);
  }
  if (r < 192) {
    const int rm = (r < 96) ? r : r - 96;
    const int idx = b * 256 + 160 + rm;
    val += fmaf(sumq[idx], invnq[idx], sumk[idx] * invnk[idx]);
  }
  val *= (1.0f / 4096.f) * 0.25f * 0.9f;
  const float4 o = {val, val, val, val};
  float4* dst = reinterpret_cast<float4*>(out2 + ((size_t)b * C + r) * L);
  for (int i = threadIdx.x; i < 1024; i += 256) dst[i] = o;
}

// ---------------- launch ----------------
extern "C" void kernel_launch(void* const* d_in, const int* in_sizes, int n_in,
                              void* d_out, int out_size, void* d_ws, size_t ws_size,
                              hipStream_t stream)
{
  const float* x           = (const float*)d_in[0];
  const float* temperature = (const float*)d_in[1];
  const float* w_qkv       = (const float*)d_in[2];
  const float* w_dw        = (const float*)d_in[3];
  const float* w_proj      = (const float*)d_in[4];
  const float* w_gate      = (const float*)d_in[5];
  const float* b_gate      = (const float*)d_in[6];
  const float* w_down      = (const float*)d_in[7];
  const float* b_down      = (const float*)d_in[8];
  const float* w_up        = (const float*)d_in[9];
  const float* b_up        = (const float*)d_in[10];

  if (ws_size < 202548224ULL) return;

  char* ws = (char*)d_ws;
  // Region A [0, 96M):
  float*          qkv_pre  = (float*)(ws);                        // 96MB, dead after dwconv
  unsigned short* vTSh     = (unsigned short*)(ws);                // 16MB
  unsigned short* vTSl     = (unsigned short*)(ws + 16777216);     // 16MB
  unsigned short* zqTh     = (unsigned short*)(ws + 33554432);     // 16MB
  unsigned short* zqTl     = (unsigned short*)(ws + 50331648);     // 16MB
  float*          Spart    = (float*)(ws + 67108864);              // 4.72MB
  unsigned short* attnPh   = (unsigned short*)(ws + 73400320);     // 288KB
  unsigned short* attnPl   = (unsigned short*)(ws + 74448896);     // 288KB
  unsigned short* preprojh = (unsigned short*)(ws);                // 16MB (after pv; bf16)
  unsigned short* preprojl = (unsigned short*)(ws + 16777216);     // 16MB
  // Region B [96M, 192M):
  unsigned short* XThi     = (unsigned short*)(ws + 100663296);    // 16MB (f16)
  unsigned short* XTlo     = (unsigned short*)(ws + 117440512);    // 16MB
  unsigned short* qkSh     = (unsigned short*)(ws + 100663296);    // 32MB (after qkv gemm; bf16)
  unsigned short* qkSl     = (unsigned short*)(ws + 134217728);    // 32MB
  float*          vbuf     = (float*)(ws + 167772160);             // 32MB
  unsigned short* outTh    = (unsigned short*)(ws + 100663296);    // 16MB (after scores; f16)
  unsigned short* outTl    = (unsigned short*)(ws + 117440512);    // 16MB
  unsigned short* zTh      = (unsigned short*)(ws + 134217728);    // 16MB (f16)
  unsigned short* zTl      = (unsigned short*)(ws + 150994944);    // 16MB
  unsigned short* gatedh   = (unsigned short*)(ws + 167772160);    // 16MB (after vpack; f16)
  unsigned short* gatedl   = (unsigned short*)(ws + 184549376);    // 16MB
  unsigned short* midh     = (unsigned short*)(ws + 134217728);    // 8MB (after gate gemm; f16)
  unsigned short* midl     = (unsigned short*)(ws + 142606336);    // 8MB
  // Region C [192M+, persistent):
  unsigned short* Wf16   = (unsigned short*)(ws + 201326592);      // 655360 B (327680 f16)
  unsigned short* WprojH = (unsigned short*)(ws + 201981952);      // 128KB
  unsigned short* WprojL = (unsigned short*)(ws + 202113024);      // 128KB
  float* csum   = (float*)(ws + 202244096);                        // 16KB
  float* csumsq = (float*)(ws + 202260480);                        // 16KB
  float* sumq   = (float*)(ws + 202276864);                        // 8KB
  float* sumk   = (float*)(ws + 202285056);                        // 8KB
  float* invnq  = (float*)(ws + 202293248);                        // 8KB
  float* invnk  = (float*)(ws + 202301440);                        // 8KB
  int*   order  = (int*)(ws + 202309632);                          // 1KB

  float* out_all = (float*)d_out;
  float* qv_out  = out_all + (size_t)B * C * L;

  // 0. weight + input splits
  wsplit_kernel<<<1536, 256, 0, stream>>>(w_qkv, w_gate, w_down, w_up, w_proj,
                                          Wf16, WprojH, WprojL);
  splitx_kernel<<<dim3(64, 4, 8), 256, 0, stream>>>(x, XThi, XTlo);
  // 1. qkv = w_qkv @ x  (f16 2-pass MFMA, out fp32 [b][768][L])
  hgemm<256, 0><<<dim3(32, 6, 8), 256, 0, stream>>>(
      XThi, XTlo, Wf16, qkv_pre, nullptr, nullptr, nullptr, nullptr, nullptr, 768);
  // 2. depthwise conv (+ split-pack q,k bf16 hi/lo; v fp32; channel stats)
  dwconv2_kernel<<<dim3(768, 8), 256, 0, stream>>>(qkv_pre, w_dw, qkSh, qkSl, vbuf, csum, csumsq);
  // 3. channel ordering + sorted stats (one dispatch)
  rankstats_kernel<<<1, 256, 0, stream>>>(csum, csumsq, order, sumq, sumk, invnq, invnk);
  // 4. pack v^T + zq (bf16 hi/lo)
  vpack_kernel<<<dim3(64, 8), 256, 0, stream>>>(vbuf, qkSh, qkSl, order, invnq, invnk,
                                                vTSh, vTSl, zqTh, zqTl);
  // 5. attention
  scores_kernel<<<dim3(8, 8, 5), 256, 0, stream>>>(qkSh, qkSl, order, Spart);
  softmax_kernel<<<dim3(8, 4, 4), 256, 9216, stream>>>(Spart, invnq, invnk, temperature, attnPh, attnPl);
  pv_kernel<<<dim3(32, 8, 4), 256, 0, stream>>>(vTSh, vTSl, attnPh, attnPl, zqTh, zqTl,
                                                outTh, outTl, zTh, zTl);
  // 6. MLP chain (f16 2-pass)
  hgemm<256, 2><<<dim3(32, 2, 8), 256, 0, stream>>>(
      zTh, zTl, Wf16 + 196608, nullptr, gatedh, gatedl, b_gate, zTh, zTl, 256);
  hgemm<256, 1><<<dim3(32, 1, 8), 256, 0, stream>>>(
      gatedh, gatedl, Wf16 + 262144, nullptr, midh, midl, b_down, nullptr, nullptr, 128);
  hgemm<128, 5><<<dim3(32, 2, 8), 256, 0, stream>>>(
      midh, midl, Wf16 + 294912, nullptr, preprojh, preprojl, b_up, outTh, outTl, 256);
  // 7. final projection (bf16 3-pass precision firewall) -> output 0
  mgemm<256><<<dim3(32, 2, 8), 256, 0, stream>>>(
      preprojh, preprojl, WprojH, WprojL, out_all, 256);
  // 8. qv_cache -> output 1
  qv_kernel<<<2048, 256, 0, stream>>>(sumq, sumk, invnq, invnk, qv_out);
}

// Round 8
// 238.628 us; speedup vs baseline: 2.5155x; 1.2574x over previous
//
#include <hip/hip_runtime.h>
#include <hip/hip_fp16.h>
#include <math.h>

#define B 8
#define C 256
#define L 4096
#define OC3 768

typedef __attribute__((ext_vector_type(8))) short short8v;
typedef __attribute__((ext_vector_type(8))) unsigned short u16x8;
typedef __attribute__((ext_vector_type(4))) float f32x4;

// ---------------- helpers ----------------
__device__ __forceinline__ float gelu_exact(float x){
  return 0.5f * x * (1.0f + erff(x * 0.70710678118654752440f));
}
__device__ __forceinline__ float wave_sum(float v){
  #pragma unroll
  for (int off = 32; off > 0; off >>= 1) v += __shfl_down(v, off, 64);
  return v;
}
__device__ __forceinline__ unsigned short bf16_rne(float f){
  unsigned int u = __float_as_uint(f);
  unsigned int r = u + 0x7FFFu + ((u >> 16) & 1u);
  return (unsigned short)(r >> 16);
}
__device__ __forceinline__ float bf16_tof(unsigned short h){
  return __uint_as_float(((unsigned int)h) << 16);
}
// bf16 split pair in one u32: low16 = hi, high16 = lo
__device__ __forceinline__ unsigned int splitpack(float v){
  unsigned short hi = bf16_rne(v);
  float lof = v - bf16_tof(hi);
  unsigned short lo = bf16_rne(lof);
  return (unsigned int)hi | ((unsigned int)lo << 16);
}
// f16 helpers
__device__ __forceinline__ unsigned short f16b(float f){
  return __half_as_ushort(__float2half_rn(f));
}
__device__ __forceinline__ float f16tof(unsigned short u){
  return __half2float(__ushort_as_half(u));
}
// f16 split pair
__device__ __forceinline__ unsigned int splitpackh(float v){
  unsigned short hi = f16b(v);
  float lof = v - f16tof(hi);
  unsigned short lo = f16b(lof);
  return (unsigned int)hi | ((unsigned int)lo << 16);
}
// async global->LDS 16B per lane; LDS dest must be wave-uniform base
__device__ __forceinline__ void gl16(const unsigned short* g, unsigned short* l){
  __builtin_amdgcn_global_load_lds(
      (const __attribute__((address_space(1))) void*)g,
      (__attribute__((address_space(3))) void*)l, 16, 0, 0);
}

// ---------------- weight split ----------------
// Wf16: qkv@0 (196608), gate@196608 (65536), down@262144 (32768), up@294912 (32768) -- f16
// proj -> bf16 hi/lo planes (65536 each)
__global__ __launch_bounds__(256) void wsplit_kernel(
    const float* __restrict__ wqkv, const float* __restrict__ wgate,
    const float* __restrict__ wdown, const float* __restrict__ wup,
    const float* __restrict__ wproj,
    unsigned short* __restrict__ Wf16,
    unsigned short* __restrict__ PH, unsigned short* __restrict__ PLo)
{
  int idx = blockIdx.x * 256 + threadIdx.x;   // 0..393215
  if (idx < 327680) {
    float s;
    if (idx < 196608)      s = wqkv[idx];
    else if (idx < 262144) s = wgate[idx - 196608];
    else if (idx < 294912) s = wdown[idx - 262144];
    else                   s = wup[idx - 294912];
    Wf16[idx] = f16b(s);
  } else {
    int j = idx - 327680;
    unsigned int p = splitpack(wproj[j]);
    PH[j] = (unsigned short)(p & 0xFFFFu); PLo[j] = (unsigned short)(p >> 16);
  }
}

// ---------------- x [b][c][l] fp32 -> xT hi/lo f16 [b][l][c] ----------------
__global__ __launch_bounds__(256) void splitx_kernel(const float* __restrict__ x,
    unsigned short* __restrict__ XThi, unsigned short* __restrict__ XTlo)
{
  __shared__ float st[64][68];
  const int b = blockIdx.z, c0 = blockIdx.y * 64, lb = blockIdx.x * 64;
  const int t = threadIdx.x;
  #pragma unroll
  for (int i = 0; i < 4; i++) {
    int row = (t >> 4) + i * 16;
    int col = (t & 15) * 4;
    float4 v = *(const float4*)&x[((size_t)b * C + c0 + row) * L + lb + col];
    st[row][col] = v.x; st[row][col+1] = v.y; st[row][col+2] = v.z; st[row][col+3] = v.w;
  }
  __syncthreads();
  const int l = t >> 2, cq = t & 3;
  u16x8 hv0, hv1, lv0, lv1;
  #pragma unroll
  for (int i = 0; i < 16; i++) {
    unsigned int p = splitpackh(st[cq * 16 + i][l]);
    if (i < 8) { hv0[i] = (unsigned short)(p & 0xFFFFu); lv0[i] = (unsigned short)(p >> 16); }
    else       { hv1[i-8] = (unsigned short)(p & 0xFFFFu); lv1[i-8] = (unsigned short)(p >> 16); }
  }
  size_t o = ((size_t)b * L + lb + l) * C + c0 + cq * 16;
  *(u16x8*)&XThi[o]     = hv0;
  *(u16x8*)&XThi[o + 8] = hv1;
  *(u16x8*)&XTlo[o]     = lv0;
  *(u16x8*)&XTlo[o + 8] = lv1;
}

// ---------------- f16 MFMA GEMM, 2-phase double-buffered ----------------
// MODE: 1 = 1-pass (A single plane), 2 = mixed (blockIdx.y<2: 2-pass, else 1-pass)
// EPI: 0 = store fp32 transposed [b][o][L]
//      1 = +bias, store single f16 [b][l][o]
//      2 = gelu(acc+bias)*extra(f16 single), store single f16
//      5 = acc+bias+extra(f16 single), store BF16 pair (feeds proj)
template<int KTOT, int EPI, int MODE>
__global__ __launch_bounds__(256) void hgemm(
    const unsigned short* __restrict__ Ahi_g, const unsigned short* __restrict__ Alo_g,
    const unsigned short* __restrict__ Bw_g,
    float* __restrict__ outF,
    unsigned short* __restrict__ outH, unsigned short* __restrict__ outLo,
    const float* __restrict__ bias, const unsigned short* __restrict__ extraH,
    int Ntot)
{
  constexpr int NP = (MODE == 1) ? 2 : 3;   // planes: Ahi, [Alo], B
  __shared__ unsigned short SB[2][NP][128 * 32];
  const int t  = threadIdx.x;
  const int lb = blockIdx.x * 128;
  const int o0 = blockIdx.y * 128;
  const int b  = blockIdx.z;
  const int w  = t >> 6, lane = t & 63;
  const int wm = w >> 1, wn = w & 1;
  const int ln = lane & 15, lg = lane >> 4;
  const int lrow  = lane >> 2;
  const int chunk = (lane & 3) ^ ((lane >> 4) & 3);
  const int slot  = lg ^ (ln >> 2);
  const bool twop = (MODE == 2) ? (blockIdx.y < 2) : false;

  f32x4 z4 = {0.f, 0.f, 0.f, 0.f};
  f32x4 acc[4][4];
  #pragma unroll
  for (int i = 0; i < 4; i++)
    #pragma unroll
    for (int j = 0; j < 4; j++) acc[i][j] = z4;

  const size_t arow0 = (size_t)b * L + lb;
  constexpr int NKT = KTOT / 32;

  auto stage = [&](int kt, int cb) {
    const int k0 = kt * 32;
    #pragma unroll
    for (int i = 0; i < 2; i++) {
      const int rb = w * 32 + i * 16;
      const size_t ga = (arow0 + rb + lrow) * KTOT + k0 + chunk * 8;
      gl16(Ahi_g + ga, &SB[cb][0][rb * 32]);
      if (NP == 3 && twop) gl16(Alo_g + ga, &SB[cb][1][rb * 32]);
      const size_t gb = (size_t)(o0 + rb + lrow) * KTOT + k0 + chunk * 8;
      gl16(Bw_g + gb, &SB[cb][NP - 1][rb * 32]);
    }
  };

  stage(0, 0);
  __syncthreads();
  int cur = 0;
  for (int kt = 0; kt < NKT; ++kt) {
    if (kt + 1 < NKT) stage(kt + 1, cur ^ 1);
    short8v bwf[4];
    #pragma unroll
    for (int nf = 0; nf < 4; nf++) {
      const int off = (wn * 64 + nf * 16 + ln) * 32 + slot * 8;
      bwf[nf] = *(const short8v*)&SB[cur][NP - 1][off];
    }
    #pragma unroll
    for (int mf = 0; mf < 4; mf++) {
      const int off = (wm * 64 + mf * 16 + ln) * 32 + slot * 8;
      const short8v ah = *(const short8v*)&SB[cur][0][off];
      #pragma unroll
      for (int nf = 0; nf < 4; nf++)
        acc[mf][nf] = __builtin_amdgcn_mfma_f32_16x16x32_f16(ah, bwf[nf], acc[mf][nf], 0, 0, 0);
      if (NP == 3 && twop) {
        const short8v al = *(const short8v*)&SB[cur][1][off];
        #pragma unroll
        for (int nf = 0; nf < 4; nf++)
          acc[mf][nf] = __builtin_amdgcn_mfma_f32_16x16x32_f16(al, bwf[nf], acc[mf][nf], 0, 0, 0);
      }
    }
    __syncthreads();
    cur ^= 1;
  }
  #pragma unroll
  for (int mf = 0; mf < 4; mf++) {
    const int mbase = lb + wm * 64 + mf * 16 + lg * 4;
    #pragma unroll
    for (int nf = 0; nf < 4; nf++) {
      const int o = o0 + wn * 64 + nf * 16 + ln;
      if (EPI == 0) {
        float4 r;
        r.x = acc[mf][nf][0]; r.y = acc[mf][nf][1];
        r.z = acc[mf][nf][2]; r.w = acc[mf][nf][3];
        *(float4*)&outF[((size_t)b * Ntot + o) * L + mbase] = r;
      } else {
        const float bv = bias ? bias[o] : 0.0f;
        #pragma unroll
        for (int r = 0; r < 4; r++) {
          const size_t idx = ((size_t)b * L + mbase + r) * Ntot + o;
          float v = acc[mf][nf][r] + bv;
          if (EPI == 2) { v = gelu_exact(v) * f16tof(extraH[idx]); }
          if (EPI == 5) { v = v + f16tof(extraH[idx]); }
          if (EPI == 5) {
            const unsigned int p = splitpack(v);
            outH[idx]  = (unsigned short)(p & 0xFFFFu);
            outLo[idx] = (unsigned short)(p >> 16);
          } else {
            outH[idx] = f16b(v);
          }
        }
      }
    }
  }
}

// ---------------- bf16 3-pass MFMA GEMM (proj only) ----------------
template<int KTOT>
__global__ __launch_bounds__(256) void mgemm(
    const unsigned short* __restrict__ Ahi_g, const unsigned short* __restrict__ Alo_g,
    const unsigned short* __restrict__ Bhi_g, const unsigned short* __restrict__ Blo_g,
    float* __restrict__ outF, int Ntot)
{
  __shared__ unsigned short SB[2][4][128 * 32];
  const int t  = threadIdx.x;
  const int lb = blockIdx.x * 128;
  const int o0 = blockIdx.y * 128;
  const int b  = blockIdx.z;
  const int w  = t >> 6, lane = t & 63;
  const int wm = w >> 1, wn = w & 1;
  const int ln = lane & 15, lg = lane >> 4;
  const int lrow  = lane >> 2;
  const int chunk = (lane & 3) ^ ((lane >> 4) & 3);
  const int slot  = lg ^ (ln >> 2);

  f32x4 z4 = {0.f, 0.f, 0.f, 0.f};
  f32x4 acc[4][4];
  #pragma unroll
  for (int i = 0; i < 4; i++)
    #pragma unroll
    for (int j = 0; j < 4; j++) acc[i][j] = z4;

  const size_t arow0 = (size_t)b * L + lb;
  constexpr int NKT = KTOT / 32;

  auto stage = [&](int kt, int cb) {
    const int k0 = kt * 32;
    #pragma unroll
    for (int i = 0; i < 2; i++) {
      const int rb = w * 32 + i * 16;
      const size_t ga = (arow0 + rb + lrow) * KTOT + k0 + chunk * 8;
      gl16(Ahi_g + ga, &SB[cb][0][rb * 32]);
      gl16(Alo_g + ga, &SB[cb][1][rb * 32]);
      const size_t gb = (size_t)(o0 + rb + lrow) * KTOT + k0 + chunk * 8;
      gl16(Bhi_g + gb, &SB[cb][2][rb * 32]);
      gl16(Blo_g + gb, &SB[cb][3][rb * 32]);
    }
  };

  stage(0, 0);
  __syncthreads();
  int cur = 0;
  for (int kt = 0; kt < NKT; ++kt) {
    if (kt + 1 < NKT) stage(kt + 1, cur ^ 1);
    short8v bhf[4], blf[4];
    #pragma unroll
    for (int nf = 0; nf < 4; nf++) {
      const int off = (wn * 64 + nf * 16 + ln) * 32 + slot * 8;
      bhf[nf] = *(const short8v*)&SB[cur][2][off];
      blf[nf] = *(const short8v*)&SB[cur][3][off];
    }
    #pragma unroll
    for (int mf = 0; mf < 4; mf++) {
      const int off = (wm * 64 + mf * 16 + ln) * 32 + slot * 8;
      const short8v ah = *(const short8v*)&SB[cur][0][off];
      const short8v al = *(const short8v*)&SB[cur][1][off];
      #pragma unroll
      for (int nf = 0; nf < 4; nf++) {
        acc[mf][nf] = __builtin_amdgcn_mfma_f32_16x16x32_bf16(ah, bhf[nf], acc[mf][nf], 0, 0, 0);
        acc[mf][nf] = __builtin_amdgcn_mfma_f32_16x16x32_bf16(ah, blf[nf], acc[mf][nf], 0, 0, 0);
        acc[mf][nf] = __builtin_amdgcn_mfma_f32_16x16x32_bf16(al, bhf[nf], acc[mf][nf], 0, 0, 0);
      }
    }
    __syncthreads();
    cur ^= 1;
  }
  #pragma unroll
  for (int mf = 0; mf < 4; mf++) {
    const int mbase = lb + wm * 64 + mf * 16 + lg * 4;
    #pragma unroll
    for (int nf = 0; nf < 4; nf++) {
      const int o = o0 + wn * 64 + nf * 16 + ln;
      float4 r;
      r.x = acc[mf][nf][0]; r.y = acc[mf][nf][1];
      r.z = acc[mf][nf][2]; r.w = acc[mf][nf][3];
      *(float4*)&outF[((size_t)b * Ntot + o) * L + mbase] = r;
    }
  }
}

// ---------------- depthwise 3x3 conv: halo-padded branchless; q,k,v -> single f16 ----------------
__global__ __launch_bounds__(256) void dwconv2_kernel(
    const float* __restrict__ in, const float* __restrict__ wdw,
    unsigned short* __restrict__ qkF, unsigned short* __restrict__ vF,
    float* __restrict__ csum, float* __restrict__ csumsq)
{
  __shared__ float p[66][73];
  __shared__ float rs[4][2];
  const int ch = blockIdx.x;
  const int b  = blockIdx.y;
  const int t  = threadIdx.x;
  const size_t base = ((size_t)b * OC3 + ch) * L;
  float wt[9];
  #pragma unroll
  for (int j = 0; j < 9; j++) wt[j] = wdw[ch * 9 + j];
  if (t < 66) { p[0][3 + t] = 0.f; p[65][3 + t] = 0.f; }
  if (t < 64) { p[1 + t][3] = 0.f; p[1 + t][68] = 0.f; }
  #pragma unroll
  for (int i = 0; i < 4; i++) {
    int pix = (i * 256 + t) * 4;
    const float4 v = *reinterpret_cast<const float4*>(&in[base + pix]);
    int h = pix >> 6, ww = pix & 63;
    p[1+h][4+ww] = v.x; p[1+h][5+ww] = v.y; p[1+h][6+ww] = v.z; p[1+h][7+ww] = v.w;
  }
  __syncthreads();
  const int h  = t >> 2;
  const int w0 = (t & 3) * 16;
  float r0a[18], r1a[18], r2a[18];
  #pragma unroll
  for (int c = 0; c < 18; c++) {
    r0a[c] = p[h][w0 + 3 + c];
    r1a[c] = p[h + 1][w0 + 3 + c];
    r2a[c] = p[h + 2][w0 + 3 + c];
  }
  float res[16];
  float s = 0.f, s2 = 0.f;
  #pragma unroll
  for (int j = 0; j < 16; j++) {
    float acc;
    acc = r0a[j] * wt[0];
    acc = fmaf(r0a[j+1], wt[1], acc);
    acc = fmaf(r0a[j+2], wt[2], acc);
    acc = fmaf(r1a[j],   wt[3], acc);
    acc = fmaf(r1a[j+1], wt[4], acc);
    acc = fmaf(r1a[j+2], wt[5], acc);
    acc = fmaf(r2a[j],   wt[6], acc);
    acc = fmaf(r2a[j+1], wt[7], acc);
    acc = fmaf(r2a[j+2], wt[8], acc);
    res[j] = acc;
    s += acc;
    s2 = fmaf(acc, acc, s2);
  }
  u16x8 h0, h1;
  #pragma unroll
  for (int j = 0; j < 16; j++) {
    if (j < 8) h0[j]   = f16b(res[j]);
    else       h1[j-8] = f16b(res[j]);
  }
  if (ch < 512) {
    const size_t qi = ((size_t)b * 512 + ch) * L + t * 16;
    *(u16x8*)&qkF[qi]     = h0;
    *(u16x8*)&qkF[qi + 8] = h1;
    s = wave_sum(s); s2 = wave_sum(s2);
    const int lane = t & 63, wid = t >> 6;
    if (lane == 0) { rs[wid][0] = s; rs[wid][1] = s2; }
    __syncthreads();
    if (t == 0) {
      csum[b * 512 + ch]   = rs[0][0] + rs[1][0] + rs[2][0] + rs[3][0];
      csumsq[b * 512 + ch] = rs[0][1] + rs[1][1] + rs[2][1] + rs[3][1];
    }
  } else {
    const size_t vi = ((size_t)b * 256 + (ch - 512)) * L + t * 16;
    *(u16x8*)&vF[vi]     = h0;
    *(u16x8*)&vF[vi + 8] = h1;
  }
}

// ---------------- rank (stable descending) + sorted stats ----------------
__global__ __launch_bounds__(256) void rankstats_kernel(
    const float* __restrict__ csum, const float* __restrict__ csumsq,
    int* __restrict__ order,
    float* __restrict__ sumq, float* __restrict__ sumk,
    float* __restrict__ invnq, float* __restrict__ invnk)
{
  const int c = threadIdx.x;
  float key = 0.f;
  #pragma unroll
  for (int b = 0; b < 8; b++) key += csum[b * 512 + c];
  __shared__ float keys[256];
  __shared__ int ordS[256];
  keys[c] = key;
  __syncthreads();
  int rank = 0;
  for (int j = 0; j < 256; j++) {
    float kj = keys[j];
    rank += (kj > key) || (kj == key && j < c);
  }
  order[rank] = c;
  ordS[rank] = c;
  __syncthreads();
  const int ch = ordS[c];
  #pragma unroll
  for (int b = 0; b < 8; b++) {
    sumq[b * 256 + c]  = csum[b * 512 + ch];
    invnq[b * 256 + c] = 1.0f / fmaxf(sqrtf(csumsq[b * 512 + ch]), 1e-12f);
    sumk[b * 256 + c]  = csum[b * 512 + 256 + ch];
    invnk[b * 256 + c] = 1.0f / fmaxf(sqrtf(csumsq[b * 512 + 256 + ch]), 1e-12f);
  }
}

// ---------------- pack: vTS = v^T sorted (f16) [b][l][r]; zqT = qn+kn (f16) [b][l][r] ----------------
__global__ __launch_bounds__(256) void vpack_kernel(
    const unsigned short* __restrict__ vF, const unsigned short* __restrict__ qkF,
    const int* __restrict__ order,
    const float* __restrict__ invnq, const float* __restrict__ invnk,
    unsigned short* __restrict__ vTS, unsigned short* __restrict__ zqT)
{
  __shared__ float vt[64][65];
  __shared__ float zt[64][65];
  __shared__ int   ordS[256];
  __shared__ float iqS[256], ikS[256];
  const int t = threadIdx.x, lb = blockIdx.x * 64, b = blockIdx.y;
  ordS[t] = order[t];
  iqS[t] = invnq[b * 256 + t];
  ikS[t] = invnk[b * 256 + t];
  __syncthreads();
  for (int cc = 0; cc < 4; cc++) {
    const int r0 = cc * 64;
    for (int i = t; i < 1024; i += 256) {
      const int row = i >> 4, q = i & 15;
      const int ch = ordS[r0 + row];
      const float iq = iqS[r0 + row], ik = ikS[r0 + row];
      const ushort4 v4 = *(const ushort4*)&vF[((size_t)b * 256 + ch) * L + lb + q * 4];
      vt[q*4+0][row] = f16tof(v4.x); vt[q*4+1][row] = f16tof(v4.y);
      vt[q*4+2][row] = f16tof(v4.z); vt[q*4+3][row] = f16tof(v4.w);
      const ushort4 q4 = *(const ushort4*)&qkF[((size_t)b * 512 + ch) * L + lb + q * 4];
      const ushort4 k4 = *(const ushort4*)&qkF[((size_t)b * 512 + 256 + ch) * L + lb + q * 4];
      zt[q*4+0][row] = f16tof(q4.x) * iq + f16tof(k4.x) * ik;
      zt[q*4+1][row] = f16tof(q4.y) * iq + f16tof(k4.y) * ik;
      zt[q*4+2][row] = f16tof(q4.z) * iq + f16tof(k4.z) * ik;
      zt[q*4+3][row] = f16tof(q4.w) * iq + f16tof(k4.w) * ik;
    }
    __syncthreads();
    const int l = t >> 2, qq = t & 3;
    const size_t ob = ((size_t)b * L + lb + l) * 256 + r0 + qq * 16;
    u16x8 vv[2], zz[2];
    #pragma unroll
    for (int j = 0; j < 16; j++) {
      vv[j>>3][j&7] = f16b(vt[l][qq*16 + j]);
      zz[j>>3][j&7] = f16b(zt[l][qq*16 + j]);
    }
    *(u16x8*)&vTS[ob]     = vv[0]; *(u16x8*)&vTS[ob + 8] = vv[1];
    *(u16x8*)&zqT[ob]     = zz[0]; *(u16x8*)&zqT[ob + 8] = zz[1];
    __syncthreads();
  }
}

// ---------------- scores via 1-pass f16 MFMA, 2-phase gather staging ----------------
template<int G, int GI, int START, int MB, int SPB>
__device__ void scores_body(const unsigned short* __restrict__ qkF,
    const int* __restrict__ order, float* __restrict__ Spart,
    unsigned short* Ah, unsigned short* Bh, int* ordS)
{
  constexpr int MR = (G - MB * 64 < 64) ? (G - MB * 64) : 64;
  constexpr int NF = G / 16;
  const int t = threadIdx.x, ks = blockIdx.x, b = blockIdx.y;
  const int w = t >> 6, lane = t & 63, ln = lane & 15, lg = lane >> 4;
  const int lrow  = lane >> 2;
  const int chunk = (lane & 3) ^ ((lane >> 4) & 3);
  const int slot  = lg ^ (ln >> 2);
  for (int i = t; i < G; i += 256) ordS[i] = order[START + i];
  __syncthreads();
  const int k0 = ks * 512;
  const bool act = (w * 16) < MR;
  f32x4 z4 = {0.f, 0.f, 0.f, 0.f};
  f32x4 acc[NF];
  #pragma unroll
  for (int i = 0; i < NF; i++) acc[i] = z4;

  auto stage = [&](int kc, int cb) {
    for (int i = w; i < MR / 16; i += 4) {
      const int rb = i * 16;
      const int ch = ordS[MB * 64 + rb + lrow];
      const size_t g = ((size_t)b * 512 + ch) * L + k0 + kc + chunk * 8;
      gl16(qkF + g, &Ah[cb * 2048 + rb * 32]);
    }
    for (int i = w; i < G / 16; i += 4) {
      const int rb = i * 16;
      const int ch = 256 + ordS[rb + lrow];
      const size_t g = ((size_t)b * 512 + ch) * L + k0 + kc + chunk * 8;
      gl16(qkF + g, &Bh[cb * 3072 + rb * 32]);
    }
  };

  stage(0, 0);
  __syncthreads();
  int cur = 0;
  for (int kc = 0; kc < 512; kc += 32) {
    if (kc + 32 < 512) stage(kc + 32, cur ^ 1);
    if (act) {
      const int aoff = cur * 2048 + (w * 16 + ln) * 32 + slot * 8;
      const short8v ah = *(const short8v*)&Ah[aoff];
      #pragma unroll
      for (int nf = 0; nf < NF; nf++) {
        const int boff = cur * 3072 + (nf * 16 + ln) * 32 + slot * 8;
        const short8v bh = *(const short8v*)&Bh[boff];
        acc[nf] = __builtin_amdgcn_mfma_f32_16x16x32_f16(ah, bh, acc[nf], 0, 0, 0);
      }
    }
    __syncthreads();
    cur ^= 1;
  }
  if (act) {
    float* dst = Spart + (size_t)b * 147456 + SPB + ks * G * G;
    #pragma unroll
    for (int nf = 0; nf < NF; nf++) {
      const int d = nf * 16 + ln;
      #pragma unroll
      for (int r = 0; r < 4; r++) {
        const int m = MB * 64 + w * 16 + lg * 4 + r;
        dst[m * G + d] = acc[nf][r];
      }
    }
  }
}

__global__ __launch_bounds__(256) void scores_kernel(const unsigned short* __restrict__ qkF,
    const int* __restrict__ order, float* __restrict__ Spart)
{
  __shared__ unsigned short Ah[2 * 64 * 32];
  __shared__ unsigned short Bh[2 * 96 * 32];
  __shared__ int ordS[96];
  switch (blockIdx.z) {
    case 0:  scores_body<32, 0, 0,   0, 0    >(qkF, order, Spart, Ah, Bh, ordS); break;
    case 1:  scores_body<64, 1, 32,  0, 8192 >(qkF, order, Spart, Ah, Bh, ordS); break;
    case 2:  scores_body<64, 2, 96,  0, 40960>(qkF, order, Spart, Ah, Bh, ordS); break;
    case 3:  scores_body<96, 3, 160, 0, 73728>(qkF, order, Spart, Ah, Bh, ordS); break;
    default: scores_body<96, 3, 160, 1, 73728>(qkF, order, Spart, Ah, Bh, ordS); break;
  }
}

// ---------------- reduce partials, scale, wave-parallel softmax -> single f16 attn ----------------
template<int G, int GI, int START, int SPB, int AOFF>
__device__ void softmax_body(const float* __restrict__ Spart, const float* __restrict__ invnq,
    const float* __restrict__ invnk, const float* __restrict__ temperature,
    unsigned short* __restrict__ attnP, float* Sm)
{
  constexpr int RQ = G / 4;
  const int t = threadIdx.x;
  const int b = blockIdx.x;
  const int r0 = blockIdx.z * RQ;
  const float temp = temperature[GI];
  for (int idx = t; idx < RQ * G; idx += 256) {
    const int rl = idx / G, d = idx - rl * G;
    const int gidx = (r0 + rl) * G + d;
    float s = 0.f;
    #pragma unroll
    for (int ks = 0; ks < 8; ks++)
      s += Spart[(size_t)b * 147456 + SPB + ks * G * G + gidx];
    Sm[idx] = s * invnq[b * 256 + START + r0 + rl] * invnk[b * 256 + START + d] * temp;
  }
  __syncthreads();
  const int wv = t >> 6, lane = t & 63;
  for (int r = wv; r < RQ; r += 4) {
    const float v0 = (lane < G) ? Sm[r * G + lane] : -INFINITY;
    const float v1 = (64 + lane < G) ? Sm[r * G + 64 + lane] : -INFINITY;
    float m = fmaxf(v0, v1);
    #pragma unroll
    for (int off = 32; off > 0; off >>= 1) m = fmaxf(m, __shfl_xor(m, off, 64));
    const float e0 = (lane < G) ? expf(v0 - m) : 0.f;
    const float e1 = (64 + lane < G) ? expf(v1 - m) : 0.f;
    float s = e0 + e1;
    #pragma unroll
    for (int off = 32; off > 0; off >>= 1) s += __shfl_xor(s, off, 64);
    const float inv = 1.0f / s;
    const size_t base = (size_t)b * 18432 + AOFF + (size_t)(r0 + r) * G;
    if (lane < G)      attnP[base + lane]      = f16b(e0 * inv);
    if (64 + lane < G) attnP[base + 64 + lane] = f16b(e1 * inv);
  }
}

__global__ __launch_bounds__(256) void softmax_kernel(const float* __restrict__ Spart,
    const float* __restrict__ invnq, const float* __restrict__ invnk,
    const float* __restrict__ temperature, unsigned short* __restrict__ attnP)
{
  extern __shared__ float smem[];
  switch (blockIdx.y) {
    case 0:  softmax_body<32, 0, 0,   0,     0   >(Spart, invnq, invnk, temperature, attnP, smem); break;
    case 1:  softmax_body<64, 1, 32,  8192,  1024>(Spart, invnq, invnk, temperature, attnP, smem); break;
    case 2:  softmax_body<64, 2, 96,  40960, 5120>(Spart, invnq, invnk, temperature, attnP, smem); break;
    default: softmax_body<96, 3, 160, 73728, 9216>(Spart, invnq, invnk, temperature, attnP, smem); break;
  }
}

// ---------------- PV via 1-pass f16 MFMA, fused z epilogue -> single f16 ----------------
template<int G, int GI, int START, int AOFF>
__device__ void pv_body(
    const unsigned short* __restrict__ vTS, const unsigned short* __restrict__ attnP,
    const unsigned short* __restrict__ zqT,
    unsigned short* __restrict__ outT, unsigned short* __restrict__ zT,
    unsigned short* Ah, unsigned short* Bh)
{
  constexpr int NF = G / 16;
  const int t = threadIdx.x, b = blockIdx.y, l0 = blockIdx.x * 128;
  const int w = t >> 6, lane = t & 63, ln = lane & 15, lg = lane >> 4;
  const int lrow  = lane >> 2;
  const int chunk = (lane & 3) ^ ((lane >> 4) & 3);
  const int slot  = lg ^ (ln >> 2);
  f32x4 z4 = {0.f, 0.f, 0.f, 0.f};
  f32x4 acc[2][NF];
  #pragma unroll
  for (int i = 0; i < 2; i++)
    #pragma unroll
    for (int j = 0; j < NF; j++) acc[i][j] = z4;
  for (int kc = 0; kc < G; kc += 32) {
    #pragma unroll
    for (int i = 0; i < 2; i++) {
      const int rb = w * 32 + i * 16;
      const size_t g = ((size_t)b * L + l0 + rb + lrow) * 256 + START + kc + chunk * 8;
      gl16(vTS + g, &Ah[rb * 32]);
    }
    for (int i = w; i < G / 16; i += 4) {
      const int rb = i * 16;
      const size_t g = (size_t)b * 18432 + AOFF + (size_t)(rb + lrow) * G + kc + chunk * 8;
      gl16(attnP + g, &Bh[rb * 32]);
    }
    __syncthreads();
    short8v bhf[NF];
    #pragma unroll
    for (int nf = 0; nf < NF; nf++)
      bhf[nf] = *(const short8v*)&Bh[(nf * 16 + ln) * 32 + slot * 8];
    #pragma unroll
    for (int mi = 0; mi < 2; mi++) {
      const int aoff = ((w * 2 + mi) * 16 + ln) * 32 + slot * 8;
      const short8v ah = *(const short8v*)&Ah[aoff];
      #pragma unroll
      for (int nf = 0; nf < NF; nf++)
        acc[mi][nf] = __builtin_amdgcn_mfma_f32_16x16x32_f16(ah, bhf[nf], acc[mi][nf], 0, 0, 0);
    }
    __syncthreads();
  }
  #pragma unroll
  for (int mi = 0; mi < 2; mi++) {
    const int lbase = l0 + (w * 2 + mi) * 16 + lg * 4;
    #pragma unroll
    for (int nf = 0; nf < NF; nf++) {
      const int col = START + nf * 16 + ln;
      #pragma unroll
      for (int r = 0; r < 4; r++) {
        const size_t idx = ((size_t)b * L + lbase + r) * 256 + col;
        const float v = acc[mi][nf][r];
        outT[idx] = f16b(v);
        zT[idx]   = f16b(v + f16tof(zqT[idx]));
      }
    }
  }
}

__global__ __launch_bounds__(256) void pv_kernel(
    const unsigned short* __restrict__ vTS, const unsigned short* __restrict__ attnP,
    const unsigned short* __restrict__ zqT,
    unsigned short* __restrict__ outT, unsigned short* __restrict__ zT)
{
  __shared__ unsigned short Ah[128 * 32];
  __shared__ unsigned short Bh[96 * 32];
  switch (blockIdx.z) {
    case 0:  pv_body<32, 0, 0,   0   >(vTS, attnP, zqT, outT, zT, Ah, Bh); break;
    case 1:  pv_body<64, 1, 32,  1024>(vTS, attnP, zqT, outT, zT, Ah, Bh); break;
    case 2:  pv_body<64, 2, 96,  5120>(vTS, attnP, zqT, outT, zT, Ah, Bh); break;
    default: pv_body<96, 3, 160, 9216>(vTS, attnP, zqT, outT, zT, Ah, Bh); break;
  }
}

// ---------------- qv_cache ----------------
__global__ __launch_bounds__(256) void qv_kernel(const float* __restrict__ sumq,
    const float* __restrict__ sumk, const float* __restrict__ invnq,
    const float* __restrict__ invnk, float* __restrict__ out2)
{
  const int b = blockIdx.x >> 8, r = blockIdx.x & 255;
  float val = 0.f;
  {
    const int idx = b * 256 + 0 + (r & 31);
    val += fmaf(sumq[idx], invnq[idx], sumk[idx] * invnk[idx]);
  }
  {
    const int idx = b * 256 + 32 + (r & 63);
    val += fmaf(sumq[idx], invnq[idx], sumk[idx] * invnk[idx]);
  }
  {
    const int idx = b * 256 + 96 + (r & 63);
    val += fmaf(sumq[idx], invnq[idx], sumk[idx] * invnk[idx]);
  }
  if (r < 192) {
    const int rm = (r < 96) ? r : r - 96;
    const int idx = b * 256 + 160 + rm;
    val += fmaf(sumq[idx], invnq[idx], sumk[idx] * invnk[idx]);
  }
  val *= (1.0f / 4096.f) * 0.25f * 0.9f;
  const float4 o = {val, val, val, val};
  float4* dst = reinterpret_cast<float4*>(out2 + ((size_t)b * C + r) * L);
  for (int i = threadIdx.x; i < 1024; i += 256) dst[i] = o;
}

// ---------------- launch ----------------
extern "C" void kernel_launch(void* const* d_in, const int* in_sizes, int n_in,
                              void* d_out, int out_size, void* d_ws, size_t ws_size,
                              hipStream_t stream)
{
  const float* x           = (const float*)d_in[0];
  const float* temperature = (const float*)d_in[1];
  const float* w_qkv       = (const float*)d_in[2];
  const float* w_dw        = (const float*)d_in[3];
  const float* w_proj      = (const float*)d_in[4];
  const float* w_gate      = (const float*)d_in[5];
  const float* b_gate      = (const float*)d_in[6];
  const float* w_down      = (const float*)d_in[7];
  const float* b_down      = (const float*)d_in[8];
  const float* w_up        = (const float*)d_in[9];
  const float* b_up        = (const float*)d_in[10];

  if (ws_size < 202548224ULL) return;

  char* ws = (char*)d_ws;
  // Region A [0, 96M):
  float*          qkv_pre  = (float*)(ws);                      // 96MB, dead after dwconv
  unsigned short* vTS      = (unsigned short*)(ws);              // 16MB (f16 single)
  unsigned short* zqT      = (unsigned short*)(ws + 16777216);   // 16MB
  float*          Spart    = (float*)(ws + 33554432);            // 4.72MB
  unsigned short* attnP    = (unsigned short*)(ws + 38797312);   // 288KB (f16 single)
  unsigned short* preprojh = (unsigned short*)(ws);              // 16MB (after pv; bf16 pair)
  unsigned short* preprojl = (unsigned short*)(ws + 16777216);   // 16MB
  // Region B [96M, 192M):
  unsigned short* XThi     = (unsigned short*)(ws + 100663296);  // 16MB (f16)
  unsigned short* XTlo     = (unsigned short*)(ws + 117440512);  // 16MB
  unsigned short* qkF      = (unsigned short*)(ws + 100663296);  // 32MB (after qkv; f16 single)
  unsigned short* vF       = (unsigned short*)(ws + 134217728);  // 16MB (f16 single)
  unsigned short* outT     = (unsigned short*)(ws + 150994944);  // 16MB (f16 single)
  unsigned short* zT       = (unsigned short*)(ws + 167772160);  // 16MB (f16 single)
  unsigned short* gated    = (unsigned short*)(ws + 184549376);  // 16MB (f16 single)
  unsigned short* mid      = (unsigned short*)(ws + 100663296);  // 8MB (after scores; f16 single)
  // Region C [192M+, persistent):
  unsigned short* Wf16   = (unsigned short*)(ws + 201326592);    // 655KB
  unsigned short* WprojH = (unsigned short*)(ws + 201981952);    // 128KB
  unsigned short* WprojL = (unsigned short*)(ws + 202113024);    // 128KB
  float* csum   = (float*)(ws + 202244096);
  float* csumsq = (float*)(ws + 202260480);
  float* sumq   = (float*)(ws + 202276864);
  float* sumk   = (float*)(ws + 202285056);
  float* invnq  = (float*)(ws + 202293248);
  float* invnk  = (float*)(ws + 202301440);
  int*   order  = (int*)(ws + 202309632);

  float* out_all = (float*)d_out;
  float* qv_out  = out_all + (size_t)B * C * L;

  // 0. weight + input splits
  wsplit_kernel<<<1536, 256, 0, stream>>>(w_qkv, w_gate, w_down, w_up, w_proj,
                                          Wf16, WprojH, WprojL);
  splitx_kernel<<<dim3(64, 4, 8), 256, 0, stream>>>(x, XThi, XTlo);
  // 1. qkv = w_qkv @ x  (mixed: q-blocks 2-pass, k/v-blocks 1-pass; out fp32 [b][768][L])
  hgemm<256, 0, 2><<<dim3(32, 6, 8), 256, 0, stream>>>(
      XThi, XTlo, Wf16, qkv_pre, nullptr, nullptr, nullptr, nullptr, 768);
  // 2. depthwise conv -> q,k,v single f16 + channel stats
  dwconv2_kernel<<<dim3(768, 8), 256, 0, stream>>>(qkv_pre, w_dw, qkF, vF, csum, csumsq);
  // 3. channel ordering + sorted stats
  rankstats_kernel<<<1, 256, 0, stream>>>(csum, csumsq, order, sumq, sumk, invnq, invnk);
  // 4. pack v^T sorted + zq (single f16)
  vpack_kernel<<<dim3(64, 8), 256, 0, stream>>>(vF, qkF, order, invnq, invnk, vTS, zqT);
  // 5. attention (1-pass f16)
  scores_kernel<<<dim3(8, 8, 5), 256, 0, stream>>>(qkF, order, Spart);
  softmax_kernel<<<dim3(8, 4, 4), 256, 9216, stream>>>(Spart, invnq, invnk, temperature, attnP);
  pv_kernel<<<dim3(32, 8, 4), 256, 0, stream>>>(vTS, attnP, zqT, outT, zT);
  // 6. MLP chain (1-pass f16)
  hgemm<256, 2, 1><<<dim3(32, 2, 8), 256, 0, stream>>>(
      zT, nullptr, Wf16 + 196608, nullptr, gated, nullptr, b_gate, zT, 256);
  hgemm<256, 1, 1><<<dim3(32, 1, 8), 256, 0, stream>>>(
      gated, nullptr, Wf16 + 262144, nullptr, mid, nullptr, b_down, nullptr, 128);
  hgemm<128, 5, 1><<<dim3(32, 2, 8), 256, 0, stream>>>(
      mid, nullptr, Wf16 + 294912, nullptr, preprojh, preprojl, b_up, outT, 256);
  // 7. final projection (bf16 3-pass precision firewall) -> output 0
  mgemm<256><<<dim3(32, 2, 8), 256, 0, stream>>>(
      preprojh, preprojl, WprojH, WprojL, out_all, 256);
  // 8. qv_cache -> output 1
  qv_kernel<<<2048, 256, 0, stream>>>(sumq, sumk, invnq, invnk, qv_out);
}

// Round 9
// 219.327 us; speedup vs baseline: 2.7368x; 1.0880x over previous
//
#include <hip/hip_runtime.h>
#include <hip/hip_fp16.h>
#include <math.h>

#define B 8
#define C 256
#define L 4096
#define OC3 768

typedef __attribute__((ext_vector_type(8))) short short8v;
typedef __attribute__((ext_vector_type(8))) unsigned short u16x8;
typedef __attribute__((ext_vector_type(4))) float f32x4;

// ---------------- helpers ----------------
__device__ __forceinline__ float gelu_exact(float x){
  return 0.5f * x * (1.0f + erff(x * 0.70710678118654752440f));
}
__device__ __forceinline__ float wave_sum(float v){
  #pragma unroll
  for (int off = 32; off > 0; off >>= 1) v += __shfl_down(v, off, 64);
  return v;
}
__device__ __forceinline__ unsigned short bf16_rne(float f){
  unsigned int u = __float_as_uint(f);
  unsigned int r = u + 0x7FFFu + ((u >> 16) & 1u);
  return (unsigned short)(r >> 16);
}
__device__ __forceinline__ float bf16_tof(unsigned short h){
  return __uint_as_float(((unsigned int)h) << 16);
}
__device__ __forceinline__ unsigned int splitpack(float v){
  unsigned short hi = bf16_rne(v);
  float lof = v - bf16_tof(hi);
  unsigned short lo = bf16_rne(lof);
  return (unsigned int)hi | ((unsigned int)lo << 16);
}
__device__ __forceinline__ unsigned short f16b(float f){
  return __half_as_ushort(__float2half_rn(f));
}
__device__ __forceinline__ float f16tof(unsigned short u){
  return __half2float(__ushort_as_half(u));
}
__device__ __forceinline__ unsigned int splitpackh(float v){
  unsigned short hi = f16b(v);
  float lof = v - f16tof(hi);
  unsigned short lo = f16b(lof);
  return (unsigned int)hi | ((unsigned int)lo << 16);
}
// async global->LDS 16B per lane; LDS dest must be wave-uniform base
__device__ __forceinline__ void gl16(const unsigned short* g, unsigned short* l){
  __builtin_amdgcn_global_load_lds(
      (const __attribute__((address_space(1))) void*)g,
      (__attribute__((address_space(3))) void*)l, 16, 0, 0);
}

// ---------------- weight split ----------------
// Wf16: qkv@0 (196608), gate@196608 (65536), down@262144 (32768), up@294912 (32768) -- f16
// proj -> f16 hi/lo PAIR planes (65536 each): near-exact weights for the firewall
__global__ __launch_bounds__(256) void wsplit_kernel(
    const float* __restrict__ wqkv, const float* __restrict__ wgate,
    const float* __restrict__ wdown, const float* __restrict__ wup,
    const float* __restrict__ wproj,
    unsigned short* __restrict__ Wf16,
    unsigned short* __restrict__ PH, unsigned short* __restrict__ PLo)
{
  int idx = blockIdx.x * 256 + threadIdx.x;   // 0..393215
  if (idx < 327680) {
    float s;
    if (idx < 196608)      s = wqkv[idx];
    else if (idx < 262144) s = wgate[idx - 196608];
    else if (idx < 294912) s = wdown[idx - 262144];
    else                   s = wup[idx - 294912];
    Wf16[idx] = f16b(s);
  } else {
    int j = idx - 327680;   // 0..65535
    float wv = wproj[j];
    unsigned short hh = f16b(wv);
    PH[j]  = hh;
    PLo[j] = f16b(wv - f16tof(hh));
  }
}

// ---------------- x [b][c][l] fp32 -> xT hi/lo f16 [b][l][c] ----------------
__global__ __launch_bounds__(256) void splitx_kernel(const float* __restrict__ x,
    unsigned short* __restrict__ XThi, unsigned short* __restrict__ XTlo)
{
  __shared__ float st[64][68];
  const int b = blockIdx.z, c0 = blockIdx.y * 64, lb = blockIdx.x * 64;
  const int t = threadIdx.x;
  #pragma unroll
  for (int i = 0; i < 4; i++) {
    int row = (t >> 4) + i * 16;
    int col = (t & 15) * 4;
    float4 v = *(const float4*)&x[((size_t)b * C + c0 + row) * L + lb + col];
    st[row][col] = v.x; st[row][col+1] = v.y; st[row][col+2] = v.z; st[row][col+3] = v.w;
  }
  __syncthreads();
  const int l = t >> 2, cq = t & 3;
  u16x8 hv0, hv1, lv0, lv1;
  #pragma unroll
  for (int i = 0; i < 16; i++) {
    unsigned int p = splitpackh(st[cq * 16 + i][l]);
    if (i < 8) { hv0[i] = (unsigned short)(p & 0xFFFFu); lv0[i] = (unsigned short)(p >> 16); }
    else       { hv1[i-8] = (unsigned short)(p & 0xFFFFu); lv1[i-8] = (unsigned short)(p >> 16); }
  }
  size_t o = ((size_t)b * L + lb + l) * C + c0 + cq * 16;
  *(u16x8*)&XThi[o]     = hv0;
  *(u16x8*)&XThi[o + 8] = hv1;
  *(u16x8*)&XTlo[o]     = lv0;
  *(u16x8*)&XTlo[o + 8] = lv1;
}

// ---------------- f16 MFMA GEMM, 2-phase double-buffered ----------------
// MODE: 1 = A single plane          (planes: A, B)
//       2 = A mixed pair: blockIdx.y<2 2-pass, else 1-pass (planes: Ahi, Alo, B)
//       3 = B pair (weights hi/lo), A single; 2-pass       (planes: A, Bh, Bl=Alo_g)
// EPI:  0 = store fp32 [b][o][L]
//       1 = +bias, store f16 [b][l][o]
//       2 = gelu(acc+bias)*extra, store f16 [b][l][o]
//       5 = acc+bias+extra, store f16 [b][l][o]
//       6 = mixed qkv: y<2 -> fp32 q[b][256][L]; y>=2 -> f16 kv[b][512][L]
template<int KTOT, int EPI, int MODE>
__global__ __launch_bounds__(256) void hgemm(
    const unsigned short* __restrict__ Ahi_g, const unsigned short* __restrict__ Alo_g,
    const unsigned short* __restrict__ Bw_g,
    float* __restrict__ outF,
    unsigned short* __restrict__ outH,
    const float* __restrict__ bias, const unsigned short* __restrict__ extraH,
    int Ntot)
{
  constexpr int NP = (MODE == 1) ? 2 : 3;
  __shared__ unsigned short SB[2][NP][128 * 32];
  const int t  = threadIdx.x;
  const int lb = blockIdx.x * 128;
  const int o0 = blockIdx.y * 128;
  const int b  = blockIdx.z;
  const int w  = t >> 6, lane = t & 63;
  const int wm = w >> 1, wn = w & 1;
  const int ln = lane & 15, lg = lane >> 4;
  const int lrow  = lane >> 2;
  const int chunk = (lane & 3) ^ ((lane >> 4) & 3);
  const int slot  = lg ^ (ln >> 2);
  const bool twop = (MODE == 2) ? (blockIdx.y < 2) : false;

  f32x4 z4 = {0.f, 0.f, 0.f, 0.f};
  f32x4 acc[4][4];
  #pragma unroll
  for (int i = 0; i < 4; i++)
    #pragma unroll
    for (int j = 0; j < 4; j++) acc[i][j] = z4;

  const size_t arow0 = (size_t)b * L + lb;
  constexpr int NKT = KTOT / 32;

  auto stage = [&](int kt, int cb) {
    const int k0 = kt * 32;
    #pragma unroll
    for (int i = 0; i < 2; i++) {
      const int rb = w * 32 + i * 16;
      const size_t ga = (arow0 + rb + lrow) * KTOT + k0 + chunk * 8;
      gl16(Ahi_g + ga, &SB[cb][0][rb * 32]);
      if (MODE == 2 && twop) gl16(Alo_g + ga, &SB[cb][1][rb * 32]);
      const size_t gb = (size_t)(o0 + rb + lrow) * KTOT + k0 + chunk * 8;
      if (MODE == 3) {
        gl16(Bw_g + gb,  &SB[cb][1][rb * 32]);
        gl16(Alo_g + gb, &SB[cb][2][rb * 32]);
      } else {
        gl16(Bw_g + gb, &SB[cb][NP - 1][rb * 32]);
      }
    }
  };

  stage(0, 0);
  __syncthreads();
  int cur = 0;
  for (int kt = 0; kt < NKT; ++kt) {
    if (kt + 1 < NKT) stage(kt + 1, cur ^ 1);
    if (MODE == 3) {
      short8v bh[4], bl[4];
      #pragma unroll
      for (int nf = 0; nf < 4; nf++) {
        const int off = (wn * 64 + nf * 16 + ln) * 32 + slot * 8;
        bh[nf] = *(const short8v*)&SB[cur][1][off];
        bl[nf] = *(const short8v*)&SB[cur][2][off];
      }
      #pragma unroll
      for (int mf = 0; mf < 4; mf++) {
        const int off = (wm * 64 + mf * 16 + ln) * 32 + slot * 8;
        const short8v a = *(const short8v*)&SB[cur][0][off];
        #pragma unroll
        for (int nf = 0; nf < 4; nf++) {
          acc[mf][nf] = __builtin_amdgcn_mfma_f32_16x16x32_f16(a, bh[nf], acc[mf][nf], 0, 0, 0);
          acc[mf][nf] = __builtin_amdgcn_mfma_f32_16x16x32_f16(a, bl[nf], acc[mf][nf], 0, 0, 0);
        }
      }
    } else {
      short8v bwf[4];
      #pragma unroll
      for (int nf = 0; nf < 4; nf++) {
        const int off = (wn * 64 + nf * 16 + ln) * 32 + slot * 8;
        bwf[nf] = *(const short8v*)&SB[cur][NP - 1][off];
      }
      #pragma unroll
      for (int mf = 0; mf < 4; mf++) {
        const int off = (wm * 64 + mf * 16 + ln) * 32 + slot * 8;
        const short8v ah = *(const short8v*)&SB[cur][0][off];
        #pragma unroll
        for (int nf = 0; nf < 4; nf++)
          acc[mf][nf] = __builtin_amdgcn_mfma_f32_16x16x32_f16(ah, bwf[nf], acc[mf][nf], 0, 0, 0);
        if (MODE == 2) {
          if (twop) {
            const short8v al = *(const short8v*)&SB[cur][1][off];
            #pragma unroll
            for (int nf = 0; nf < 4; nf++)
              acc[mf][nf] = __builtin_amdgcn_mfma_f32_16x16x32_f16(al, bwf[nf], acc[mf][nf], 0, 0, 0);
          }
        }
      }
    }
    __syncthreads();
    cur ^= 1;
  }
  #pragma unroll
  for (int mf = 0; mf < 4; mf++) {
    const int mbase = lb + wm * 64 + mf * 16 + lg * 4;
    #pragma unroll
    for (int nf = 0; nf < 4; nf++) {
      const int o = o0 + wn * 64 + nf * 16 + ln;
      if (EPI == 0) {
        float4 r;
        r.x = acc[mf][nf][0]; r.y = acc[mf][nf][1];
        r.z = acc[mf][nf][2]; r.w = acc[mf][nf][3];
        *(float4*)&outF[((size_t)b * Ntot + o) * L + mbase] = r;
      } else if (EPI == 6) {
        if (o0 < 256) {
          float4 r;
          r.x = acc[mf][nf][0]; r.y = acc[mf][nf][1];
          r.z = acc[mf][nf][2]; r.w = acc[mf][nf][3];
          *(float4*)&outF[((size_t)b * 256 + o) * L + mbase] = r;
        } else {
          ushort4 r;
          r.x = f16b(acc[mf][nf][0]); r.y = f16b(acc[mf][nf][1]);
          r.z = f16b(acc[mf][nf][2]); r.w = f16b(acc[mf][nf][3]);
          *(ushort4*)&outH[((size_t)b * 512 + (o - 256)) * L + mbase] = r;
        }
      } else {
        const float bv = bias ? bias[o] : 0.0f;
        #pragma unroll
        for (int r = 0; r < 4; r++) {
          const size_t idx = ((size_t)b * L + mbase + r) * Ntot + o;
          float v = acc[mf][nf][r] + bv;
          if (EPI == 2) { v = gelu_exact(v) * f16tof(extraH[idx]); }
          if (EPI == 5) { v = v + f16tof(extraH[idx]); }
          outH[idx] = f16b(v);
        }
      }
    }
  }
}

// ---------------- depthwise 3x3 conv: q from fp32, k/v from f16; out single f16 ----------------
__global__ __launch_bounds__(256) void dwconv2_kernel(
    const float* __restrict__ inQ, const unsigned short* __restrict__ inKV,
    const float* __restrict__ wdw,
    unsigned short* __restrict__ qkF, unsigned short* __restrict__ vF,
    float* __restrict__ csum, float* __restrict__ csumsq)
{
  __shared__ float p[66][73];
  __shared__ float rs[4][2];
  const int ch = blockIdx.x;
  const int b  = blockIdx.y;
  const int t  = threadIdx.x;
  float wt[9];
  #pragma unroll
  for (int j = 0; j < 9; j++) wt[j] = wdw[ch * 9 + j];
  if (t < 66) { p[0][3 + t] = 0.f; p[65][3 + t] = 0.f; }
  if (t < 64) { p[1 + t][3] = 0.f; p[1 + t][68] = 0.f; }
  if (ch < 256) {
    const size_t base = ((size_t)b * 256 + ch) * L;
    #pragma unroll
    for (int i = 0; i < 4; i++) {
      int pix = (i * 256 + t) * 4;
      const float4 v = *reinterpret_cast<const float4*>(&inQ[base + pix]);
      int h = pix >> 6, ww = pix & 63;
      p[1+h][4+ww] = v.x; p[1+h][5+ww] = v.y; p[1+h][6+ww] = v.z; p[1+h][7+ww] = v.w;
    }
  } else {
    const size_t base = ((size_t)b * 512 + (ch - 256)) * L + t * 16;
    const u16x8 a0 = *(const u16x8*)&inKV[base];
    const u16x8 a1 = *(const u16x8*)&inKV[base + 8];
    const int h = t >> 2, w0 = (t & 3) * 16;
    #pragma unroll
    for (int j = 0; j < 8; j++) {
      p[1+h][4+w0+j]   = f16tof((unsigned short)a0[j]);
      p[1+h][12+w0+j]  = f16tof((unsigned short)a1[j]);
    }
  }
  __syncthreads();
  const int h  = t >> 2;
  const int w0 = (t & 3) * 16;
  float r0a[18], r1a[18], r2a[18];
  #pragma unroll
  for (int c = 0; c < 18; c++) {
    r0a[c] = p[h][w0 + 3 + c];
    r1a[c] = p[h + 1][w0 + 3 + c];
    r2a[c] = p[h + 2][w0 + 3 + c];
  }
  float res[16];
  float s = 0.f, s2 = 0.f;
  #pragma unroll
  for (int j = 0; j < 16; j++) {
    float acc;
    acc = r0a[j] * wt[0];
    acc = fmaf(r0a[j+1], wt[1], acc);
    acc = fmaf(r0a[j+2], wt[2], acc);
    acc = fmaf(r1a[j],   wt[3], acc);
    acc = fmaf(r1a[j+1], wt[4], acc);
    acc = fmaf(r1a[j+2], wt[5], acc);
    acc = fmaf(r2a[j],   wt[6], acc);
    acc = fmaf(r2a[j+1], wt[7], acc);
    acc = fmaf(r2a[j+2], wt[8], acc);
    res[j] = acc;
    s += acc;
    s2 = fmaf(acc, acc, s2);
  }
  u16x8 h0, h1;
  #pragma unroll
  for (int j = 0; j < 16; j++) {
    if (j < 8) h0[j]   = f16b(res[j]);
    else       h1[j-8] = f16b(res[j]);
  }
  if (ch < 512) {
    const size_t qi = ((size_t)b * 512 + ch) * L + t * 16;
    *(u16x8*)&qkF[qi]     = h0;
    *(u16x8*)&qkF[qi + 8] = h1;
    s = wave_sum(s); s2 = wave_sum(s2);
    const int lane = t & 63, wid = t >> 6;
    if (lane == 0) { rs[wid][0] = s; rs[wid][1] = s2; }
    __syncthreads();
    if (t == 0) {
      csum[b * 512 + ch]   = rs[0][0] + rs[1][0] + rs[2][0] + rs[3][0];
      csumsq[b * 512 + ch] = rs[0][1] + rs[1][1] + rs[2][1] + rs[3][1];
    }
  } else {
    const size_t vi = ((size_t)b * 256 + (ch - 512)) * L + t * 16;
    *(u16x8*)&vF[vi]     = h0;
    *(u16x8*)&vF[vi + 8] = h1;
  }
}

// ---------------- rank (stable descending) + sorted stats ----------------
__global__ __launch_bounds__(256) void rankstats_kernel(
    const float* __restrict__ csum, const float* __restrict__ csumsq,
    int* __restrict__ order,
    float* __restrict__ sumq, float* __restrict__ sumk,
    float* __restrict__ invnq, float* __restrict__ invnk)
{
  const int c = threadIdx.x;
  float key = 0.f;
  #pragma unroll
  for (int b = 0; b < 8; b++) key += csum[b * 512 + c];
  __shared__ float keys[256];
  __shared__ int ordS[256];
  keys[c] = key;
  __syncthreads();
  int rank = 0;
  for (int j = 0; j < 256; j++) {
    float kj = keys[j];
    rank += (kj > key) || (kj == key && j < c);
  }
  order[rank] = c;
  ordS[rank] = c;
  __syncthreads();
  const int ch = ordS[c];
  #pragma unroll
  for (int b = 0; b < 8; b++) {
    sumq[b * 256 + c]  = csum[b * 512 + ch];
    invnq[b * 256 + c] = 1.0f / fmaxf(sqrtf(csumsq[b * 512 + ch]), 1e-12f);
    sumk[b * 256 + c]  = csum[b * 512 + 256 + ch];
    invnk[b * 256 + c] = 1.0f / fmaxf(sqrtf(csumsq[b * 512 + 256 + ch]), 1e-12f);
  }
}

// ---------------- pack: vTS = v^T sorted (f16) [b][l][r]; zqT = qn+kn (f16) [b][l][r] ----------------
__global__ __launch_bounds__(256) void vpack_kernel(
    const unsigned short* __restrict__ vF, const unsigned short* __restrict__ qkF,
    const int* __restrict__ order,
    const float* __restrict__ invnq, const float* __restrict__ invnk,
    unsigned short* __restrict__ vTS, unsigned short* __restrict__ zqT)
{
  __shared__ float vt[64][65];
  __shared__ float zt[64][65];
  __shared__ int   ordS[256];
  __shared__ float iqS[256], ikS[256];
  const int t = threadIdx.x, lb = blockIdx.x * 64, b = blockIdx.y;
  ordS[t] = order[t];
  iqS[t] = invnq[b * 256 + t];
  ikS[t] = invnk[b * 256 + t];
  __syncthreads();
  for (int cc = 0; cc < 4; cc++) {
    const int r0 = cc * 64;
    for (int i = t; i < 1024; i += 256) {
      const int row = i >> 4, q = i & 15;
      const int ch = ordS[r0 + row];
      const float iq = iqS[r0 + row], ik = ikS[r0 + row];
      const ushort4 v4 = *(const ushort4*)&vF[((size_t)b * 256 + ch) * L + lb + q * 4];
      vt[q*4+0][row] = f16tof(v4.x); vt[q*4+1][row] = f16tof(v4.y);
      vt[q*4+2][row] = f16tof(v4.z); vt[q*4+3][row] = f16tof(v4.w);
      const ushort4 q4 = *(const ushort4*)&qkF[((size_t)b * 512 + ch) * L + lb + q * 4];
      const ushort4 k4 = *(const ushort4*)&qkF[((size_t)b * 512 + 256 + ch) * L + lb + q * 4];
      zt[q*4+0][row] = f16tof(q4.x) * iq + f16tof(k4.x) * ik;
      zt[q*4+1][row] = f16tof(q4.y) * iq + f16tof(k4.y) * ik;
      zt[q*4+2][row] = f16tof(q4.z) * iq + f16tof(k4.z) * ik;
      zt[q*4+3][row] = f16tof(q4.w) * iq + f16tof(k4.w) * ik;
    }
    __syncthreads();
    const int l = t >> 2, qq = t & 3;
    const size_t ob = ((size_t)b * L + lb + l) * 256 + r0 + qq * 16;
    u16x8 vv[2], zz[2];
    #pragma unroll
    for (int j = 0; j < 16; j++) {
      vv[j>>3][j&7] = f16b(vt[l][qq*16 + j]);
      zz[j>>3][j&7] = f16b(zt[l][qq*16 + j]);
    }
    *(u16x8*)&vTS[ob]     = vv[0]; *(u16x8*)&vTS[ob + 8] = vv[1];
    *(u16x8*)&zqT[ob]     = zz[0]; *(u16x8*)&zqT[ob + 8] = zz[1];
    __syncthreads();
  }
}

// ---------------- scores via 1-pass f16 MFMA, 2-phase gather staging ----------------
template<int G, int GI, int START, int MB, int SPB>
__device__ void scores_body(const unsigned short* __restrict__ qkF,
    const int* __restrict__ order, float* __restrict__ Spart,
    unsigned short* Ah, unsigned short* Bh, int* ordS)
{
  constexpr int MR = (G - MB * 64 < 64) ? (G - MB * 64) : 64;
  constexpr int NF = G / 16;
  const int t = threadIdx.x, ks = blockIdx.x, b = blockIdx.y;
  const int w = t >> 6, lane = t & 63, ln = lane & 15, lg = lane >> 4;
  const int lrow  = lane >> 2;
  const int chunk = (lane & 3) ^ ((lane >> 4) & 3);
  const int slot  = lg ^ (ln >> 2);
  for (int i = t; i < G; i += 256) ordS[i] = order[START + i];
  __syncthreads();
  const int k0 = ks * 512;
  const bool act = (w * 16) < MR;
  f32x4 z4 = {0.f, 0.f, 0.f, 0.f};
  f32x4 acc[NF];
  #pragma unroll
  for (int i = 0; i < NF; i++) acc[i] = z4;

  auto stage = [&](int kc, int cb) {
    for (int i = w; i < MR / 16; i += 4) {
      const int rb = i * 16;
      const int ch = ordS[MB * 64 + rb + lrow];
      const size_t g = ((size_t)b * 512 + ch) * L + k0 + kc + chunk * 8;
      gl16(qkF + g, &Ah[cb * 2048 + rb * 32]);
    }
    for (int i = w; i < G / 16; i += 4) {
      const int rb = i * 16;
      const int ch = 256 + ordS[rb + lrow];
      const size_t g = ((size_t)b * 512 + ch) * L + k0 + kc + chunk * 8;
      gl16(qkF + g, &Bh[cb * 3072 + rb * 32]);
    }
  };

  stage(0, 0);
  __syncthreads();
  int cur = 0;
  for (int kc = 0; kc < 512; kc += 32) {
    if (kc + 32 < 512) stage(kc + 32, cur ^ 1);
    if (act) {
      const int aoff = cur * 2048 + (w * 16 + ln) * 32 + slot * 8;
      const short8v ah = *(const short8v*)&Ah[aoff];
      #pragma unroll
      for (int nf = 0; nf < NF; nf++) {
        const int boff = cur * 3072 + (nf * 16 + ln) * 32 + slot * 8;
        const short8v bh = *(const short8v*)&Bh[boff];
        acc[nf] = __builtin_amdgcn_mfma_f32_16x16x32_f16(ah, bh, acc[nf], 0, 0, 0);
      }
    }
    __syncthreads();
    cur ^= 1;
  }
  if (act) {
    float* dst = Spart + (size_t)b * 147456 + SPB + ks * G * G;
    #pragma unroll
    for (int nf = 0; nf < NF; nf++) {
      const int d = nf * 16 + ln;
      #pragma unroll
      for (int r = 0; r < 4; r++) {
        const int m = MB * 64 + w * 16 + lg * 4 + r;
        dst[m * G + d] = acc[nf][r];
      }
    }
  }
}

__global__ __launch_bounds__(256) void scores_kernel(const unsigned short* __restrict__ qkF,
    const int* __restrict__ order, float* __restrict__ Spart)
{
  __shared__ unsigned short Ah[2 * 64 * 32];
  __shared__ unsigned short Bh[2 * 96 * 32];
  __shared__ int ordS[96];
  switch (blockIdx.z) {
    case 0:  scores_body<32, 0, 0,   0, 0    >(qkF, order, Spart, Ah, Bh, ordS); break;
    case 1:  scores_body<64, 1, 32,  0, 8192 >(qkF, order, Spart, Ah, Bh, ordS); break;
    case 2:  scores_body<64, 2, 96,  0, 40960>(qkF, order, Spart, Ah, Bh, ordS); break;
    case 3:  scores_body<96, 3, 160, 0, 73728>(qkF, order, Spart, Ah, Bh, ordS); break;
    default: scores_body<96, 3, 160, 1, 73728>(qkF, order, Spart, Ah, Bh, ordS); break;
  }
}

// ---------------- reduce partials, scale, wave-parallel softmax -> single f16 attn ----------------
template<int G, int GI, int START, int SPB, int AOFF>
__device__ void softmax_body(const float* __restrict__ Spart, const float* __restrict__ invnq,
    const float* __restrict__ invnk, const float* __restrict__ temperature,
    unsigned short* __restrict__ attnP, float* Sm)
{
  constexpr int RQ = G / 4;
  const int t = threadIdx.x;
  const int b = blockIdx.x;
  const int r0 = blockIdx.z * RQ;
  const float temp = temperature[GI];
  for (int idx = t; idx < RQ * G; idx += 256) {
    const int rl = idx / G, d = idx - rl * G;
    const int gidx = (r0 + rl) * G + d;
    float s = 0.f;
    #pragma unroll
    for (int ks = 0; ks < 8; ks++)
      s += Spart[(size_t)b * 147456 + SPB + ks * G * G + gidx];
    Sm[idx] = s * invnq[b * 256 + START + r0 + rl] * invnk[b * 256 + START + d] * temp;
  }
  __syncthreads();
  const int wv = t >> 6, lane = t & 63;
  for (int r = wv; r < RQ; r += 4) {
    const float v0 = (lane < G) ? Sm[r * G + lane] : -INFINITY;
    const float v1 = (64 + lane < G) ? Sm[r * G + 64 + lane] : -INFINITY;
    float m = fmaxf(v0, v1);
    #pragma unroll
    for (int off = 32; off > 0; off >>= 1) m = fmaxf(m, __shfl_xor(m, off, 64));
    const float e0 = (lane < G) ? expf(v0 - m) : 0.f;
    const float e1 = (64 + lane < G) ? expf(v1 - m) : 0.f;
    float s = e0 + e1;
    #pragma unroll
    for (int off = 32; off > 0; off >>= 1) s += __shfl_xor(s, off, 64);
    const float inv = 1.0f / s;
    const size_t base = (size_t)b * 18432 + AOFF + (size_t)(r0 + r) * G;
    if (lane < G)      attnP[base + lane]      = f16b(e0 * inv);
    if (64 + lane < G) attnP[base + 64 + lane] = f16b(e1 * inv);
  }
}

__global__ __launch_bounds__(256) void softmax_kernel(const float* __restrict__ Spart,
    const float* __restrict__ invnq, const float* __restrict__ invnk,
    const float* __restrict__ temperature, unsigned short* __restrict__ attnP)
{
  extern __shared__ float smem[];
  switch (blockIdx.y) {
    case 0:  softmax_body<32, 0, 0,   0,     0   >(Spart, invnq, invnk, temperature, attnP, smem); break;
    case 1:  softmax_body<64, 1, 32,  8192,  1024>(Spart, invnq, invnk, temperature, attnP, smem); break;
    case 2:  softmax_body<64, 2, 96,  40960, 5120>(Spart, invnq, invnk, temperature, attnP, smem); break;
    default: softmax_body<96, 3, 160, 73728, 9216>(Spart, invnq, invnk, temperature, attnP, smem); break;
  }
}

// ---------------- PV via 1-pass f16 MFMA, fused z epilogue -> single f16 ----------------
template<int G, int GI, int START, int AOFF>
__device__ void pv_body(
    const unsigned short* __restrict__ vTS, const unsigned short* __restrict__ attnP,
    const unsigned short* __restrict__ zqT,
    unsigned short* __restrict__ outT, unsigned short* __restrict__ zT,
    unsigned short* Ah, unsigned short* Bh)
{
  constexpr int NF = G / 16;
  const int t = threadIdx.x, b = blockIdx.y, l0 = blockIdx.x * 128;
  const int w = t >> 6, lane = t & 63, ln = lane & 15, lg = lane >> 4;
  const int lrow  = lane >> 2;
  const int chunk = (lane & 3) ^ ((lane >> 4) & 3);
  const int slot  = lg ^ (ln >> 2);
  f32x4 z4 = {0.f, 0.f, 0.f, 0.f};
  f32x4 acc[2][NF];
  #pragma unroll
  for (int i = 0; i < 2; i++)
    #pragma unroll
    for (int j = 0; j < NF; j++) acc[i][j] = z4;
  for (int kc = 0; kc < G; kc += 32) {
    #pragma unroll
    for (int i = 0; i < 2; i++) {
      const int rb = w * 32 + i * 16;
      const size_t g = ((size_t)b * L + l0 + rb + lrow) * 256 + START + kc + chunk * 8;
      gl16(vTS + g, &Ah[rb * 32]);
    }
    for (int i = w; i < G / 16; i += 4) {
      const int rb = i * 16;
      const size_t g = (size_t)b * 18432 + AOFF + (size_t)(rb + lrow) * G + kc + chunk * 8;
      gl16(attnP + g, &Bh[rb * 32]);
    }
    __syncthreads();
    short8v bhf[NF];
    #pragma unroll
    for (int nf = 0; nf < NF; nf++)
      bhf[nf] = *(const short8v*)&Bh[(nf * 16 + ln) * 32 + slot * 8];
    #pragma unroll
    for (int mi = 0; mi < 2; mi++) {
      const int aoff = ((w * 2 + mi) * 16 + ln) * 32 + slot * 8;
      const short8v ah = *(const short8v*)&Ah[aoff];
      #pragma unroll
      for (int nf = 0; nf < NF; nf++)
        acc[mi][nf] = __builtin_amdgcn_mfma_f32_16x16x32_f16(ah, bhf[nf], acc[mi][nf], 0, 0, 0);
    }
    __syncthreads();
  }
  #pragma unroll
  for (int mi = 0; mi < 2; mi++) {
    const int lbase = l0 + (w * 2 + mi) * 16 + lg * 4;
    #pragma unroll
    for (int nf = 0; nf < NF; nf++) {
      const int col = START + nf * 16 + ln;
      #pragma unroll
      for (int r = 0; r < 4; r++) {
        const size_t idx = ((size_t)b * L + lbase + r) * 256 + col;
        const float v = acc[mi][nf][r];
        outT[idx] = f16b(v);
        zT[idx]   = f16b(v + f16tof(zqT[idx]));
      }
    }
  }
}

__global__ __launch_bounds__(256) void pv_kernel(
    const unsigned short* __restrict__ vTS, const unsigned short* __restrict__ attnP,
    const unsigned short* __restrict__ zqT,
    unsigned short* __restrict__ outT, unsigned short* __restrict__ zT)
{
  __shared__ unsigned short Ah[128 * 32];
  __shared__ unsigned short Bh[96 * 32];
  switch (blockIdx.z) {
    case 0:  pv_body<32, 0, 0,   0   >(vTS, attnP, zqT, outT, zT, Ah, Bh); break;
    case 1:  pv_body<64, 1, 32,  1024>(vTS, attnP, zqT, outT, zT, Ah, Bh); break;
    case 2:  pv_body<64, 2, 96,  5120>(vTS, attnP, zqT, outT, zT, Ah, Bh); break;
    default: pv_body<96, 3, 160, 9216>(vTS, attnP, zqT, outT, zT, Ah, Bh); break;
  }
}

// ---------------- qv_cache ----------------
__global__ __launch_bounds__(256) void qv_kernel(const float* __restrict__ sumq,
    const float* __restrict__ sumk, const float* __restrict__ invnq,
    const float* __restrict__ invnk, float* __restrict__ out2)
{
  const int b = blockIdx.x >> 8, r = blockIdx.x & 255;
  float val = 0.f;
  {
    const int idx = b * 256 + 0 + (r & 31);
    val += fmaf(sumq[idx], invnq[idx], sumk[idx] * invnk[idx]);
  }
  {
    const int idx = b * 256 + 32 + (r & 63);
    val += fmaf(sumq[idx], invnq[idx], sumk[idx] * invnk[idx]);
  }
  {
    const int idx = b * 256 + 96 + (r & 63);
    val += fmaf(sumq[idx], invnq[idx], sumk[idx] * invnk[idx]);
  }
  if (r < 192) {
    const int rm = (r < 96) ? r : r - 96;
    const int idx = b * 256 + 160 + rm;
    val += fmaf(sumq[idx], invnq[idx], sumk[idx] * invnk[idx]);
  }
  val *= (1.0f / 4096.f) * 0.25f * 0.9f;
  const float4 o = {val, val, val, val};
  float4* dst = reinterpret_cast<float4*>(out2 + ((size_t)b * C + r) * L);
  for (int i = threadIdx.x; i < 1024; i += 256) dst[i] = o;
}

// ---------------- launch ----------------
extern "C" void kernel_launch(void* const* d_in, const int* in_sizes, int n_in,
                              void* d_out, int out_size, void* d_ws, size_t ws_size,
                              hipStream_t stream)
{
  const float* x           = (const float*)d_in[0];
  const float* temperature = (const float*)d_in[1];
  const float* w_qkv       = (const float*)d_in[2];
  const float* w_dw        = (const float*)d_in[3];
  const float* w_proj      = (const float*)d_in[4];
  const float* w_gate      = (const float*)d_in[5];
  const float* b_gate      = (const float*)d_in[6];
  const float* w_down      = (const float*)d_in[7];
  const float* b_down      = (const float*)d_in[8];
  const float* w_up        = (const float*)d_in[9];
  const float* b_up        = (const float*)d_in[10];

  if (ws_size < 202548224ULL) return;

  char* ws = (char*)d_ws;
  // Region A [0, 96M):
  float*          qkvQ    = (float*)(ws);                      // 32MB fp32 q (dead after conv)
  unsigned short* kvF     = (unsigned short*)(ws + 33554432);  // 32MB f16 k,v (dead after conv)
  unsigned short* vTS     = (unsigned short*)(ws);             // 16MB (after conv)
  unsigned short* zqT     = (unsigned short*)(ws + 16777216);  // 16MB
  float*          Spart   = (float*)(ws + 33554432);           // 4.72MB (after conv)
  unsigned short* attnP   = (unsigned short*)(ws + 38797312);  // 288KB
  unsigned short* preproj = (unsigned short*)(ws);             // 16MB (after pv; single f16)
  // Region B [96M, 192M):
  unsigned short* XThi    = (unsigned short*)(ws + 100663296); // 16MB (dead after qkv)
  unsigned short* XTlo    = (unsigned short*)(ws + 117440512); // 16MB
  unsigned short* qkF     = (unsigned short*)(ws + 100663296); // 32MB (conv out)
  unsigned short* vF      = (unsigned short*)(ws + 134217728); // 16MB
  unsigned short* outT    = (unsigned short*)(ws + 150994944); // 16MB
  unsigned short* zT      = (unsigned short*)(ws + 167772160); // 16MB
  unsigned short* gated   = (unsigned short*)(ws + 184549376); // 16MB
  unsigned short* mid     = (unsigned short*)(ws + 100663296); // 8MB (after scores/vpack)
  // Region C [192M+, persistent):
  unsigned short* Wf16   = (unsigned short*)(ws + 201326592);  // 655360B
  unsigned short* WprojH = (unsigned short*)(ws + 201981952);  // 128KB
  unsigned short* WprojL = (unsigned short*)(ws + 202113024);  // 128KB
  float* csum   = (float*)(ws + 202244096);
  float* csumsq = (float*)(ws + 202260480);
  float* sumq   = (float*)(ws + 202276864);
  float* sumk   = (float*)(ws + 202285056);
  float* invnq  = (float*)(ws + 202293248);
  float* invnk  = (float*)(ws + 202301440);
  int*   order  = (int*)(ws + 202309632);

  float* out_all = (float*)d_out;
  float* qv_out  = out_all + (size_t)B * C * L;

  // 0. weight + input splits
  wsplit_kernel<<<1536, 256, 0, stream>>>(w_qkv, w_gate, w_down, w_up, w_proj,
                                          Wf16, WprojH, WprojL);
  splitx_kernel<<<dim3(64, 4, 8), 256, 0, stream>>>(x, XThi, XTlo);
  // 1. qkv: q-blocks 2-pass -> fp32; k/v-blocks 1-pass -> f16
  hgemm<256, 6, 2><<<dim3(32, 6, 8), 256, 0, stream>>>(
      XThi, XTlo, Wf16, qkvQ, kvF, nullptr, nullptr, 768);
  // 2. depthwise conv (q fp32-in, k/v f16-in) -> qkF/vF single f16 + stats
  dwconv2_kernel<<<dim3(768, 8), 256, 0, stream>>>(qkvQ, kvF, w_dw, qkF, vF, csum, csumsq);
  // 3. channel ordering + sorted stats
  rankstats_kernel<<<1, 256, 0, stream>>>(csum, csumsq, order, sumq, sumk, invnq, invnk);
  // 4. pack v^T sorted + zq (single f16)
  vpack_kernel<<<dim3(64, 8), 256, 0, stream>>>(vF, qkF, order, invnq, invnk, vTS, zqT);
  // 5. attention (1-pass f16)
  scores_kernel<<<dim3(8, 8, 5), 256, 0, stream>>>(qkF, order, Spart);
  softmax_kernel<<<dim3(8, 4, 4), 256, 9216, stream>>>(Spart, invnq, invnk, temperature, attnP);
  pv_kernel<<<dim3(32, 8, 4), 256, 0, stream>>>(vTS, attnP, zqT, outT, zT);
  // 6. MLP chain (1-pass f16)
  hgemm<256, 2, 1><<<dim3(32, 2, 8), 256, 0, stream>>>(
      zT, nullptr, Wf16 + 196608, nullptr, gated, b_gate, zT, 256);
  hgemm<256, 1, 1><<<dim3(32, 1, 8), 256, 0, stream>>>(
      gated, nullptr, Wf16 + 262144, nullptr, mid, b_down, nullptr, 128);
  hgemm<128, 5, 1><<<dim3(32, 2, 8), 256, 0, stream>>>(
      mid, nullptr, Wf16 + 294912, nullptr, preproj, b_up, outT, 256);
  // 7. final projection: 2-pass, f16-PAIR weights (firewall on weight side) -> output 0
  hgemm<256, 0, 3><<<dim3(32, 2, 8), 256, 0, stream>>>(
      preproj, WprojL, WprojH, out_all, nullptr, nullptr, nullptr, 256);
  // 8. qv_cache -> output 1
  qv_kernel<<<2048, 256, 0, stream>>>(sumq, sumk, invnq, invnk, qv_out);
}